// Round 1
// baseline (15230.655 us; speedup 1.0000x reference)
//
#include <hip/hip_runtime.h>
#include <math.h>

#define BB 2
#define NN 20000
#define EE 100000
#define DD 3
#define KK 128
#define CC 128
#define LL 3
#define FCC 128
#define GJ (DD*CC)   // 384

// ---- scratch (device globals; ~225MB, avoids d_ws size assumptions) ----
__device__ __align__(16) float d_bc[BB*NN*KK];
__device__ __align__(16) float d_bs[BB*NN*KK];
__device__ float d_nw[BB*NN];
__device__ __align__(16) float d_hbuf0[BB*CC*NN];
__device__ __align__(16) float d_hbuf1[BB*CC*NN];
__device__ __align__(16) float d_hT[BB*NN*CC];
__device__ __align__(16) float d_gacc[BB*NN*GJ];   // also reused as u-buffer for fc1 output
__device__ __align__(16) float d_g[BB*GJ*NN];
__device__ float d_xc[BB*CC*KK];
__device__ float d_xs[BB*CC*KK];
__device__ float d_x0v[BB*CC];
__device__ float d_fcv[BB*CC*KK];
__device__ float d_fsv[BB*CC*KK];
__device__ float d_f0v[BB*CC];

// ---- basis: bc/bs = cos/sin(nodes . (modes*sp_L)), nw = node_weights ----
__global__ __launch_bounds__(128) void k_basis(const float* __restrict__ nodes,
                                               const float* __restrict__ nodew,
                                               const float* __restrict__ modes,
                                               const float* __restrict__ spL) {
  int bn = blockIdx.x;            // b*NN+n
  int k  = threadIdx.x;
  float x0 = nodes[bn*3+0], x1 = nodes[bn*3+1], x2 = nodes[bn*3+2];
  float tmp = x0*modes[k*3+0]*spL[0] + x1*modes[k*3+1]*spL[1] + x2*modes[k*3+2]*spL[2];
  d_bc[bn*KK+k] = cosf(tmp);
  d_bs[bn*KK+k] = sinf(tmp);
  if (k == 0) d_nw[bn] = nodew[bn];
}

// ---- fc0: h[b][c][n] = cat(x,t) @ fc0_w + fc0_b ----
__global__ __launch_bounds__(256) void k_h0(const float* __restrict__ x,
                                            const float* __restrict__ t,
                                            const float* __restrict__ w,
                                            const float* __restrict__ bias) {
  int tid = blockIdx.x*256 + threadIdx.x;        // = (b*CC+c)*NN + n
  int n = tid % NN;
  int bc_ = tid / NN;
  int c = bc_ % CC;
  int b = bc_ / CC;
  const float* xv = x + (b*NN + n)*3;
  float acc = bias[c] + xv[0]*w[c] + xv[1]*w[CC+c] + xv[2]*w[2*CC+c]
            + t[b*NN+n]*w[3*CC+c];
  d_hbuf0[tid] = acc;
}

__global__ __launch_bounds__(256) void k_zero_xcxs() {
  int tid = blockIdx.x*256 + threadIdx.x;        // BB*CC*KK = 32768 threads
  d_xc[tid] = 0.f;
  d_xs[tid] = 0.f;
}

__global__ __launch_bounds__(256) void k_zero_gacc() {
  int tid = blockIdx.x*256 + threadIdx.x;        // BB*NN*GJ/4 float4s
  reinterpret_cast<float4*>(d_gacc)[tid] = make_float4(0.f,0.f,0.f,0.f);
}

// ---- GEMM1: xc[b,c,k] = sum_n h[b,c,n]*bc[b,n,k]*nw ; xs = -sum_n h*bs*nw ----
__global__ __launch_bounds__(256) void k_gemm1(int cur) {
  int blk = blockIdx.x;                 // b * (4 ctiles) * (32 chunks)
  int b   = blk / (4*32);
  int rem = blk % (4*32);
  int ct  = rem / 32;
  int ch  = rem % 32;
  int k   = threadIdx.x & 127;
  int cg  = threadIdx.x >> 7;
  int cbase = ct*32 + cg*16;
  const float* h = cur ? d_hbuf1 : d_hbuf0;
  float accC[16], accS[16];
  #pragma unroll
  for (int i = 0; i < 16; i++) { accC[i] = 0.f; accS[i] = 0.f; }
  int n0 = ch*625;
  for (int n = n0; n < n0+625; n++) {
    float nwv = d_nw[b*NN+n];
    float bcv = d_bc[(b*NN+n)*KK + k] * nwv;
    float bsv = d_bs[(b*NN+n)*KK + k] * nwv;
    #pragma unroll
    for (int i = 0; i < 16; i++) {
      float hv = h[(b*CC + cbase + i)*NN + n];
      accC[i] += hv*bcv;
      accS[i] -= hv*bsv;
    }
  }
  for (int i = 0; i < 16; i++) {
    atomicAdd(&d_xc[(b*CC + cbase + i)*KK + k], accC[i]);
    atomicAdd(&d_xs[(b*CC + cbase + i)*KK + k], accS[i]);
  }
}

// ---- x0[b,c] = sum_n h[b,c,n]*nw[b,n] ----
__global__ __launch_bounds__(256) void k_x0(int cur) {
  const float* h = cur ? d_hbuf1 : d_hbuf0;
  int b = blockIdx.x >> 7, c = blockIdx.x & 127;
  const float* hp  = h + (b*CC + c)*NN;
  const float* nwp = d_nw + b*NN;
  float acc = 0.f;
  for (int n = threadIdx.x; n < NN; n += 256) acc += hp[n]*nwp[n];
  __shared__ float red[256];
  red[threadIdx.x] = acc;
  __syncthreads();
  for (int s = 128; s > 0; s >>= 1) {
    if (threadIdx.x < s) red[threadIdx.x] += red[threadIdx.x + s];
    __syncthreads();
  }
  if (threadIdx.x == 0) d_x0v[blockIdx.x] = red[0];
}

// ---- spectral mix: fc_ = xc*Wc - xs*Ws ; fs_ = xs*Wc + xc*Ws (per k matvec) ----
__global__ __launch_bounds__(128) void k_spec(const float* __restrict__ Wc,
                                              const float* __restrict__ Ws, int l) {
  int b = blockIdx.x >> 7;
  int o = blockIdx.x & 127;
  int k = threadIdx.x;
  const float* wcp = Wc + ((size_t)(l*CC)*CC + o)*KK + k;
  const float* wsp = Ws + ((size_t)(l*CC)*CC + o)*KK + k;
  float fc = 0.f, fs = 0.f;
  for (int i = 0; i < CC; i++) {
    float xcv = d_xc[(b*CC + i)*KK + k];
    float xsv = d_xs[(b*CC + i)*KK + k];
    float wcv = wcp[(size_t)i*CC*KK];
    float wsv = wsp[(size_t)i*CC*KK];
    fc += xcv*wcv - xsv*wsv;
    fs += xsv*wcv + xcv*wsv;
  }
  d_fcv[(b*CC + o)*KK + k] = fc;
  d_fsv[(b*CC + o)*KK + k] = fs;
}

// ---- f0[b,o] = sum_i x0[b,i]*W0[l,i,o] ----
__global__ __launch_bounds__(128) void k_f0(const float* __restrict__ W0, int l) {
  int b = blockIdx.x;
  int o = threadIdx.x;
  float acc = 0.f;
  for (int i = 0; i < CC; i++) acc += d_x0v[b*CC + i]*W0[(l*CC + i)*CC + o];
  d_f0v[b*CC + o] = acc;
}

// ---- transpose h (b,c,n) -> hT (b,n,c) for coalesced edge gathers ----
__global__ __launch_bounds__(256) void k_transpose(int cur) {
  __shared__ float tile[32][129];
  const float* h = cur ? d_hbuf1 : d_hbuf0;
  int blk = blockIdx.x;
  int nt = blk % 625;
  int b  = blk / 625;
  int n0 = nt*32;
  int nl = threadIdx.x & 31;
  int cg = threadIdx.x >> 5;
  for (int c = cg; c < 128; c += 8)
    tile[nl][c] = h[(b*CC + c)*NN + n0 + nl];
  __syncthreads();
  int cl = threadIdx.x & 127;
  int nr = threadIdx.x >> 7;
  for (int nn = nr; nn < 32; nn += 2)
    d_hT[(b*NN + n0 + nn)*CC + cl] = tile[nn][cl];
}

// ---- edge gradient: atomic segment-sum over src ----
__global__ __launch_bounds__(256) void k_grad(const int* __restrict__ edges,
                                              const float* __restrict__ egw) {
  int idx2 = blockIdx.x*2 + (threadIdx.x >> 7);   // global (b*EE+e)
  int c = threadIdx.x & 127;
  int b = idx2 / EE;
  int e = idx2 % EE;
  int src = edges[(b*EE + e)*2 + 0];
  int dst = edges[(b*EE + e)*2 + 1];
  float diff = d_hT[(b*NN + dst)*CC + c] - d_hT[(b*NN + src)*CC + c];
  float w0 = egw[(b*EE + e)*3 + 0];
  float w1 = egw[(b*EE + e)*3 + 1];
  float w2 = egw[(b*EE + e)*3 + 2];
  float* gp = d_gacc + (size_t)(b*NN + src)*GJ;
  atomicAdd(&gp[0*CC + c], w0*diff);
  atomicAdd(&gp[1*CC + c], w1*diff);
  atomicAdd(&gp[2*CC + c], w2*diff);
}

// ---- g[b,j,n] = gacc[b,n,j] / (1+|gacc|): transpose + nonlinearity ----
__global__ __launch_bounds__(256) void k_gnorm() {
  __shared__ float tile[32][129];
  int blk = blockIdx.x;
  int jt = blk % 3;
  int nt = (blk/3) % 625;
  int b  = blk / (3*625);
  int n0 = nt*32;
  int jl = threadIdx.x & 127;
  int ng = threadIdx.x >> 7;
  for (int nn = ng; nn < 32; nn += 2)
    tile[nn][jl] = d_gacc[(size_t)(b*NN + n0 + nn)*GJ + jt*128 + jl];
  __syncthreads();
  int nl = threadIdx.x & 31;
  int jg = threadIdx.x >> 5;
  for (int jj = jg; jj < 128; jj += 8) {
    float v = tile[nl][jj];
    d_g[(size_t)(b*GJ + jt*128 + jj)*NN + n0 + nl] = v/(1.f + fabsf(v));
  }
}

// ---- fused layer output: h_new = x1 + x2 + x3 (+ gelu) ----
__global__ __launch_bounds__(256) void k_layer_out(const float* __restrict__ wsw,
                                                   const float* __restrict__ wsb,
                                                   const float* __restrict__ gwsw,
                                                   const float* __restrict__ gwsb,
                                                   int l, int cur, int apply_gelu) {
  int tid = blockIdx.x*256 + threadIdx.x;   // = (b*CC+o)*NN + n
  int n  = tid % NN;
  int bo = tid / NN;
  int o  = bo % CC;
  int b  = bo / CC;
  const float* h  = cur ? d_hbuf1 : d_hbuf0;
  float*       hn = cur ? d_hbuf0 : d_hbuf1;
  const float* fcp = d_fcv + (b*CC + o)*KK;
  const float* fsp = d_fsv + (b*CC + o)*KK;
  const float* bcp = d_bc + (b*NN + n)*KK;
  const float* bsp = d_bs + (b*NN + n)*KK;
  float ac = 0.f, as = 0.f;
  #pragma unroll 8
  for (int k2 = 0; k2 < KK; k2++) { ac += fcp[k2]*bcp[k2]; as += fsp[k2]*bsp[k2]; }
  float acc = d_f0v[b*CC + o] + 2.f*ac - 2.f*as;
  const float* wr = wsw + (l*CC + o)*CC;
  const float* hb = h + b*CC*NN + n;
  float a2 = wsb[l*CC + o];
  #pragma unroll 8
  for (int c2 = 0; c2 < CC; c2++) a2 += wr[c2]*hb[c2*NN];
  const float* gr = gwsw + (l*CC + o)*GJ;
  const float* gb = d_g + (size_t)b*GJ*NN + n;
  float a3 = gwsb[l*CC + o];
  #pragma unroll 8
  for (int j = 0; j < GJ; j++) a3 += gr[j]*gb[(size_t)j*NN];
  float r = acc + a2 + a3;
  if (apply_gelu) r = 0.5f*r*(1.f + erff(r*0.70710678118f));
  hn[tid] = r;
}

// ---- fc1 + gelu -> u (reuse d_gacc), layout [b][n][o2] ----
__global__ __launch_bounds__(256) void k_fc1(const float* __restrict__ fc1w,
                                             const float* __restrict__ fc1b, int cur) {
  int tid = blockIdx.x*256 + threadIdx.x;   // = (b*NN+n)*FCC + o2
  int o2 = tid & 127;
  int bn = tid >> 7;
  int b = bn / NN, n = bn % NN;
  const float* h = cur ? d_hbuf1 : d_hbuf0;
  const float* hb = h + b*CC*NN + n;
  float acc = fc1b[o2];
  #pragma unroll 8
  for (int c = 0; c < CC; c++) acc += hb[(size_t)c*NN]*fc1w[c*FCC + o2];
  acc = 0.5f*acc*(1.f + erff(acc*0.70710678118f));
  d_gacc[tid] = acc;
}

// ---- fc2 + residual ----
__global__ __launch_bounds__(256) void k_out(const float* __restrict__ x,
                                             const float* __restrict__ t,
                                             const float* __restrict__ fc2w,
                                             const float* __restrict__ fc2b,
                                             float* __restrict__ out) {
  int tid = blockIdx.x*256 + threadIdx.x;   // b*NN+n
  if (tid >= BB*NN) return;
  const float* up = d_gacc + (size_t)tid*FCC;
  float a0 = fc2b[0], a1 = fc2b[1], a2v = fc2b[2];
  #pragma unroll 8
  for (int o2 = 0; o2 < FCC; o2++) {
    float uv = up[o2];
    a0  += uv*fc2w[o2*3 + 0];
    a1  += uv*fc2w[o2*3 + 1];
    a2v += uv*fc2w[o2*3 + 2];
  }
  float tv = t[tid];
  out[tid*3 + 0] = x[tid*3 + 0] + tv*a0;
  out[tid*3 + 1] = x[tid*3 + 1] + tv*a1;
  out[tid*3 + 2] = x[tid*3 + 2] + tv*a2v;
}

extern "C" void kernel_launch(void* const* d_in, const int* in_sizes, int n_in,
                              void* d_out, int out_size, void* d_ws, size_t ws_size,
                              hipStream_t stream) {
  const float* x     = (const float*)d_in[0];
  const float* t     = (const float*)d_in[1];
  const float* nodes = (const float*)d_in[3];
  const float* nodew = (const float*)d_in[4];
  const int*   edges = (const int*)d_in[5];
  const float* egw   = (const float*)d_in[6];
  const float* modes = (const float*)d_in[7];
  const float* spL   = (const float*)d_in[8];
  const float* fc0w  = (const float*)d_in[9];
  const float* fc0b  = (const float*)d_in[10];
  const float* Wc    = (const float*)d_in[11];
  const float* Ws    = (const float*)d_in[12];
  const float* W0    = (const float*)d_in[13];
  const float* wsw   = (const float*)d_in[14];
  const float* wsb   = (const float*)d_in[15];
  const float* gwsw  = (const float*)d_in[16];
  const float* gwsb  = (const float*)d_in[17];
  const float* fc1w  = (const float*)d_in[18];
  const float* fc1b  = (const float*)d_in[19];
  const float* fc2w  = (const float*)d_in[20];
  const float* fc2b  = (const float*)d_in[21];
  float* out = (float*)d_out;

  hipLaunchKernelGGL(k_basis, dim3(BB*NN), dim3(128), 0, stream, nodes, nodew, modes, spL);
  hipLaunchKernelGGL(k_h0, dim3(BB*CC*NN/256), dim3(256), 0, stream, x, t, fc0w, fc0b);

  int cur = 0;
  for (int l = 0; l < LL; l++) {
    hipLaunchKernelGGL(k_zero_xcxs, dim3(BB*CC*KK/256), dim3(256), 0, stream);
    hipLaunchKernelGGL(k_gemm1, dim3(BB*4*32), dim3(256), 0, stream, cur);
    hipLaunchKernelGGL(k_x0, dim3(BB*CC), dim3(256), 0, stream, cur);
    hipLaunchKernelGGL(k_spec, dim3(BB*CC), dim3(128), 0, stream, Wc, Ws, l);
    hipLaunchKernelGGL(k_f0, dim3(BB), dim3(CC), 0, stream, W0, l);
    hipLaunchKernelGGL(k_transpose, dim3(BB*625), dim3(256), 0, stream, cur);
    hipLaunchKernelGGL(k_zero_gacc, dim3(BB*NN*GJ/4/256), dim3(256), 0, stream);
    hipLaunchKernelGGL(k_grad, dim3(BB*EE/2), dim3(256), 0, stream, edges, egw);
    hipLaunchKernelGGL(k_gnorm, dim3(BB*625*3), dim3(256), 0, stream);
    hipLaunchKernelGGL(k_layer_out, dim3(BB*CC*NN/256), dim3(256), 0, stream,
                       wsw, wsb, gwsw, gwsb, l, cur, (l != LL-1) ? 1 : 0);
    cur ^= 1;
  }

  hipLaunchKernelGGL(k_fc1, dim3(BB*NN*FCC/256), dim3(256), 0, stream, fc1w, fc1b, cur);
  hipLaunchKernelGGL(k_out, dim3((BB*NN + 255)/256), dim3(256), 0, stream, x, t, fc2w, fc2b, out);
}

// Round 2
// 2956.744 us; speedup vs baseline: 5.1512x; 5.1512x over previous
//
#include <hip/hip_runtime.h>
#include <math.h>

#define BB 2
#define NN 20000
#define EE 100000
#define DD 3
#define KK 128
#define CC 128
#define LL 3
#define FCC 128
#define GJ (DD*CC)    // 384
#define KR 768        // stacked contraction: 128 bc + 128 bs + 128 h + 384 g
#define NP 20096      // padded N: 157 tiles * 128
#define NTILE 128
#define OTILE 64
#define KCH 32

// ---- scratch (device globals) ----
__device__ __align__(16) float d_bc[BB*NN*KK];       // [b][n][k] for k_gemm1
__device__ __align__(16) float d_bs[BB*NN*KK];
__device__ float d_nw[BB*NN];
__device__ __align__(16) float d_stack[(size_t)BB*KR*NP];  // rows: 0 bcT,128 bsT,256 h,384 g
__device__ __align__(16) float d_hnew[(size_t)BB*CC*NP];   // GEMM output / fc1 output
__device__ __align__(16) float d_hT[BB*NN*CC];
__device__ __align__(16) float d_gacc[(size_t)BB*NN*GJ];
__device__ __align__(16) float d_Amat[BB*KR*CC];     // [b][r][o]
__device__ float d_xc[BB*CC*KK];
__device__ float d_xs[BB*CC*KK];
__device__ float d_x0v[BB*CC];
__device__ float d_fcv[BB*CC*KK];
__device__ float d_fsv[BB*CC*KK];
__device__ float d_bias[BB*CC];

// ---- basis: bc/bs[n][k] = cos/sin(nodes . (modes*sp_L)), nw ----
__global__ __launch_bounds__(128) void k_basis(const float* __restrict__ nodes,
                                               const float* __restrict__ nodew,
                                               const float* __restrict__ modes,
                                               const float* __restrict__ spL) {
  int bn = blockIdx.x;
  int k  = threadIdx.x;
  float x0 = nodes[bn*3+0], x1 = nodes[bn*3+1], x2 = nodes[bn*3+2];
  float tmp = x0*modes[k*3+0]*spL[0] + x1*modes[k*3+1]*spL[1] + x2*modes[k*3+2]*spL[2];
  d_bc[bn*KK+k] = cosf(tmp);
  d_bs[bn*KK+k] = sinf(tmp);
  if (k == 0) d_nw[bn] = nodew[bn];
}

// ---- transpose bc/bs [n][k] -> stack rows [k][n] (run once) ----
__global__ __launch_bounds__(256) void k_basisT() {
  __shared__ float t1[32][129];
  __shared__ float t2[32][129];
  int blk = blockIdx.x;
  int nt = blk % 625;
  int b  = blk / 625;
  int n0 = nt*32;
  int nl = threadIdx.x & 31;
  int cg = threadIdx.x >> 5;
  for (int k = cg; k < 128; k += 8) {
    t1[nl][k] = d_bc[(b*NN + n0 + nl)*KK + k];
    t2[nl][k] = d_bs[(b*NN + n0 + nl)*KK + k];
  }
  __syncthreads();
  int kl = threadIdx.x & 127;
  int nr = threadIdx.x >> 7;
  float* bcT = d_stack + (size_t)(b*KR + 0)*NP;
  float* bsT = d_stack + (size_t)(b*KR + 128)*NP;
  for (int nn = nr; nn < 32; nn += 2) {
    bcT[(size_t)kl*NP + n0 + nn] = t1[nn][kl];
    bsT[(size_t)kl*NP + n0 + nn] = t2[nn][kl];
  }
}

// ---- fc0 -> stack h rows ----
__global__ __launch_bounds__(256) void k_h0(const float* __restrict__ x,
                                            const float* __restrict__ t,
                                            const float* __restrict__ w,
                                            const float* __restrict__ bias) {
  int tid = blockIdx.x*256 + threadIdx.x;  // (b*CC+c)*NN + n
  int n = tid % NN;
  int bc_ = tid / NN;
  int c = bc_ % CC;
  int b = bc_ / CC;
  const float* xv = x + (b*NN + n)*3;
  float acc = bias[c] + xv[0]*w[c] + xv[1]*w[CC+c] + xv[2]*w[2*CC+c]
            + t[b*NN+n]*w[3*CC+c];
  d_stack[(size_t)(b*KR + 256 + c)*NP + n] = acc;
}

__global__ __launch_bounds__(256) void k_zero_xcxs() {
  int tid = blockIdx.x*256 + threadIdx.x;
  d_xc[tid] = 0.f;
  d_xs[tid] = 0.f;
}

__global__ __launch_bounds__(256) void k_zero_gacc() {
  int tid = blockIdx.x*256 + threadIdx.x;
  reinterpret_cast<float4*>(d_gacc)[tid] = make_float4(0.f,0.f,0.f,0.f);
}

// ---- GEMM1: xc[b,c,k] = sum_n h[b,c,n]*bc[b,n,k]*nw ; xs = -sum h*bs*nw ----
__global__ __launch_bounds__(256) void k_gemm1() {
  int blk = blockIdx.x;
  int b   = blk / (4*32);
  int rem = blk % (4*32);
  int ct  = rem / 32;
  int ch  = rem % 32;
  int k   = threadIdx.x & 127;
  int cg  = threadIdx.x >> 7;
  int cbase = ct*32 + cg*16;
  const float* h = d_stack + (size_t)(b*KR + 256)*NP;
  float accC[16], accS[16];
  #pragma unroll
  for (int i = 0; i < 16; i++) { accC[i] = 0.f; accS[i] = 0.f; }
  int n0 = ch*625;
  for (int n = n0; n < n0+625; n++) {
    float nwv = d_nw[b*NN+n];
    float bcv = d_bc[(b*NN+n)*KK + k] * nwv;
    float bsv = d_bs[(b*NN+n)*KK + k] * nwv;
    #pragma unroll
    for (int i = 0; i < 16; i++) {
      float hv = h[(size_t)(cbase + i)*NP + n];
      accC[i] += hv*bcv;
      accS[i] -= hv*bsv;
    }
  }
  for (int i = 0; i < 16; i++) {
    atomicAdd(&d_xc[(b*CC + cbase + i)*KK + k], accC[i]);
    atomicAdd(&d_xs[(b*CC + cbase + i)*KK + k], accS[i]);
  }
}

// ---- x0[b,c] = sum_n h[b,c,n]*nw ----
__global__ __launch_bounds__(256) void k_x0() {
  int b = blockIdx.x >> 7, c = blockIdx.x & 127;
  const float* hp  = d_stack + (size_t)(b*KR + 256 + c)*NP;
  const float* nwp = d_nw + b*NN;
  float acc = 0.f;
  for (int n = threadIdx.x; n < NN; n += 256) acc += hp[n]*nwp[n];
  __shared__ float red[256];
  red[threadIdx.x] = acc;
  __syncthreads();
  for (int s = 128; s > 0; s >>= 1) {
    if (threadIdx.x < s) red[threadIdx.x] += red[threadIdx.x + s];
    __syncthreads();
  }
  if (threadIdx.x == 0) d_x0v[blockIdx.x] = red[0];
}

// ---- spectral mix per k ----
__global__ __launch_bounds__(128) void k_spec(const float* __restrict__ Wc,
                                              const float* __restrict__ Ws, int l) {
  int b = blockIdx.x >> 7;
  int o = blockIdx.x & 127;
  int k = threadIdx.x;
  const float* wcp = Wc + ((size_t)(l*CC)*CC + o)*KK + k;
  const float* wsp = Ws + ((size_t)(l*CC)*CC + o)*KK + k;
  float fc = 0.f, fs = 0.f;
  for (int i = 0; i < CC; i++) {
    float xcv = d_xc[(b*CC + i)*KK + k];
    float xsv = d_xs[(b*CC + i)*KK + k];
    float wcv = wcp[(size_t)i*CC*KK];
    float wsv = wsp[(size_t)i*CC*KK];
    fc += xcv*wcv - xsv*wsv;
    fs += xsv*wcv + xcv*wsv;
  }
  d_fcv[(b*CC + o)*KK + k] = fc;
  d_fsv[(b*CC + o)*KK + k] = fs;
}

// ---- f0 + full bias ----
__global__ __launch_bounds__(128) void k_f0(const float* __restrict__ W0,
                                            const float* __restrict__ wsb,
                                            const float* __restrict__ gwsb, int l) {
  int b = blockIdx.x;
  int o = threadIdx.x;
  float acc = 0.f;
  for (int i = 0; i < CC; i++) acc += d_x0v[b*CC + i]*W0[(l*CC + i)*CC + o];
  d_bias[b*CC + o] = acc + wsb[l*CC + o] + gwsb[l*CC + o];
}

// ---- build A matrix [b][r][o] with scales folded ----
__global__ __launch_bounds__(128) void k_buildA(const float* __restrict__ wsw,
                                                const float* __restrict__ gwsw, int l) {
  int br = blockIdx.x;          // b*KR + r
  int b = br / KR;
  int r = br % KR;
  int o = threadIdx.x;
  float v;
  if (r < 128)       v =  2.f*d_fcv[(b*CC + o)*KK + r];
  else if (r < 256)  v = -2.f*d_fsv[(b*CC + o)*KK + (r-128)];
  else if (r < 384)  v = wsw[(l*CC + o)*CC + (r-256)];
  else               v = gwsw[(l*CC + o)*GJ + (r-384)];
  d_Amat[(b*KR + r)*CC + o] = v;
}

// ---- transpose h (stack) -> hT [b][n][c] for edge gathers ----
__global__ __launch_bounds__(256) void k_transpose() {
  __shared__ float tile[32][129];
  int blk = blockIdx.x;
  int nt = blk % 625;
  int b  = blk / 625;
  int n0 = nt*32;
  int nl = threadIdx.x & 31;
  int cg = threadIdx.x >> 5;
  const float* h = d_stack + (size_t)(b*KR + 256)*NP;
  for (int c = cg; c < 128; c += 8)
    tile[nl][c] = h[(size_t)c*NP + n0 + nl];
  __syncthreads();
  int cl = threadIdx.x & 127;
  int nr = threadIdx.x >> 7;
  for (int nn = nr; nn < 32; nn += 2)
    d_hT[(b*NN + n0 + nn)*CC + cl] = tile[nn][cl];
}

// ---- edge gradient: atomic segment-sum over src ----
__global__ __launch_bounds__(256) void k_grad(const int* __restrict__ edges,
                                              const float* __restrict__ egw) {
  int idx2 = blockIdx.x*2 + (threadIdx.x >> 7);
  int c = threadIdx.x & 127;
  int b = idx2 / EE;
  int e = idx2 % EE;
  int src = edges[(b*EE + e)*2 + 0];
  int dst = edges[(b*EE + e)*2 + 1];
  float diff = d_hT[(b*NN + dst)*CC + c] - d_hT[(b*NN + src)*CC + c];
  float w0 = egw[(b*EE + e)*3 + 0];
  float w1 = egw[(b*EE + e)*3 + 1];
  float w2 = egw[(b*EE + e)*3 + 2];
  float* gp = d_gacc + (size_t)(b*NN + src)*GJ;
  atomicAdd(&gp[0*CC + c], w0*diff);
  atomicAdd(&gp[1*CC + c], w1*diff);
  atomicAdd(&gp[2*CC + c], w2*diff);
}

// ---- g rows of stack: g[b][j][n] = gacc[b][n][j]/(1+|.|) ----
__global__ __launch_bounds__(256) void k_gnorm() {
  __shared__ float tile[32][129];
  int blk = blockIdx.x;
  int jt = blk % 3;
  int nt = (blk/3) % 625;
  int b  = blk / (3*625);
  int n0 = nt*32;
  int jl = threadIdx.x & 127;
  int ng = threadIdx.x >> 7;
  for (int nn = ng; nn < 32; nn += 2)
    tile[nn][jl] = d_gacc[(size_t)(b*NN + n0 + nn)*GJ + jt*128 + jl];
  __syncthreads();
  int nl = threadIdx.x & 31;
  int jg = threadIdx.x >> 5;
  float* grow = d_stack + (size_t)(b*KR + 384 + jt*128)*NP;
  for (int jj = jg; jj < 128; jj += 8) {
    float v = tile[nl][jj];
    grow[(size_t)jj*NP + n0 + nl] = v/(1.f + fabsf(v));
  }
}

// ---- the big tiled GEMM: C[b][o][n] = sum_r A[b][r][o]*B[b][r][n] + bias ----
// A row stride 128 (o contiguous), B row stride NP, C row stride NP.
__global__ __launch_bounds__(256) void k_gemm_big(const float* __restrict__ A, size_t asb,
                                                  const float* __restrict__ Bm, size_t bsb,
                                                  float* __restrict__ Cm, size_t csb,
                                                  int K,
                                                  const float* __restrict__ bias, int bias_sb,
                                                  int gelu) {
  __shared__ float As[KCH][OTILE];    // 8KB
  __shared__ float Bs[KCH][NTILE];    // 16KB
  int b = blockIdx.z;
  const float* Ab = A + asb*b;
  const float* Bb = Bm + bsb*b;
  int o_base = blockIdx.y*OTILE;
  int n_base = blockIdx.x*NTILE;
  int tid = threadIdx.x;
  int tn = tid & 15;         // n-group: n0 = n_base + tn*8
  int to = tid >> 4;         // o-group: o0 = o_base + to*4
  float acc[4][8];
  #pragma unroll
  for (int i = 0; i < 4; i++)
    #pragma unroll
    for (int j = 0; j < 8; j++) acc[i][j] = 0.f;

  for (int k0 = 0; k0 < K; k0 += KCH) {
    __syncthreads();
    // A chunk: 32 rows x 64 cols = 512 float4, 2/thread
    #pragma unroll
    for (int i = 0; i < 2; i++) {
      int idx = tid + i*256;
      int r = idx >> 4;
      int c4 = (idx & 15)*4;
      *(float4*)&As[r][c4] = *(const float4*)&Ab[(size_t)(k0+r)*128 + o_base + c4];
    }
    // B chunk: 32 rows x 128 cols = 1024 float4, 4/thread
    #pragma unroll
    for (int i = 0; i < 4; i++) {
      int idx = tid + i*256;
      int r = idx >> 5;
      int c4 = (idx & 31)*4;
      *(float4*)&Bs[r][c4] = *(const float4*)&Bb[(size_t)(k0+r)*NP + n_base + c4];
    }
    __syncthreads();
    #pragma unroll 8
    for (int kk = 0; kk < KCH; kk++) {
      float4 a4 = *(float4*)&As[kk][to*4];
      float4 b4a = *(float4*)&Bs[kk][tn*8];
      float4 b4b = *(float4*)&Bs[kk][tn*8+4];
      float av[4] = {a4.x, a4.y, a4.z, a4.w};
      float bv[8] = {b4a.x, b4a.y, b4a.z, b4a.w, b4b.x, b4b.y, b4b.z, b4b.w};
      #pragma unroll
      for (int i = 0; i < 4; i++)
        #pragma unroll
        for (int j = 0; j < 8; j++)
          acc[i][j] += av[i]*bv[j];
    }
  }
  // epilogue
  const float* bp = bias + (size_t)bias_sb*b;
  #pragma unroll
  for (int i = 0; i < 4; i++) {
    int o = o_base + to*4 + i;
    float bvv = bp[o];
    float vals[8];
    #pragma unroll
    for (int j = 0; j < 8; j++) {
      float r = acc[i][j] + bvv;
      if (gelu) r = 0.5f*r*(1.f + erff(r*0.70710678118f));
      vals[j] = r;
    }
    int n0 = n_base + tn*8;
    float* crow = Cm + csb*b + (size_t)o*NP;
    if (n0 < NN)     *(float4*)&crow[n0]   = make_float4(vals[0],vals[1],vals[2],vals[3]);
    if (n0+4 < NN)   *(float4*)&crow[n0+4] = make_float4(vals[4],vals[5],vals[6],vals[7]);
  }
}

// ---- copy hnew -> stack h rows ----
__global__ __launch_bounds__(256) void k_copy_h() {
  size_t tid = (size_t)blockIdx.x*256 + threadIdx.x;   // over BB*CC*NP
  size_t bc_ = tid / NP;
  size_t n = tid % NP;
  size_t b = bc_ / CC, c = bc_ % CC;
  d_stack[((b*KR + 256 + c))*(size_t)NP + n] = d_hnew[tid];
}

// ---- fc2 + residual; u = d_hnew [b][o2][n] ----
__global__ __launch_bounds__(256) void k_out(const float* __restrict__ x,
                                             const float* __restrict__ t,
                                             const float* __restrict__ fc2w,
                                             const float* __restrict__ fc2b,
                                             float* __restrict__ out) {
  int tid = blockIdx.x*256 + threadIdx.x;   // b*NN+n
  if (tid >= BB*NN) return;
  int b = tid / NN, n = tid % NN;
  const float* up = d_hnew + (size_t)b*CC*NP + n;
  float a0 = fc2b[0], a1 = fc2b[1], a2v = fc2b[2];
  #pragma unroll 8
  for (int o2 = 0; o2 < FCC; o2++) {
    float uv = up[(size_t)o2*NP];
    a0  += uv*fc2w[o2*3 + 0];
    a1  += uv*fc2w[o2*3 + 1];
    a2v += uv*fc2w[o2*3 + 2];
  }
  float tv = t[tid];
  out[tid*3 + 0] = x[tid*3 + 0] + tv*a0;
  out[tid*3 + 1] = x[tid*3 + 1] + tv*a1;
  out[tid*3 + 2] = x[tid*3 + 2] + tv*a2v;
}

extern "C" void kernel_launch(void* const* d_in, const int* in_sizes, int n_in,
                              void* d_out, int out_size, void* d_ws, size_t ws_size,
                              hipStream_t stream) {
  const float* x     = (const float*)d_in[0];
  const float* t     = (const float*)d_in[1];
  const float* nodes = (const float*)d_in[3];
  const float* nodew = (const float*)d_in[4];
  const int*   edges = (const int*)d_in[5];
  const float* egw   = (const float*)d_in[6];
  const float* modes = (const float*)d_in[7];
  const float* spL   = (const float*)d_in[8];
  const float* fc0w  = (const float*)d_in[9];
  const float* fc0b  = (const float*)d_in[10];
  const float* Wc    = (const float*)d_in[11];
  const float* Ws    = (const float*)d_in[12];
  const float* W0    = (const float*)d_in[13];
  const float* wsw   = (const float*)d_in[14];
  const float* wsb   = (const float*)d_in[15];
  const float* gwsw  = (const float*)d_in[16];
  const float* gwsb  = (const float*)d_in[17];
  const float* fc1w  = (const float*)d_in[18];
  const float* fc1b  = (const float*)d_in[19];
  const float* fc2w  = (const float*)d_in[20];
  const float* fc2b  = (const float*)d_in[21];
  float* out = (float*)d_out;

  float* d_stack_p; hipGetSymbolAddress((void**)&d_stack_p, HIP_SYMBOL(d_stack));
  float* d_Amat_p;  hipGetSymbolAddress((void**)&d_Amat_p,  HIP_SYMBOL(d_Amat));
  float* d_hnew_p;  hipGetSymbolAddress((void**)&d_hnew_p,  HIP_SYMBOL(d_hnew));
  float* d_bias_p;  hipGetSymbolAddress((void**)&d_bias_p,  HIP_SYMBOL(d_bias));

  hipLaunchKernelGGL(k_basis, dim3(BB*NN), dim3(128), 0, stream, nodes, nodew, modes, spL);
  hipLaunchKernelGGL(k_basisT, dim3(BB*625), dim3(256), 0, stream);
  hipLaunchKernelGGL(k_h0, dim3(BB*CC*NN/256), dim3(256), 0, stream, x, t, fc0w, fc0b);

  for (int l = 0; l < LL; l++) {
    if (l > 0)
      hipLaunchKernelGGL(k_copy_h, dim3((unsigned)((size_t)BB*CC*NP/256)), dim3(256), 0, stream);
    hipLaunchKernelGGL(k_zero_xcxs, dim3(BB*CC*KK/256), dim3(256), 0, stream);
    hipLaunchKernelGGL(k_gemm1, dim3(BB*4*32), dim3(256), 0, stream);
    hipLaunchKernelGGL(k_x0, dim3(BB*CC), dim3(256), 0, stream);
    hipLaunchKernelGGL(k_spec, dim3(BB*CC), dim3(128), 0, stream, Wc, Ws, l);
    hipLaunchKernelGGL(k_f0, dim3(BB), dim3(CC), 0, stream, W0, wsb, gwsb, l);
    hipLaunchKernelGGL(k_buildA, dim3(BB*KR), dim3(128), 0, stream, wsw, gwsw, l);
    hipLaunchKernelGGL(k_transpose, dim3(BB*625), dim3(256), 0, stream);
    hipLaunchKernelGGL(k_zero_gacc, dim3((unsigned)((size_t)BB*NN*GJ/4/256)), dim3(256), 0, stream);
    hipLaunchKernelGGL(k_grad, dim3(BB*EE/2), dim3(256), 0, stream, edges, egw);
    hipLaunchKernelGGL(k_gnorm, dim3(BB*625*3), dim3(256), 0, stream);
    hipLaunchKernelGGL(k_gemm_big, dim3(157, CC/OTILE, BB), dim3(256), 0, stream,
                       d_Amat_p, (size_t)KR*CC, d_stack_p, (size_t)KR*NP,
                       d_hnew_p, (size_t)CC*NP, KR, d_bias_p, CC, (l != LL-1) ? 1 : 0);
  }

  // fc1: reuse GEMM with A = fc1_w [c][o2] (shared across b), then fc2+residual
  hipLaunchKernelGGL(k_copy_h, dim3((unsigned)((size_t)BB*CC*NP/256)), dim3(256), 0, stream);
  hipLaunchKernelGGL(k_gemm_big, dim3(157, FCC/OTILE, BB), dim3(256), 0, stream,
                     fc1w, (size_t)0,
                     d_stack_p + (size_t)256*NP, (size_t)KR*NP,
                     d_hnew_p, (size_t)FCC*NP, CC, fc1b, 0, 1);
  hipLaunchKernelGGL(k_out, dim3((BB*NN + 255)/256), dim3(256), 0, stream, x, t, fc2w, fc2b, out);
}

// Round 3
// 1947.313 us; speedup vs baseline: 7.8214x; 1.5184x over previous
//
#include <hip/hip_runtime.h>
#include <math.h>

#define BB 2
#define NN 20000
#define EE 100000
#define DD 3
#define KK 128
#define CC 128
#define LL 3
#define FCC 128
#define GJ (DD*CC)    // 384
#define KR 768        // stacked contraction: 128 bc + 128 bs + 128 h + 384 g
#define NP 20096      // padded N: 157 tiles * 128
#define NTILE 128
#define OTILE 64
#define KCH 32
#define NCHK 157      // split-k chunks for gemm1 (128 n each)

// ---- scratch (device globals) ----
__device__ __align__(16) float d_bc[(size_t)BB*NP*KK];   // [b][n][k], padded rows
__device__ __align__(16) float d_bs[(size_t)BB*NP*KK];
__device__ float d_nw[BB*NN];
__device__ __align__(16) float d_stack[(size_t)BB*KR*NP];  // rows: 0 bcT,128 bsT,256 h,384 g
__device__ __align__(16) float d_hnew[(size_t)BB*CC*NP];
__device__ __align__(16) float d_hT[(size_t)BB*NN*CC];     // [b][n][c] unweighted
__device__ __align__(16) float d_hTw[(size_t)BB*NP*CC];    // [b][n][c] * nw, zero-padded
__device__ __align__(16) float d_gacc[(size_t)BB*NN*GJ];
__device__ __align__(16) float d_Amat[BB*KR*CC];
__device__ __align__(16) float d_part[(size_t)BB*2*NCHK*2*64*128]; // [b*2+half][chunk][arr][64][128]
__device__ float d_xc[BB*CC*KK];
__device__ float d_xs[BB*CC*KK];
__device__ float d_x0v[BB*CC];
__device__ float d_fcv[BB*CC*KK];
__device__ float d_fsv[BB*CC*KK];
__device__ float d_bias[BB*CC];

// ---- basis ----
__global__ __launch_bounds__(128) void k_basis(const float* __restrict__ nodes,
                                               const float* __restrict__ nodew,
                                               const float* __restrict__ modes,
                                               const float* __restrict__ spL) {
  int bn = blockIdx.x;            // b*NN + n
  int k  = threadIdx.x;
  int b = bn / NN, n = bn % NN;
  float x0 = nodes[bn*3+0], x1 = nodes[bn*3+1], x2 = nodes[bn*3+2];
  float tmp = x0*modes[k*3+0]*spL[0] + x1*modes[k*3+1]*spL[1] + x2*modes[k*3+2]*spL[2];
  d_bc[((size_t)(b*NP + n))*KK + k] = cosf(tmp);
  d_bs[((size_t)(b*NP + n))*KK + k] = sinf(tmp);
  if (k == 0) d_nw[bn] = nodew[bn];
}

// ---- zero pads of bc/bs/hTw rows [NN,NP) ----
__global__ __launch_bounds__(256) void k_zero_pad() {
  int tid = blockIdx.x*256 + threadIdx.x;   // 3 arrays * BB * 96 * 128 = 73728
  int arr = tid / 24576;
  int rem = tid % 24576;
  int b = rem / 12288;
  int r = rem % 12288;
  int n = NN + r/128;
  int k = r % 128;
  size_t idx = ((size_t)(b*NP + n))*128 + k;
  if (arr == 0) d_bc[idx] = 0.f;
  else if (arr == 1) d_bs[idx] = 0.f;
  else d_hTw[idx] = 0.f;
}

// ---- transpose bc/bs [n][k] -> stack rows [k][n] (once) ----
__global__ __launch_bounds__(256) void k_basisT() {
  __shared__ float t1[32][129];
  __shared__ float t2[32][129];
  int blk = blockIdx.x;
  int nt = blk % 625;
  int b  = blk / 625;
  int n0 = nt*32;
  int nl = threadIdx.x & 31;
  int cg = threadIdx.x >> 5;
  for (int k = cg; k < 128; k += 8) {
    t1[nl][k] = d_bc[((size_t)(b*NP + n0 + nl))*KK + k];
    t2[nl][k] = d_bs[((size_t)(b*NP + n0 + nl))*KK + k];
  }
  __syncthreads();
  int kl = threadIdx.x & 127;
  int nr = threadIdx.x >> 7;
  float* bcT = d_stack + (size_t)(b*KR + 0)*NP;
  float* bsT = d_stack + (size_t)(b*KR + 128)*NP;
  for (int nn = nr; nn < 32; nn += 2) {
    bcT[(size_t)kl*NP + n0 + nn] = t1[nn][kl];
    bsT[(size_t)kl*NP + n0 + nn] = t2[nn][kl];
  }
}

// ---- fc0 -> stack h rows ----
__global__ __launch_bounds__(256) void k_h0(const float* __restrict__ x,
                                            const float* __restrict__ t,
                                            const float* __restrict__ w,
                                            const float* __restrict__ bias) {
  int tid = blockIdx.x*256 + threadIdx.x;
  int n = tid % NN;
  int bc_ = tid / NN;
  int c = bc_ % CC;
  int b = bc_ / CC;
  const float* xv = x + (b*NN + n)*3;
  float acc = bias[c] + xv[0]*w[c] + xv[1]*w[CC+c] + xv[2]*w[2*CC+c]
            + t[b*NN+n]*w[3*CC+c];
  d_stack[(size_t)(b*KR + 256 + c)*NP + n] = acc;
}

__global__ __launch_bounds__(256) void k_zero_gacc() {
  int tid = blockIdx.x*256 + threadIdx.x;
  reinterpret_cast<float4*>(d_gacc)[tid] = make_float4(0.f,0.f,0.f,0.f);
}

// ---- transpose h -> hT [n][c] and hTw = hT*nw ----
__global__ __launch_bounds__(256) void k_transpose() {
  __shared__ float tile[32][129];
  int blk = blockIdx.x;
  int nt = blk % 625;
  int b  = blk / 625;
  int n0 = nt*32;
  int nl = threadIdx.x & 31;
  int cg = threadIdx.x >> 5;
  const float* h = d_stack + (size_t)(b*KR + 256)*NP;
  for (int c = cg; c < 128; c += 8)
    tile[nl][c] = h[(size_t)c*NP + n0 + nl];
  __syncthreads();
  int cl = threadIdx.x & 127;
  int nr = threadIdx.x >> 7;
  for (int nn = nr; nn < 32; nn += 2) {
    float v = tile[nn][cl];
    float nwv = d_nw[b*NN + n0 + nn];
    d_hT[((size_t)(b*NN + n0 + nn))*CC + cl] = v;
    d_hTw[((size_t)(b*NP + n0 + nn))*CC + cl] = v*nwv;
  }
}

// ---- gemm1 v2: split-k tiled GEMM ----
// xc[c,k] = sum_n hTw[n,c]*bc[n,k] ; xs[c,k] = -sum_n hTw[n,c]*bs[n,k]
__global__ __launch_bounds__(256) void k_gemm1() {
  __shared__ float As[16][64];
  __shared__ float Bc[16][128];
  __shared__ float Bs[16][128];
  int chunk = blockIdx.x;        // 157
  int half  = blockIdx.y;        // c half
  int b     = blockIdx.z;
  int tid = threadIdx.x;
  int tk = tid & 15;             // k0 = tk*8
  int tc = tid >> 4;             // c0 = tc*4
  float accC[4][8], accS[4][8];
  #pragma unroll
  for (int i = 0; i < 4; i++)
    #pragma unroll
    for (int j = 0; j < 8; j++) { accC[i][j] = 0.f; accS[i][j] = 0.f; }
  int n0 = chunk*128;
  for (int s = 0; s < 8; s++) {
    int nb = n0 + s*16;
    __syncthreads();
    {
      int r = tid >> 4, c4 = (tid & 15)*4;
      *(float4*)&As[r][c4] = *(const float4*)&d_hTw[((size_t)(b*NP + nb + r))*CC + half*64 + c4];
    }
    #pragma unroll
    for (int i = 0; i < 2; i++) {
      int idx = tid + i*256;
      int r = idx >> 5, k4 = (idx & 31)*4;
      *(float4*)&Bc[r][k4] = *(const float4*)&d_bc[((size_t)(b*NP + nb + r))*KK + k4];
      *(float4*)&Bs[r][k4] = *(const float4*)&d_bs[((size_t)(b*NP + nb + r))*KK + k4];
    }
    __syncthreads();
    #pragma unroll
    for (int kk = 0; kk < 16; kk++) {
      float4 a4  = *(float4*)&As[kk][tc*4];
      float4 c4a = *(float4*)&Bc[kk][tk*8];
      float4 c4b = *(float4*)&Bc[kk][tk*8+4];
      float4 s4a = *(float4*)&Bs[kk][tk*8];
      float4 s4b = *(float4*)&Bs[kk][tk*8+4];
      float av[4] = {a4.x, a4.y, a4.z, a4.w};
      float cv[8] = {c4a.x,c4a.y,c4a.z,c4a.w,c4b.x,c4b.y,c4b.z,c4b.w};
      float sv[8] = {s4a.x,s4a.y,s4a.z,s4a.w,s4b.x,s4b.y,s4b.z,s4b.w};
      #pragma unroll
      for (int i = 0; i < 4; i++)
        #pragma unroll
        for (int j = 0; j < 8; j++) {
          accC[i][j] += av[i]*cv[j];
          accS[i][j] -= av[i]*sv[j];
        }
    }
  }
  float* base = d_part + (size_t)((b*2 + half)*NCHK + chunk)*2*8192;
  #pragma unroll
  for (int i = 0; i < 4; i++) {
    int row = tc*4 + i;
    *(float4*)&base[row*128 + tk*8]     = make_float4(accC[i][0],accC[i][1],accC[i][2],accC[i][3]);
    *(float4*)&base[row*128 + tk*8 + 4] = make_float4(accC[i][4],accC[i][5],accC[i][6],accC[i][7]);
    *(float4*)&base[8192 + row*128 + tk*8]     = make_float4(accS[i][0],accS[i][1],accS[i][2],accS[i][3]);
    *(float4*)&base[8192 + row*128 + tk*8 + 4] = make_float4(accS[i][4],accS[i][5],accS[i][6],accS[i][7]);
  }
}

// ---- reduce split-k partials -> xc, xs ----
__global__ __launch_bounds__(256) void k_reduce1() {
  int tid = blockIdx.x*256 + threadIdx.x;   // ((b*2+arr)*128 + c)*128 + k, 65536 total
  int k = tid & 127;
  int rest = tid >> 7;
  int c = rest & 127;
  int ba = rest >> 7;
  int arr = ba & 1, b = ba >> 1;
  int half = c >> 6, cl = c & 63;
  const float* p = d_part + ((size_t)(b*2 + half)*NCHK*2 + arr)*8192 + cl*128 + k;
  float acc = 0.f;
  for (int ch = 0; ch < NCHK; ch++) acc += p[(size_t)ch*16384];
  if (arr == 0) d_xc[(b*CC + c)*KK + k] = acc;
  else          d_xs[(b*CC + c)*KK + k] = acc;
}

// ---- x0[b,c] = sum_n h[b,c,n]*nw ----
__global__ __launch_bounds__(256) void k_x0() {
  int b = blockIdx.x >> 7, c = blockIdx.x & 127;
  const float* hp  = d_stack + (size_t)(b*KR + 256 + c)*NP;
  const float* nwp = d_nw + b*NN;
  float acc = 0.f;
  for (int n = threadIdx.x; n < NN; n += 256) acc += hp[n]*nwp[n];
  __shared__ float red[256];
  red[threadIdx.x] = acc;
  __syncthreads();
  for (int s = 128; s > 0; s >>= 1) {
    if (threadIdx.x < s) red[threadIdx.x] += red[threadIdx.x + s];
    __syncthreads();
  }
  if (threadIdx.x == 0) d_x0v[blockIdx.x] = red[0];
}

// ---- spectral mix per k ----
__global__ __launch_bounds__(128) void k_spec(const float* __restrict__ Wc,
                                              const float* __restrict__ Ws, int l) {
  int b = blockIdx.x >> 7;
  int o = blockIdx.x & 127;
  int k = threadIdx.x;
  const float* wcp = Wc + ((size_t)(l*CC)*CC + o)*KK + k;
  const float* wsp = Ws + ((size_t)(l*CC)*CC + o)*KK + k;
  float fc = 0.f, fs = 0.f;
  for (int i = 0; i < CC; i++) {
    float xcv = d_xc[(b*CC + i)*KK + k];
    float xsv = d_xs[(b*CC + i)*KK + k];
    float wcv = wcp[(size_t)i*CC*KK];
    float wsv = wsp[(size_t)i*CC*KK];
    fc += xcv*wcv - xsv*wsv;
    fs += xsv*wcv + xcv*wsv;
  }
  d_fcv[(b*CC + o)*KK + k] = fc;
  d_fsv[(b*CC + o)*KK + k] = fs;
}

// ---- f0 + full bias ----
__global__ __launch_bounds__(128) void k_f0(const float* __restrict__ W0,
                                            const float* __restrict__ wsb,
                                            const float* __restrict__ gwsb, int l) {
  int b = blockIdx.x;
  int o = threadIdx.x;
  float acc = 0.f;
  for (int i = 0; i < CC; i++) acc += d_x0v[b*CC + i]*W0[(l*CC + i)*CC + o];
  d_bias[b*CC + o] = acc + wsb[l*CC + o] + gwsb[l*CC + o];
}

// ---- build A matrix [b][r][o] ----
__global__ __launch_bounds__(128) void k_buildA(const float* __restrict__ wsw,
                                                const float* __restrict__ gwsw, int l) {
  int br = blockIdx.x;
  int b = br / KR;
  int r = br % KR;
  int o = threadIdx.x;
  float v;
  if (r < 128)       v =  2.f*d_fcv[(b*CC + o)*KK + r];
  else if (r < 256)  v = -2.f*d_fsv[(b*CC + o)*KK + (r-128)];
  else if (r < 384)  v = wsw[(l*CC + o)*CC + (r-256)];
  else               v = gwsw[(l*CC + o)*GJ + (r-384)];
  d_Amat[(b*KR + r)*CC + o] = v;
}

// ---- edge gradient: atomic segment-sum over src ----
__global__ __launch_bounds__(256) void k_grad(const int* __restrict__ edges,
                                              const float* __restrict__ egw) {
  int idx2 = blockIdx.x*2 + (threadIdx.x >> 7);
  int c = threadIdx.x & 127;
  int b = idx2 / EE;
  int e = idx2 % EE;
  int src = edges[(b*EE + e)*2 + 0];
  int dst = edges[(b*EE + e)*2 + 1];
  float diff = d_hT[((size_t)(b*NN + dst))*CC + c] - d_hT[((size_t)(b*NN + src))*CC + c];
  float w0 = egw[(b*EE + e)*3 + 0];
  float w1 = egw[(b*EE + e)*3 + 1];
  float w2 = egw[(b*EE + e)*3 + 2];
  float* gp = d_gacc + (size_t)(b*NN + src)*GJ;
  atomicAdd(&gp[0*CC + c], w0*diff);
  atomicAdd(&gp[1*CC + c], w1*diff);
  atomicAdd(&gp[2*CC + c], w2*diff);
}

// ---- g rows of stack ----
__global__ __launch_bounds__(256) void k_gnorm() {
  __shared__ float tile[32][129];
  int blk = blockIdx.x;
  int jt = blk % 3;
  int nt = (blk/3) % 625;
  int b  = blk / (3*625);
  int n0 = nt*32;
  int jl = threadIdx.x & 127;
  int ng = threadIdx.x >> 7;
  for (int nn = ng; nn < 32; nn += 2)
    tile[nn][jl] = d_gacc[(size_t)(b*NN + n0 + nn)*GJ + jt*128 + jl];
  __syncthreads();
  int nl = threadIdx.x & 31;
  int jg = threadIdx.x >> 5;
  float* grow = d_stack + (size_t)(b*KR + 384 + jt*128)*NP;
  for (int jj = jg; jj < 128; jj += 8) {
    float v = tile[nl][jj];
    grow[(size_t)jj*NP + n0 + nl] = v/(1.f + fabsf(v));
  }
}

// ---- big tiled GEMM: C[b][o][n] = sum_r A[b][r][o]*B[b][r][n] + bias ----
__global__ __launch_bounds__(256) void k_gemm_big(const float* __restrict__ A, size_t asb,
                                                  const float* __restrict__ Bm, size_t bsb,
                                                  float* __restrict__ Cm, size_t csb,
                                                  int K,
                                                  const float* __restrict__ bias, int bias_sb,
                                                  int gelu) {
  __shared__ float As[KCH][OTILE];
  __shared__ float Bs[KCH][NTILE];
  int b = blockIdx.z;
  const float* Ab = A + asb*b;
  const float* Bb = Bm + bsb*b;
  int o_base = blockIdx.y*OTILE;
  int n_base = blockIdx.x*NTILE;
  int tid = threadIdx.x;
  int tn = tid & 15;
  int to = tid >> 4;
  float acc[4][8];
  #pragma unroll
  for (int i = 0; i < 4; i++)
    #pragma unroll
    for (int j = 0; j < 8; j++) acc[i][j] = 0.f;

  for (int k0 = 0; k0 < K; k0 += KCH) {
    __syncthreads();
    #pragma unroll
    for (int i = 0; i < 2; i++) {
      int idx = tid + i*256;
      int r = idx >> 4;
      int c4 = (idx & 15)*4;
      *(float4*)&As[r][c4] = *(const float4*)&Ab[(size_t)(k0+r)*128 + o_base + c4];
    }
    #pragma unroll
    for (int i = 0; i < 4; i++) {
      int idx = tid + i*256;
      int r = idx >> 5;
      int c4 = (idx & 31)*4;
      *(float4*)&Bs[r][c4] = *(const float4*)&Bb[(size_t)(k0+r)*NP + n_base + c4];
    }
    __syncthreads();
    #pragma unroll 8
    for (int kk = 0; kk < KCH; kk++) {
      float4 a4 = *(float4*)&As[kk][to*4];
      float4 b4a = *(float4*)&Bs[kk][tn*8];
      float4 b4b = *(float4*)&Bs[kk][tn*8+4];
      float av[4] = {a4.x, a4.y, a4.z, a4.w};
      float bv[8] = {b4a.x, b4a.y, b4a.z, b4a.w, b4b.x, b4b.y, b4b.z, b4b.w};
      #pragma unroll
      for (int i = 0; i < 4; i++)
        #pragma unroll
        for (int j = 0; j < 8; j++)
          acc[i][j] += av[i]*bv[j];
    }
  }
  const float* bp = bias + (size_t)bias_sb*b;
  #pragma unroll
  for (int i = 0; i < 4; i++) {
    int o = o_base + to*4 + i;
    float bvv = bp[o];
    float vals[8];
    #pragma unroll
    for (int j = 0; j < 8; j++) {
      float r = acc[i][j] + bvv;
      if (gelu) r = 0.5f*r*(1.f + erff(r*0.70710678118f));
      vals[j] = r;
    }
    int n0 = n_base + tn*8;
    float* crow = Cm + csb*b + (size_t)o*NP;
    if (n0 < NN)     *(float4*)&crow[n0]   = make_float4(vals[0],vals[1],vals[2],vals[3]);
    if (n0+4 < NN)   *(float4*)&crow[n0+4] = make_float4(vals[4],vals[5],vals[6],vals[7]);
  }
}

// ---- copy hnew -> stack h rows ----
__global__ __launch_bounds__(256) void k_copy_h() {
  size_t tid = (size_t)blockIdx.x*256 + threadIdx.x;
  size_t bc_ = tid / NP;
  size_t n = tid % NP;
  size_t b = bc_ / CC, c = bc_ % CC;
  d_stack[((b*KR + 256 + c))*(size_t)NP + n] = d_hnew[tid];
}

// ---- fc2 + residual ----
__global__ __launch_bounds__(256) void k_out(const float* __restrict__ x,
                                             const float* __restrict__ t,
                                             const float* __restrict__ fc2w,
                                             const float* __restrict__ fc2b,
                                             float* __restrict__ out) {
  int tid = blockIdx.x*256 + threadIdx.x;
  if (tid >= BB*NN) return;
  int b = tid / NN, n = tid % NN;
  const float* up = d_hnew + (size_t)b*CC*NP + n;
  float a0 = fc2b[0], a1 = fc2b[1], a2v = fc2b[2];
  #pragma unroll 8
  for (int o2 = 0; o2 < FCC; o2++) {
    float uv = up[(size_t)o2*NP];
    a0  += uv*fc2w[o2*3 + 0];
    a1  += uv*fc2w[o2*3 + 1];
    a2v += uv*fc2w[o2*3 + 2];
  }
  float tv = t[tid];
  out[tid*3 + 0] = x[tid*3 + 0] + tv*a0;
  out[tid*3 + 1] = x[tid*3 + 1] + tv*a1;
  out[tid*3 + 2] = x[tid*3 + 2] + tv*a2v;
}

extern "C" void kernel_launch(void* const* d_in, const int* in_sizes, int n_in,
                              void* d_out, int out_size, void* d_ws, size_t ws_size,
                              hipStream_t stream) {
  const float* x     = (const float*)d_in[0];
  const float* t     = (const float*)d_in[1];
  const float* nodes = (const float*)d_in[3];
  const float* nodew = (const float*)d_in[4];
  const int*   edges = (const int*)d_in[5];
  const float* egw   = (const float*)d_in[6];
  const float* modes = (const float*)d_in[7];
  const float* spL   = (const float*)d_in[8];
  const float* fc0w  = (const float*)d_in[9];
  const float* fc0b  = (const float*)d_in[10];
  const float* Wc    = (const float*)d_in[11];
  const float* Ws    = (const float*)d_in[12];
  const float* W0    = (const float*)d_in[13];
  const float* wsw   = (const float*)d_in[14];
  const float* wsb   = (const float*)d_in[15];
  const float* gwsw  = (const float*)d_in[16];
  const float* gwsb  = (const float*)d_in[17];
  const float* fc1w  = (const float*)d_in[18];
  const float* fc1b  = (const float*)d_in[19];
  const float* fc2w  = (const float*)d_in[20];
  const float* fc2b  = (const float*)d_in[21];
  float* out = (float*)d_out;

  float* d_stack_p; hipGetSymbolAddress((void**)&d_stack_p, HIP_SYMBOL(d_stack));
  float* d_Amat_p;  hipGetSymbolAddress((void**)&d_Amat_p,  HIP_SYMBOL(d_Amat));
  float* d_hnew_p;  hipGetSymbolAddress((void**)&d_hnew_p,  HIP_SYMBOL(d_hnew));
  float* d_bias_p;  hipGetSymbolAddress((void**)&d_bias_p,  HIP_SYMBOL(d_bias));

  hipLaunchKernelGGL(k_basis, dim3(BB*NN), dim3(128), 0, stream, nodes, nodew, modes, spL);
  hipLaunchKernelGGL(k_zero_pad, dim3(288), dim3(256), 0, stream);
  hipLaunchKernelGGL(k_basisT, dim3(BB*625), dim3(256), 0, stream);
  hipLaunchKernelGGL(k_h0, dim3(BB*CC*NN/256), dim3(256), 0, stream, x, t, fc0w, fc0b);

  for (int l = 0; l < LL; l++) {
    if (l > 0)
      hipLaunchKernelGGL(k_copy_h, dim3((unsigned)((size_t)BB*CC*NP/256)), dim3(256), 0, stream);
    hipLaunchKernelGGL(k_transpose, dim3(BB*625), dim3(256), 0, stream);
    hipLaunchKernelGGL(k_gemm1, dim3(NCHK, 2, BB), dim3(256), 0, stream);
    hipLaunchKernelGGL(k_reduce1, dim3(256), dim3(256), 0, stream);
    hipLaunchKernelGGL(k_x0, dim3(BB*CC), dim3(256), 0, stream);
    hipLaunchKernelGGL(k_spec, dim3(BB*CC), dim3(128), 0, stream, Wc, Ws, l);
    hipLaunchKernelGGL(k_f0, dim3(BB), dim3(CC), 0, stream, W0, wsb, gwsb, l);
    hipLaunchKernelGGL(k_buildA, dim3(BB*KR), dim3(128), 0, stream, wsw, gwsw, l);
    hipLaunchKernelGGL(k_zero_gacc, dim3((unsigned)((size_t)BB*NN*GJ/4/256)), dim3(256), 0, stream);
    hipLaunchKernelGGL(k_grad, dim3(BB*EE/2), dim3(256), 0, stream, edges, egw);
    hipLaunchKernelGGL(k_gnorm, dim3(BB*625*3), dim3(256), 0, stream);
    hipLaunchKernelGGL(k_gemm_big, dim3(157, CC/OTILE, BB), dim3(256), 0, stream,
                       d_Amat_p, (size_t)KR*CC, d_stack_p, (size_t)KR*NP,
                       d_hnew_p, (size_t)CC*NP, KR, d_bias_p, CC, (l != LL-1) ? 1 : 0);
  }

  hipLaunchKernelGGL(k_copy_h, dim3((unsigned)((size_t)BB*CC*NP/256)), dim3(256), 0, stream);
  hipLaunchKernelGGL(k_gemm_big, dim3(157, FCC/OTILE, BB), dim3(256), 0, stream,
                     fc1w, (size_t)0,
                     d_stack_p + (size_t)256*NP, (size_t)KR*NP,
                     d_hnew_p, (size_t)FCC*NP, CC, fc1b, 0, 1);
  hipLaunchKernelGGL(k_out, dim3((BB*NN + 255)/256), dim3(256), 0, stream, x, t, fc2w, fc2b, out);
}

// Round 4
// 1266.315 us; speedup vs baseline: 12.0275x; 1.5378x over previous
//
#include <hip/hip_runtime.h>
#include <math.h>

#define BB 2
#define NN 20000
#define EE 100000
#define DD 3
#define KK 128
#define CC 128
#define LL 3
#define FCC 128
#define GJ (DD*CC)    // 384
#define KR 768        // stacked contraction: 128 bc + 128 bs + 128 h + 384 g
#define NP 20096      // padded N: 157 tiles * 128
#define NTILE 128
#define OTILE 64
#define KCH 32
#define NCHK 157      // split-k chunks for gemm1 (128 n each)

// ---- scratch (device globals) ----
__device__ __align__(16) float d_bc[(size_t)BB*NP*KK];   // [b][n][k], padded rows
__device__ __align__(16) float d_bs[(size_t)BB*NP*KK];
__device__ float d_nw[BB*NN];
__device__ __align__(16) float d_stack[(size_t)BB*KR*NP];  // rows: 0 bcT,128 bsT,256 h,384 g
__device__ __align__(16) float d_hnew[(size_t)BB*CC*NP];
__device__ __align__(16) float d_hT[(size_t)BB*NN*CC];     // [b][n][c] unweighted
__device__ __align__(16) float d_hTw[(size_t)BB*NP*CC];    // [b][n][c] * nw, zero-padded
__device__ __align__(16) float d_gacc[(size_t)BB*NN*GJ];
__device__ __align__(16) float d_Amat[BB*KR*CC];
__device__ __align__(16) float d_part[(size_t)BB*2*NCHK*2*64*128];
__device__ float d_xc[BB*CC*KK];
__device__ float d_xs[BB*CC*KK];
__device__ float d_x0v[BB*CC];
__device__ float d_fcv[BB*CC*KK];
__device__ float d_fsv[BB*CC*KK];
__device__ float d_bias[BB*CC];
// CSR for edge gradient (built once per call)
__device__ int d_cnt[BB*NN];
__device__ int d_cursor[BB*NN];
__device__ int d_off[BB*(NN+1)];
__device__ int d_eidx[BB*EE];

// ---- basis ----
__global__ __launch_bounds__(128) void k_basis(const float* __restrict__ nodes,
                                               const float* __restrict__ nodew,
                                               const float* __restrict__ modes,
                                               const float* __restrict__ spL) {
  int bn = blockIdx.x;            // b*NN + n
  int k  = threadIdx.x;
  int b = bn / NN, n = bn % NN;
  float x0 = nodes[bn*3+0], x1 = nodes[bn*3+1], x2 = nodes[bn*3+2];
  float tmp = x0*modes[k*3+0]*spL[0] + x1*modes[k*3+1]*spL[1] + x2*modes[k*3+2]*spL[2];
  d_bc[((size_t)(b*NP + n))*KK + k] = cosf(tmp);
  d_bs[((size_t)(b*NP + n))*KK + k] = sinf(tmp);
  if (k == 0) d_nw[bn] = nodew[bn];
}

// ---- zero pads of bc/bs/hTw rows [NN,NP) ----
__global__ __launch_bounds__(256) void k_zero_pad() {
  int tid = blockIdx.x*256 + threadIdx.x;
  int arr = tid / 24576;
  int rem = tid % 24576;
  int b = rem / 12288;
  int r = rem % 12288;
  int n = NN + r/128;
  int k = r % 128;
  size_t idx = ((size_t)(b*NP + n))*128 + k;
  if (arr == 0) d_bc[idx] = 0.f;
  else if (arr == 1) d_bs[idx] = 0.f;
  else d_hTw[idx] = 0.f;
}

// ---- CSR build: count / scan / scatter ----
__global__ __launch_bounds__(256) void k_csr_zero() {
  int tid = blockIdx.x*256 + threadIdx.x;   // BB*NN
  if (tid < BB*NN) { d_cnt[tid] = 0; d_cursor[tid] = 0; }
}

__global__ __launch_bounds__(256) void k_csr_count(const int* __restrict__ edges) {
  int e = blockIdx.x*256 + threadIdx.x;     // BB*EE
  if (e >= BB*EE) return;
  int b = e / EE;
  int src = edges[e*2 + 0];
  atomicAdd(&d_cnt[b*NN + src], 1);
}

__global__ __launch_bounds__(1024) void k_csr_scan() {
  int b = blockIdx.x;
  __shared__ int sdata[1024];
  __shared__ int carry_s;
  int tid = threadIdx.x;
  if (tid == 0) carry_s = 0;
  __syncthreads();
  for (int chunk = 0; chunk < 20; ++chunk) {
    int i = chunk*1024 + tid;
    int v = (i < NN) ? d_cnt[b*NN + i] : 0;
    sdata[tid] = v;
    __syncthreads();
    for (int s = 1; s < 1024; s <<= 1) {
      int tv = (tid >= s) ? sdata[tid - s] : 0;
      __syncthreads();
      sdata[tid] += tv;
      __syncthreads();
    }
    int excl = carry_s + sdata[tid] - v;
    if (i < NN) d_off[b*(NN+1) + i] = excl;
    __syncthreads();
    if (tid == 1023) carry_s += sdata[1023];
    __syncthreads();
  }
  if (tid == 0) d_off[b*(NN+1) + NN] = carry_s;
}

__global__ __launch_bounds__(256) void k_csr_scatter(const int* __restrict__ edges) {
  int e = blockIdx.x*256 + threadIdx.x;     // BB*EE
  if (e >= BB*EE) return;
  int b = e / EE, ee = e % EE;
  int src = edges[e*2 + 0];
  int pos = atomicAdd(&d_cursor[b*NN + src], 1);
  d_eidx[b*EE + d_off[b*(NN+1) + src] + pos] = ee;
}

// ---- transpose bc/bs [n][k] -> stack rows [k][n] (once) ----
__global__ __launch_bounds__(256) void k_basisT() {
  __shared__ float t1[32][129];
  __shared__ float t2[32][129];
  int blk = blockIdx.x;
  int nt = blk % 625;
  int b  = blk / 625;
  int n0 = nt*32;
  int nl = threadIdx.x & 31;
  int cg = threadIdx.x >> 5;
  for (int k = cg; k < 128; k += 8) {
    t1[nl][k] = d_bc[((size_t)(b*NP + n0 + nl))*KK + k];
    t2[nl][k] = d_bs[((size_t)(b*NP + n0 + nl))*KK + k];
  }
  __syncthreads();
  int kl = threadIdx.x & 127;
  int nr = threadIdx.x >> 7;
  float* bcT = d_stack + (size_t)(b*KR + 0)*NP;
  float* bsT = d_stack + (size_t)(b*KR + 128)*NP;
  for (int nn = nr; nn < 32; nn += 2) {
    bcT[(size_t)kl*NP + n0 + nn] = t1[nn][kl];
    bsT[(size_t)kl*NP + n0 + nn] = t2[nn][kl];
  }
}

// ---- fc0 -> stack h rows ----
__global__ __launch_bounds__(256) void k_h0(const float* __restrict__ x,
                                            const float* __restrict__ t,
                                            const float* __restrict__ w,
                                            const float* __restrict__ bias) {
  int tid = blockIdx.x*256 + threadIdx.x;
  int n = tid % NN;
  int bc_ = tid / NN;
  int c = bc_ % CC;
  int b = bc_ / CC;
  const float* xv = x + (b*NN + n)*3;
  float acc = bias[c] + xv[0]*w[c] + xv[1]*w[CC+c] + xv[2]*w[2*CC+c]
            + t[b*NN+n]*w[3*CC+c];
  d_stack[(size_t)(b*KR + 256 + c)*NP + n] = acc;
}

// ---- transpose h -> hT [n][c] and hTw = hT*nw ----
__global__ __launch_bounds__(256) void k_transpose() {
  __shared__ float tile[32][129];
  int blk = blockIdx.x;
  int nt = blk % 625;
  int b  = blk / 625;
  int n0 = nt*32;
  int nl = threadIdx.x & 31;
  int cg = threadIdx.x >> 5;
  const float* h = d_stack + (size_t)(b*KR + 256)*NP;
  for (int c = cg; c < 128; c += 8)
    tile[nl][c] = h[(size_t)c*NP + n0 + nl];
  __syncthreads();
  int cl = threadIdx.x & 127;
  int nr = threadIdx.x >> 7;
  for (int nn = nr; nn < 32; nn += 2) {
    float v = tile[nn][cl];
    float nwv = d_nw[b*NN + n0 + nn];
    d_hT[((size_t)(b*NN + n0 + nn))*CC + cl] = v;
    d_hTw[((size_t)(b*NP + n0 + nn))*CC + cl] = v*nwv;
  }
}

// ---- gemm1: split-k tiled GEMM ----
__global__ __launch_bounds__(256) void k_gemm1() {
  __shared__ float As[16][64];
  __shared__ float Bc[16][128];
  __shared__ float Bs[16][128];
  int chunk = blockIdx.x;
  int half  = blockIdx.y;
  int b     = blockIdx.z;
  int tid = threadIdx.x;
  int tk = tid & 15;
  int tc = tid >> 4;
  float accC[4][8], accS[4][8];
  #pragma unroll
  for (int i = 0; i < 4; i++)
    #pragma unroll
    for (int j = 0; j < 8; j++) { accC[i][j] = 0.f; accS[i][j] = 0.f; }
  int n0 = chunk*128;
  for (int s = 0; s < 8; s++) {
    int nb = n0 + s*16;
    __syncthreads();
    {
      int r = tid >> 4, c4 = (tid & 15)*4;
      *(float4*)&As[r][c4] = *(const float4*)&d_hTw[((size_t)(b*NP + nb + r))*CC + half*64 + c4];
    }
    #pragma unroll
    for (int i = 0; i < 2; i++) {
      int idx = tid + i*256;
      int r = idx >> 5, k4 = (idx & 31)*4;
      *(float4*)&Bc[r][k4] = *(const float4*)&d_bc[((size_t)(b*NP + nb + r))*KK + k4];
      *(float4*)&Bs[r][k4] = *(const float4*)&d_bs[((size_t)(b*NP + nb + r))*KK + k4];
    }
    __syncthreads();
    #pragma unroll
    for (int kk = 0; kk < 16; kk++) {
      float4 a4  = *(float4*)&As[kk][tc*4];
      float4 c4a = *(float4*)&Bc[kk][tk*8];
      float4 c4b = *(float4*)&Bc[kk][tk*8+4];
      float4 s4a = *(float4*)&Bs[kk][tk*8];
      float4 s4b = *(float4*)&Bs[kk][tk*8+4];
      float av[4] = {a4.x, a4.y, a4.z, a4.w};
      float cv[8] = {c4a.x,c4a.y,c4a.z,c4a.w,c4b.x,c4b.y,c4b.z,c4b.w};
      float sv[8] = {s4a.x,s4a.y,s4a.z,s4a.w,s4b.x,s4b.y,s4b.z,s4b.w};
      #pragma unroll
      for (int i = 0; i < 4; i++)
        #pragma unroll
        for (int j = 0; j < 8; j++) {
          accC[i][j] += av[i]*cv[j];
          accS[i][j] -= av[i]*sv[j];
        }
    }
  }
  float* base = d_part + (size_t)((b*2 + half)*NCHK + chunk)*2*8192;
  #pragma unroll
  for (int i = 0; i < 4; i++) {
    int row = tc*4 + i;
    *(float4*)&base[row*128 + tk*8]     = make_float4(accC[i][0],accC[i][1],accC[i][2],accC[i][3]);
    *(float4*)&base[row*128 + tk*8 + 4] = make_float4(accC[i][4],accC[i][5],accC[i][6],accC[i][7]);
    *(float4*)&base[8192 + row*128 + tk*8]     = make_float4(accS[i][0],accS[i][1],accS[i][2],accS[i][3]);
    *(float4*)&base[8192 + row*128 + tk*8 + 4] = make_float4(accS[i][4],accS[i][5],accS[i][6],accS[i][7]);
  }
}

// ---- reduce split-k partials -> xc, xs ----
__global__ __launch_bounds__(256) void k_reduce1() {
  int tid = blockIdx.x*256 + threadIdx.x;
  int k = tid & 127;
  int rest = tid >> 7;
  int c = rest & 127;
  int ba = rest >> 7;
  int arr = ba & 1, b = ba >> 1;
  int half = c >> 6, cl = c & 63;
  const float* p = d_part + ((size_t)(b*2 + half)*NCHK*2 + arr)*8192 + cl*128 + k;
  float acc = 0.f;
  for (int ch = 0; ch < NCHK; ch++) acc += p[(size_t)ch*16384];
  if (arr == 0) d_xc[(b*CC + c)*KK + k] = acc;
  else          d_xs[(b*CC + c)*KK + k] = acc;
}

// ---- x0[b,c] = sum_n h[b,c,n]*nw ----
__global__ __launch_bounds__(256) void k_x0() {
  int b = blockIdx.x >> 7, c = blockIdx.x & 127;
  const float* hp  = d_stack + (size_t)(b*KR + 256 + c)*NP;
  const float* nwp = d_nw + b*NN;
  float acc = 0.f;
  for (int n = threadIdx.x; n < NN; n += 256) acc += hp[n]*nwp[n];
  __shared__ float red[256];
  red[threadIdx.x] = acc;
  __syncthreads();
  for (int s = 128; s > 0; s >>= 1) {
    if (threadIdx.x < s) red[threadIdx.x] += red[threadIdx.x + s];
    __syncthreads();
  }
  if (threadIdx.x == 0) d_x0v[blockIdx.x] = red[0];
}

// ---- spectral mix per k ----
__global__ __launch_bounds__(128) void k_spec(const float* __restrict__ Wc,
                                              const float* __restrict__ Ws, int l) {
  int b = blockIdx.x >> 7;
  int o = blockIdx.x & 127;
  int k = threadIdx.x;
  const float* wcp = Wc + ((size_t)(l*CC)*CC + o)*KK + k;
  const float* wsp = Ws + ((size_t)(l*CC)*CC + o)*KK + k;
  float fc = 0.f, fs = 0.f;
  for (int i = 0; i < CC; i++) {
    float xcv = d_xc[(b*CC + i)*KK + k];
    float xsv = d_xs[(b*CC + i)*KK + k];
    float wcv = wcp[(size_t)i*CC*KK];
    float wsv = wsp[(size_t)i*CC*KK];
    fc += xcv*wcv - xsv*wsv;
    fs += xsv*wcv + xcv*wsv;
  }
  d_fcv[(b*CC + o)*KK + k] = fc;
  d_fsv[(b*CC + o)*KK + k] = fs;
}

// ---- f0 + full bias ----
__global__ __launch_bounds__(128) void k_f0(const float* __restrict__ W0,
                                            const float* __restrict__ wsb,
                                            const float* __restrict__ gwsb, int l) {
  int b = blockIdx.x;
  int o = threadIdx.x;
  float acc = 0.f;
  for (int i = 0; i < CC; i++) acc += d_x0v[b*CC + i]*W0[(l*CC + i)*CC + o];
  d_bias[b*CC + o] = acc + wsb[l*CC + o] + gwsb[l*CC + o];
}

// ---- build A matrix [b][r][o] ----
__global__ __launch_bounds__(128) void k_buildA(const float* __restrict__ wsw,
                                                const float* __restrict__ gwsw, int l) {
  int br = blockIdx.x;
  int b = br / KR;
  int r = br % KR;
  int o = threadIdx.x;
  float v;
  if (r < 128)       v =  2.f*d_fcv[(b*CC + o)*KK + r];
  else if (r < 256)  v = -2.f*d_fsv[(b*CC + o)*KK + (r-128)];
  else if (r < 384)  v = wsw[(l*CC + o)*CC + (r-256)];
  else               v = gwsw[(l*CC + o)*GJ + (r-384)];
  d_Amat[(b*KR + r)*CC + o] = v;
}

// ---- CSR edge gradient: per-node gather, no atomics ----
// grad[n,d,c] = sum_{e in out(n)} egw[e,d]*f[dst_e,c] - (sum_e egw[e,d])*f[n,c]
__global__ __launch_bounds__(128) void k_grad_csr(const int* __restrict__ edges,
                                                  const float* __restrict__ egw) {
  int bn = blockIdx.x;            // b*NN + n
  int b = bn / NN, n = bn % NN;
  int c = threadIdx.x;
  int beg = d_off[b*(NN+1) + n];
  int end = d_off[b*(NN+1) + n + 1];
  float a0 = 0.f, a1 = 0.f, a2 = 0.f;
  float sw0 = 0.f, sw1 = 0.f, sw2 = 0.f;
  for (int p = beg; p < end; ++p) {
    int ee = d_eidx[b*EE + p];
    int dst = edges[(b*EE + ee)*2 + 1];
    float w0 = egw[(b*EE + ee)*3 + 0];
    float w1 = egw[(b*EE + ee)*3 + 1];
    float w2 = egw[(b*EE + ee)*3 + 2];
    float fv = d_hT[((size_t)(b*NN + dst))*CC + c];
    a0 += w0*fv; a1 += w1*fv; a2 += w2*fv;
    sw0 += w0; sw1 += w1; sw2 += w2;
  }
  float fs = d_hT[((size_t)bn)*CC + c];
  a0 -= sw0*fs; a1 -= sw1*fs; a2 -= sw2*fs;
  float* gp = d_gacc + (size_t)bn*GJ;
  gp[c]        = a0;
  gp[CC + c]   = a1;
  gp[2*CC + c] = a2;
}

// ---- g rows of stack ----
__global__ __launch_bounds__(256) void k_gnorm() {
  __shared__ float tile[32][129];
  int blk = blockIdx.x;
  int jt = blk % 3;
  int nt = (blk/3) % 625;
  int b  = blk / (3*625);
  int n0 = nt*32;
  int jl = threadIdx.x & 127;
  int ng = threadIdx.x >> 7;
  for (int nn = ng; nn < 32; nn += 2)
    tile[nn][jl] = d_gacc[(size_t)(b*NN + n0 + nn)*GJ + jt*128 + jl];
  __syncthreads();
  int nl = threadIdx.x & 31;
  int jg = threadIdx.x >> 5;
  float* grow = d_stack + (size_t)(b*KR + 384 + jt*128)*NP;
  for (int jj = jg; jj < 128; jj += 8) {
    float v = tile[nl][jj];
    grow[(size_t)jj*NP + n0 + nl] = v/(1.f + fabsf(v));
  }
}

// ---- big tiled GEMM: C[b][o][n] = sum_r A[b][r][o]*B[b][r][n] + bias ----
__global__ __launch_bounds__(256) void k_gemm_big(const float* __restrict__ A, size_t asb,
                                                  const float* __restrict__ Bm, size_t bsb,
                                                  float* __restrict__ Cm, size_t csb,
                                                  int K,
                                                  const float* __restrict__ bias, int bias_sb,
                                                  int gelu) {
  __shared__ float As[KCH][OTILE];
  __shared__ float Bs[KCH][NTILE];
  int b = blockIdx.z;
  const float* Ab = A + asb*b;
  const float* Bb = Bm + bsb*b;
  int o_base = blockIdx.y*OTILE;
  int n_base = blockIdx.x*NTILE;
  int tid = threadIdx.x;
  int tn = tid & 15;
  int to = tid >> 4;
  float acc[4][8];
  #pragma unroll
  for (int i = 0; i < 4; i++)
    #pragma unroll
    for (int j = 0; j < 8; j++) acc[i][j] = 0.f;

  for (int k0 = 0; k0 < K; k0 += KCH) {
    __syncthreads();
    #pragma unroll
    for (int i = 0; i < 2; i++) {
      int idx = tid + i*256;
      int r = idx >> 4;
      int c4 = (idx & 15)*4;
      *(float4*)&As[r][c4] = *(const float4*)&Ab[(size_t)(k0+r)*128 + o_base + c4];
    }
    #pragma unroll
    for (int i = 0; i < 4; i++) {
      int idx = tid + i*256;
      int r = idx >> 5;
      int c4 = (idx & 31)*4;
      *(float4*)&Bs[r][c4] = *(const float4*)&Bb[(size_t)(k0+r)*NP + n_base + c4];
    }
    __syncthreads();
    #pragma unroll 8
    for (int kk = 0; kk < KCH; kk++) {
      float4 a4 = *(float4*)&As[kk][to*4];
      float4 b4a = *(float4*)&Bs[kk][tn*8];
      float4 b4b = *(float4*)&Bs[kk][tn*8+4];
      float av[4] = {a4.x, a4.y, a4.z, a4.w};
      float bv[8] = {b4a.x, b4a.y, b4a.z, b4a.w, b4b.x, b4b.y, b4b.z, b4b.w};
      #pragma unroll
      for (int i = 0; i < 4; i++)
        #pragma unroll
        for (int j = 0; j < 8; j++)
          acc[i][j] += av[i]*bv[j];
    }
  }
  const float* bp = bias + (size_t)bias_sb*b;
  #pragma unroll
  for (int i = 0; i < 4; i++) {
    int o = o_base + to*4 + i;
    float bvv = bp[o];
    float vals[8];
    #pragma unroll
    for (int j = 0; j < 8; j++) {
      float r = acc[i][j] + bvv;
      if (gelu) r = 0.5f*r*(1.f + erff(r*0.70710678118f));
      vals[j] = r;
    }
    int n0 = n_base + tn*8;
    float* crow = Cm + csb*b + (size_t)o*NP;
    if (n0 < NN)     *(float4*)&crow[n0]   = make_float4(vals[0],vals[1],vals[2],vals[3]);
    if (n0+4 < NN)   *(float4*)&crow[n0+4] = make_float4(vals[4],vals[5],vals[6],vals[7]);
  }
}

// ---- copy hnew -> stack h rows ----
__global__ __launch_bounds__(256) void k_copy_h() {
  size_t tid = (size_t)blockIdx.x*256 + threadIdx.x;
  size_t bc_ = tid / NP;
  size_t n = tid % NP;
  size_t b = bc_ / CC, c = bc_ % CC;
  d_stack[((b*KR + 256 + c))*(size_t)NP + n] = d_hnew[tid];
}

// ---- fc2 + residual ----
__global__ __launch_bounds__(256) void k_out(const float* __restrict__ x,
                                             const float* __restrict__ t,
                                             const float* __restrict__ fc2w,
                                             const float* __restrict__ fc2b,
                                             float* __restrict__ out) {
  int tid = blockIdx.x*256 + threadIdx.x;
  if (tid >= BB*NN) return;
  int b = tid / NN, n = tid % NN;
  const float* up = d_hnew + (size_t)b*CC*NP + n;
  float a0 = fc2b[0], a1 = fc2b[1], a2v = fc2b[2];
  #pragma unroll 8
  for (int o2 = 0; o2 < FCC; o2++) {
    float uv = up[(size_t)o2*NP];
    a0  += uv*fc2w[o2*3 + 0];
    a1  += uv*fc2w[o2*3 + 1];
    a2v += uv*fc2w[o2*3 + 2];
  }
  float tv = t[tid];
  out[tid*3 + 0] = x[tid*3 + 0] + tv*a0;
  out[tid*3 + 1] = x[tid*3 + 1] + tv*a1;
  out[tid*3 + 2] = x[tid*3 + 2] + tv*a2v;
}

extern "C" void kernel_launch(void* const* d_in, const int* in_sizes, int n_in,
                              void* d_out, int out_size, void* d_ws, size_t ws_size,
                              hipStream_t stream) {
  const float* x     = (const float*)d_in[0];
  const float* t     = (const float*)d_in[1];
  const float* nodes = (const float*)d_in[3];
  const float* nodew = (const float*)d_in[4];
  const int*   edges = (const int*)d_in[5];
  const float* egw   = (const float*)d_in[6];
  const float* modes = (const float*)d_in[7];
  const float* spL   = (const float*)d_in[8];
  const float* fc0w  = (const float*)d_in[9];
  const float* fc0b  = (const float*)d_in[10];
  const float* Wc    = (const float*)d_in[11];
  const float* Ws    = (const float*)d_in[12];
  const float* W0    = (const float*)d_in[13];
  const float* wsw   = (const float*)d_in[14];
  const float* wsb   = (const float*)d_in[15];
  const float* gwsw  = (const float*)d_in[16];
  const float* gwsb  = (const float*)d_in[17];
  const float* fc1w  = (const float*)d_in[18];
  const float* fc1b  = (const float*)d_in[19];
  const float* fc2w  = (const float*)d_in[20];
  const float* fc2b  = (const float*)d_in[21];
  float* out = (float*)d_out;

  float* d_stack_p; hipGetSymbolAddress((void**)&d_stack_p, HIP_SYMBOL(d_stack));
  float* d_Amat_p;  hipGetSymbolAddress((void**)&d_Amat_p,  HIP_SYMBOL(d_Amat));
  float* d_hnew_p;  hipGetSymbolAddress((void**)&d_hnew_p,  HIP_SYMBOL(d_hnew));
  float* d_bias_p;  hipGetSymbolAddress((void**)&d_bias_p,  HIP_SYMBOL(d_bias));

  hipLaunchKernelGGL(k_basis, dim3(BB*NN), dim3(128), 0, stream, nodes, nodew, modes, spL);
  hipLaunchKernelGGL(k_zero_pad, dim3(288), dim3(256), 0, stream);
  hipLaunchKernelGGL(k_basisT, dim3(BB*625), dim3(256), 0, stream);
  hipLaunchKernelGGL(k_h0, dim3(BB*CC*NN/256), dim3(256), 0, stream, x, t, fc0w, fc0b);
  // CSR build (edges constant across layers)
  hipLaunchKernelGGL(k_csr_zero, dim3((BB*NN + 255)/256), dim3(256), 0, stream);
  hipLaunchKernelGGL(k_csr_count, dim3((BB*EE + 255)/256), dim3(256), 0, stream, edges);
  hipLaunchKernelGGL(k_csr_scan, dim3(BB), dim3(1024), 0, stream);
  hipLaunchKernelGGL(k_csr_scatter, dim3((BB*EE + 255)/256), dim3(256), 0, stream, edges);

  for (int l = 0; l < LL; l++) {
    if (l > 0)
      hipLaunchKernelGGL(k_copy_h, dim3((unsigned)((size_t)BB*CC*NP/256)), dim3(256), 0, stream);
    hipLaunchKernelGGL(k_transpose, dim3(BB*625), dim3(256), 0, stream);
    hipLaunchKernelGGL(k_gemm1, dim3(NCHK, 2, BB), dim3(256), 0, stream);
    hipLaunchKernelGGL(k_reduce1, dim3(256), dim3(256), 0, stream);
    hipLaunchKernelGGL(k_x0, dim3(BB*CC), dim3(256), 0, stream);
    hipLaunchKernelGGL(k_spec, dim3(BB*CC), dim3(128), 0, stream, Wc, Ws, l);
    hipLaunchKernelGGL(k_f0, dim3(BB), dim3(CC), 0, stream, W0, wsb, gwsb, l);
    hipLaunchKernelGGL(k_buildA, dim3(BB*KR), dim3(128), 0, stream, wsw, gwsw, l);
    hipLaunchKernelGGL(k_grad_csr, dim3(BB*NN), dim3(128), 0, stream, edges, egw);
    hipLaunchKernelGGL(k_gnorm, dim3(BB*625*3), dim3(256), 0, stream);
    hipLaunchKernelGGL(k_gemm_big, dim3(157, CC/OTILE, BB), dim3(256), 0, stream,
                       d_Amat_p, (size_t)KR*CC, d_stack_p, (size_t)KR*NP,
                       d_hnew_p, (size_t)CC*NP, KR, d_bias_p, CC, (l != LL-1) ? 1 : 0);
  }

  hipLaunchKernelGGL(k_copy_h, dim3((unsigned)((size_t)BB*CC*NP/256)), dim3(256), 0, stream);
  hipLaunchKernelGGL(k_gemm_big, dim3(157, FCC/OTILE, BB), dim3(256), 0, stream,
                     fc1w, (size_t)0,
                     d_stack_p + (size_t)256*NP, (size_t)KR*NP,
                     d_hnew_p, (size_t)FCC*NP, CC, fc1b, 0, 1);
  hipLaunchKernelGGL(k_out, dim3((BB*NN + 255)/256), dim3(256), 0, stream, x, t, fc2w, fc2b, out);
}

// Round 5
// 990.205 us; speedup vs baseline: 15.3813x; 1.2788x over previous
//
#include <hip/hip_runtime.h>
#include <math.h>

#define BB 2
#define NN 20000
#define EE 100000
#define DD 3
#define KK 128
#define CC 128
#define LL 3
#define FCC 128
#define GJ (DD*CC)    // 384
#define KR 768        // stacked contraction: 128 bc + 128 bs + 128 h + 384 g
#define NP 20096      // padded N: 157 tiles * 128
#define NCHK 157      // split-k chunks for gemm1 (128 n each)

typedef __attribute__((ext_vector_type(8))) short bf16x8;
typedef __attribute__((ext_vector_type(4))) float f32x4;

__device__ inline unsigned short f2bf(float f) {
  unsigned int u = __float_as_uint(f);
  u += 0x7fffu + ((u >> 16) & 1u);
  return (unsigned short)(u >> 16);
}

// ---- scratch (device globals) ----
__device__ __align__(16) float d_bc[(size_t)BB*NP*KK];      // [b][n][k] fp32 (gemm1)
__device__ __align__(16) float d_bs[(size_t)BB*NP*KK];
__device__ float d_nw[BB*NN];
__device__ __align__(16) unsigned short d_stackT[(size_t)BB*NP*KR]; // [b][n][r] bf16: 0 bc,128 bs,256 h,384 g
__device__ __align__(16) float d_hnewT[(size_t)BB*NP*CC];   // h [b][n][c] fp32
__device__ __align__(16) float d_uT[(size_t)BB*NP*FCC];     // fc1 out [b][n][o2]
__device__ __align__(16) float d_hTw[(size_t)BB*NP*CC];     // h*nw [b][n][c] fp32, pad-zeroed
__device__ __align__(16) unsigned short d_Amatb[BB*CC*KR];  // [b][o][r] bf16
__device__ __align__(16) unsigned short d_fc1wb[FCC*CC];    // [o2][c] bf16
__device__ __align__(16) float d_part[(size_t)BB*2*NCHK*2*64*128];
__device__ float d_xc[BB*CC*KK];
__device__ float d_xs[BB*CC*KK];
__device__ float d_x0p[BB*8*CC];
__device__ float d_fcv[BB*CC*KK];
__device__ float d_fsv[BB*CC*KK];
__device__ float d_bias[BB*CC];
// CSR
__device__ int d_cnt[BB*NN];
__device__ int d_cursor[BB*NN];
__device__ int d_off[BB*(NN+1)];
__device__ int d_eidx[BB*EE];

// ---- basis: fp32 [n][k] for gemm1 + bf16 stackT rows ----
__global__ __launch_bounds__(128) void k_basis(const float* __restrict__ nodes,
                                               const float* __restrict__ nodew,
                                               const float* __restrict__ modes,
                                               const float* __restrict__ spL) {
  int bn = blockIdx.x;            // b*NN + n
  int k  = threadIdx.x;
  int b = bn / NN, n = bn % NN;
  float x0 = nodes[bn*3+0], x1 = nodes[bn*3+1], x2 = nodes[bn*3+2];
  float tmp = x0*modes[k*3+0]*spL[0] + x1*modes[k*3+1]*spL[1] + x2*modes[k*3+2]*spL[2];
  float cv = cosf(tmp), sv = sinf(tmp);
  size_t row = (size_t)(b*NP + n);
  d_bc[row*KK + k] = cv;
  d_bs[row*KK + k] = sv;
  d_stackT[row*KR + k]       = f2bf(cv);
  d_stackT[row*KR + 128 + k] = f2bf(sv);
  if (k == 0) d_nw[bn] = nodew[bn];
}

// ---- zero pads of bc/bs/hTw fp32 rows [NN,NP) ----
__global__ __launch_bounds__(256) void k_zero_pad() {
  int tid = blockIdx.x*256 + threadIdx.x;
  int arr = tid / 24576;
  int rem = tid % 24576;
  int b = rem / 12288;
  int r = rem % 12288;
  int n = NN + r/128;
  int k = r % 128;
  size_t idx = ((size_t)(b*NP + n))*128 + k;
  if (arr == 0) d_bc[idx] = 0.f;
  else if (arr == 1) d_bs[idx] = 0.f;
  else d_hTw[idx] = 0.f;
}

// ---- CSR build ----
__global__ __launch_bounds__(256) void k_csr_zero() {
  int tid = blockIdx.x*256 + threadIdx.x;
  if (tid < BB*NN) { d_cnt[tid] = 0; d_cursor[tid] = 0; }
}

__global__ __launch_bounds__(256) void k_csr_count(const int* __restrict__ edges) {
  int e = blockIdx.x*256 + threadIdx.x;
  if (e >= BB*EE) return;
  int b = e / EE;
  int src = edges[e*2 + 0];
  atomicAdd(&d_cnt[b*NN + src], 1);
}

__global__ __launch_bounds__(1024) void k_csr_scan() {
  int b = blockIdx.x;
  __shared__ int sdata[1024];
  __shared__ int carry_s;
  int tid = threadIdx.x;
  if (tid == 0) carry_s = 0;
  __syncthreads();
  for (int chunk = 0; chunk < 20; ++chunk) {
    int i = chunk*1024 + tid;
    int v = (i < NN) ? d_cnt[b*NN + i] : 0;
    sdata[tid] = v;
    __syncthreads();
    for (int s = 1; s < 1024; s <<= 1) {
      int tv = (tid >= s) ? sdata[tid - s] : 0;
      __syncthreads();
      sdata[tid] += tv;
      __syncthreads();
    }
    int excl = carry_s + sdata[tid] - v;
    if (i < NN) d_off[b*(NN+1) + i] = excl;
    __syncthreads();
    if (tid == 1023) carry_s += sdata[1023];
    __syncthreads();
  }
  if (tid == 0) d_off[b*(NN+1) + NN] = carry_s;
}

__global__ __launch_bounds__(256) void k_csr_scatter(const int* __restrict__ edges) {
  int e = blockIdx.x*256 + threadIdx.x;
  if (e >= BB*EE) return;
  int b = e / EE, ee = e % EE;
  int src = edges[e*2 + 0];
  int pos = atomicAdd(&d_cursor[b*NN + src], 1);
  d_eidx[b*EE + d_off[b*(NN+1) + src] + pos] = ee;
}

// ---- fc0 -> hnewT [n][c] ----
__global__ __launch_bounds__(256) void k_h0(const float* __restrict__ x,
                                            const float* __restrict__ t,
                                            const float* __restrict__ w,
                                            const float* __restrict__ bias) {
  int tid = blockIdx.x*256 + threadIdx.x;   // (b*NN+n)*CC + c
  int c = tid & 127;
  int bn = tid >> 7;
  int b = bn / NN, n = bn % NN;
  const float* xv = x + bn*3;
  float acc = bias[c] + xv[0]*w[c] + xv[1]*w[CC+c] + xv[2]*w[2*CC+c]
            + t[bn]*w[3*CC+c];
  d_hnewT[((size_t)(b*NP + n))*CC + c] = acc;
}

// ---- prep: hTw = h*nw (fp32), stackT h slab (bf16) ----
__global__ __launch_bounds__(256) void k_prep() {
  int tid = blockIdx.x*256 + threadIdx.x;   // over BB*NN*CC/4
  int c4 = (tid & 31)*4;
  int bn = tid >> 5;
  int b = bn / NN, n = bn % NN;
  size_t row = (size_t)(b*NP + n);
  float4 v = *(const float4*)&d_hnewT[row*CC + c4];
  float nwv = d_nw[b*NN + n];
  *(float4*)&d_hTw[row*CC + c4] = make_float4(v.x*nwv, v.y*nwv, v.z*nwv, v.w*nwv);
  ushort4 s;
  s.x = f2bf(v.x); s.y = f2bf(v.y); s.z = f2bf(v.z); s.w = f2bf(v.w);
  *(ushort4*)&d_stackT[row*KR + 256 + c4] = s;
}

// ---- gemm1: split-k fp32 (xc = hTw^T*bc, xs = -hTw^T*bs) ----
__global__ __launch_bounds__(256) void k_gemm1() {
  __shared__ float As[16][64];
  __shared__ float Bc[16][128];
  __shared__ float Bs[16][128];
  int chunk = blockIdx.x;
  int half  = blockIdx.y;
  int b     = blockIdx.z;
  int tid = threadIdx.x;
  int tk = tid & 15;
  int tc = tid >> 4;
  float accC[4][8], accS[4][8];
  #pragma unroll
  for (int i = 0; i < 4; i++)
    #pragma unroll
    for (int j = 0; j < 8; j++) { accC[i][j] = 0.f; accS[i][j] = 0.f; }
  int n0 = chunk*128;
  for (int s = 0; s < 8; s++) {
    int nb = n0 + s*16;
    __syncthreads();
    {
      int r = tid >> 4, c4 = (tid & 15)*4;
      *(float4*)&As[r][c4] = *(const float4*)&d_hTw[((size_t)(b*NP + nb + r))*CC + half*64 + c4];
    }
    #pragma unroll
    for (int i = 0; i < 2; i++) {
      int idx = tid + i*256;
      int r = idx >> 5, k4 = (idx & 31)*4;
      *(float4*)&Bc[r][k4] = *(const float4*)&d_bc[((size_t)(b*NP + nb + r))*KK + k4];
      *(float4*)&Bs[r][k4] = *(const float4*)&d_bs[((size_t)(b*NP + nb + r))*KK + k4];
    }
    __syncthreads();
    #pragma unroll
    for (int kk = 0; kk < 16; kk++) {
      float4 a4  = *(float4*)&As[kk][tc*4];
      float4 c4a = *(float4*)&Bc[kk][tk*8];
      float4 c4b = *(float4*)&Bc[kk][tk*8+4];
      float4 s4a = *(float4*)&Bs[kk][tk*8];
      float4 s4b = *(float4*)&Bs[kk][tk*8+4];
      float av[4] = {a4.x, a4.y, a4.z, a4.w};
      float cv[8] = {c4a.x,c4a.y,c4a.z,c4a.w,c4b.x,c4b.y,c4b.z,c4b.w};
      float sv[8] = {s4a.x,s4a.y,s4a.z,s4a.w,s4b.x,s4b.y,s4b.z,s4b.w};
      #pragma unroll
      for (int i = 0; i < 4; i++)
        #pragma unroll
        for (int j = 0; j < 8; j++) {
          accC[i][j] += av[i]*cv[j];
          accS[i][j] -= av[i]*sv[j];
        }
    }
  }
  float* base = d_part + (size_t)((b*2 + half)*NCHK + chunk)*2*8192;
  #pragma unroll
  for (int i = 0; i < 4; i++) {
    int row = tc*4 + i;
    *(float4*)&base[row*128 + tk*8]     = make_float4(accC[i][0],accC[i][1],accC[i][2],accC[i][3]);
    *(float4*)&base[row*128 + tk*8 + 4] = make_float4(accC[i][4],accC[i][5],accC[i][6],accC[i][7]);
    *(float4*)&base[8192 + row*128 + tk*8]     = make_float4(accS[i][0],accS[i][1],accS[i][2],accS[i][3]);
    *(float4*)&base[8192 + row*128 + tk*8 + 4] = make_float4(accS[i][4],accS[i][5],accS[i][6],accS[i][7]);
  }
}

__global__ __launch_bounds__(256) void k_reduce1() {
  int tid = blockIdx.x*256 + threadIdx.x;
  int k = tid & 127;
  int rest = tid >> 7;
  int c = rest & 127;
  int ba = rest >> 7;
  int arr = ba & 1, b = ba >> 1;
  int half = c >> 6, cl = c & 63;
  const float* p = d_part + ((size_t)(b*2 + half)*NCHK*2 + arr)*8192 + cl*128 + k;
  float acc = 0.f;
  for (int ch = 0; ch < NCHK; ch++) acc += p[(size_t)ch*16384];
  if (arr == 0) d_xc[(b*CC + c)*KK + k] = acc;
  else          d_xs[(b*CC + c)*KK + k] = acc;
}

// ---- x0 partials: x0p[b][p][c] = sum over n-slab of h[n][c]*nw[n] ----
__global__ __launch_bounds__(128) void k_x0p() {
  int p = blockIdx.x;     // 0..7
  int b = blockIdx.y;
  int c = threadIdx.x;
  float acc = 0.f;
  int n0 = p*2500, n1 = n0 + 2500;
  for (int n = n0; n < n1; ++n)
    acc += d_hnewT[((size_t)(b*NP + n))*CC + c] * d_nw[b*NN + n];
  d_x0p[(b*8 + p)*CC + c] = acc;
}

// ---- spectral mix per k ----
__global__ __launch_bounds__(128) void k_spec(const float* __restrict__ Wc,
                                              const float* __restrict__ Ws, int l) {
  int b = blockIdx.x >> 7;
  int o = blockIdx.x & 127;
  int k = threadIdx.x;
  const float* wcp = Wc + ((size_t)(l*CC)*CC + o)*KK + k;
  const float* wsp = Ws + ((size_t)(l*CC)*CC + o)*KK + k;
  float fc = 0.f, fs = 0.f;
  for (int i = 0; i < CC; i++) {
    float xcv = d_xc[(b*CC + i)*KK + k];
    float xsv = d_xs[(b*CC + i)*KK + k];
    float wcv = wcp[(size_t)i*CC*KK];
    float wsv = wsp[(size_t)i*CC*KK];
    fc += xcv*wcv - xsv*wsv;
    fs += xsv*wcv + xcv*wsv;
  }
  d_fcv[(b*CC + o)*KK + k] = fc;
  d_fsv[(b*CC + o)*KK + k] = fs;
}

// ---- f0 + full bias ----
__global__ __launch_bounds__(128) void k_f0(const float* __restrict__ W0,
                                            const float* __restrict__ wsb,
                                            const float* __restrict__ gwsb, int l) {
  int b = blockIdx.x;
  int o = threadIdx.x;
  __shared__ float sx[CC];
  float xv = 0.f;
  #pragma unroll
  for (int p = 0; p < 8; p++) xv += d_x0p[(b*8 + p)*CC + o];
  sx[o] = xv;
  __syncthreads();
  float acc = 0.f;
  for (int i = 0; i < CC; i++) acc += sx[i]*W0[(l*CC + i)*CC + o];
  d_bias[b*CC + o] = acc + wsb[l*CC + o] + gwsb[l*CC + o];
}

// ---- build A matrix [b][o][r] bf16 (k-major) ----
__global__ __launch_bounds__(128) void k_buildAb(const float* __restrict__ wsw,
                                                 const float* __restrict__ gwsw, int l) {
  int bo = blockIdx.x;        // b*CC + o
  int b = bo >> 7, o = bo & 127;
  int t = threadIdx.x;
  unsigned short* dst = d_Amatb + (size_t)bo*KR;
  // r in [0,128): 2*fcv ; [128,256): -2*fsv ; [256,384): wsw ; [384,768): gwsw
  dst[t]       = f2bf( 2.f*d_fcv[(size_t)bo*KK + t]);
  dst[128 + t] = f2bf(-2.f*d_fsv[(size_t)bo*KK + t]);
  dst[256 + t] = f2bf(wsw[(l*CC + o)*CC + t]);
  #pragma unroll
  for (int j = 0; j < 3; j++)
    dst[384 + j*128 + t] = f2bf(gwsw[(size_t)(l*CC + o)*GJ + j*128 + t]);
}

// ---- fc1w transpose to [o2][c] bf16 ----
__global__ __launch_bounds__(128) void k_fc1w(const float* __restrict__ fc1w) {
  int c = blockIdx.x;
  int o2 = threadIdx.x;
  d_fc1wb[o2*CC + c] = f2bf(fc1w[c*FCC + o2]);
}

// ---- CSR edge gradient -> stackT g slab (bf16, with g/(1+|g|)) ----
__global__ __launch_bounds__(128) void k_grad_csr(const int* __restrict__ edges,
                                                  const float* __restrict__ egw) {
  int bn = blockIdx.x;            // b*NN + n
  int b = bn / NN, n = bn % NN;
  int c = threadIdx.x;
  int beg = d_off[b*(NN+1) + n];
  int end = d_off[b*(NN+1) + n + 1];
  float a0 = 0.f, a1 = 0.f, a2 = 0.f;
  float sw0 = 0.f, sw1 = 0.f, sw2 = 0.f;
  for (int p = beg; p < end; ++p) {
    int ee = d_eidx[b*EE + p];
    int dst = edges[(b*EE + ee)*2 + 1];
    float w0 = egw[(b*EE + ee)*3 + 0];
    float w1 = egw[(b*EE + ee)*3 + 1];
    float w2 = egw[(b*EE + ee)*3 + 2];
    float fv = d_hnewT[((size_t)(b*NP + dst))*CC + c];
    a0 += w0*fv; a1 += w1*fv; a2 += w2*fv;
    sw0 += w0; sw1 += w1; sw2 += w2;
  }
  float fs = d_hnewT[((size_t)(b*NP + n))*CC + c];
  a0 -= sw0*fs; a1 -= sw1*fs; a2 -= sw2*fs;
  unsigned short* gp = d_stackT + ((size_t)(b*NP + n))*KR + 384;
  gp[c]        = f2bf(a0/(1.f + fabsf(a0)));
  gp[CC + c]   = f2bf(a1/(1.f + fabsf(a1)));
  gp[2*CC + c] = f2bf(a2/(1.f + fabsf(a2)));
}

// ---- MFMA GEMM: Out[b][n][o] = sum_k stackT[b][n][koff+k] * W[b?][o][k] + bias[o] ----
// tile 128n x 128o per block, 4 waves each 32n x 128o, K-chunk 32.
__global__ __launch_bounds__(256) void k_mfma(int koff, int K,
                                              const unsigned short* __restrict__ W, size_t wstride,
                                              float* __restrict__ Out,
                                              const float* __restrict__ bias, int bias_stride,
                                              int gelu) {
  __shared__ unsigned short As[128*40];   // [n-row][k] pad to 40
  __shared__ unsigned short Bs[128*40];   // [o-row][k]
  int b = blockIdx.z;
  int n_base = blockIdx.x*128;
  int tid = threadIdx.x;
  int lane = tid & 63, wid = tid >> 6;
  int q = lane >> 4, m = lane & 15;

  f32x4 acc[2][8];
  #pragma unroll
  for (int i = 0; i < 2; i++)
    #pragma unroll
    for (int j = 0; j < 8; j++) acc[i][j] = (f32x4){0.f,0.f,0.f,0.f};

  const unsigned short* Wb = W + (size_t)b*wstride;
  const unsigned short* Ab = d_stackT + (size_t)b*NP*KR + koff;

  for (int k0 = 0; k0 < K; k0 += 32) {
    __syncthreads();
    #pragma unroll
    for (int i = 0; i < 2; i++) {
      int row = (tid >> 2) + i*64;
      int e8  = (tid & 3)*8;             // ushort offset (16B)
      *(uint4*)&As[row*40 + e8] = *(const uint4*)(Ab + (size_t)(n_base + row)*KR + k0 + e8);
      *(uint4*)&Bs[row*40 + e8] = *(const uint4*)(Wb + (size_t)row*K + k0 + e8);
    }
    __syncthreads();
    bf16x8 a0 = *(const bf16x8*)&As[(wid*32 + m)*40 + q*8];
    bf16x8 a1 = *(const bf16x8*)&As[(wid*32 + 16 + m)*40 + q*8];
    #pragma unroll
    for (int ot = 0; ot < 8; ot++) {
      bf16x8 bf = *(const bf16x8*)&Bs[(ot*16 + m)*40 + q*8];
      acc[0][ot] = __builtin_amdgcn_mfma_f32_16x16x32_bf16(a0, bf, acc[0][ot], 0, 0, 0);
      acc[1][ot] = __builtin_amdgcn_mfma_f32_16x16x32_bf16(a1, bf, acc[1][ot], 0, 0, 0);
    }
  }

  const float* bp = bias + (size_t)b*bias_stride;
  #pragma unroll
  for (int nt = 0; nt < 2; nt++) {
    #pragma unroll
    for (int ot = 0; ot < 8; ot++) {
      int o = ot*16 + m;
      float bvv = bp[o];
      #pragma unroll
      for (int r = 0; r < 4; r++) {
        int n = n_base + wid*32 + nt*16 + q*4 + r;
        float v = acc[nt][ot][r] + bvv;
        if (gelu) v = 0.5f*v*(1.f + erff(v*0.70710678118f));
        Out[((size_t)(b*NP + n))*128 + o] = v;
      }
    }
  }
}

// ---- fc2 + residual; u = d_uT [b][n][o2] ----
__global__ __launch_bounds__(256) void k_out(const float* __restrict__ x,
                                             const float* __restrict__ t,
                                             const float* __restrict__ fc2w,
                                             const float* __restrict__ fc2b,
                                             float* __restrict__ out) {
  int tid = blockIdx.x*256 + threadIdx.x;
  if (tid >= BB*NN) return;
  int b = tid / NN, n = tid % NN;
  const float* up = d_uT + ((size_t)(b*NP + n))*FCC;
  float a0 = fc2b[0], a1 = fc2b[1], a2v = fc2b[2];
  #pragma unroll 4
  for (int o2 = 0; o2 < FCC; o2 += 4) {
    float4 uv = *(const float4*)&up[o2];
    a0  += uv.x*fc2w[(o2+0)*3+0] + uv.y*fc2w[(o2+1)*3+0] + uv.z*fc2w[(o2+2)*3+0] + uv.w*fc2w[(o2+3)*3+0];
    a1  += uv.x*fc2w[(o2+0)*3+1] + uv.y*fc2w[(o2+1)*3+1] + uv.z*fc2w[(o2+2)*3+1] + uv.w*fc2w[(o2+3)*3+1];
    a2v += uv.x*fc2w[(o2+0)*3+2] + uv.y*fc2w[(o2+1)*3+2] + uv.z*fc2w[(o2+2)*3+2] + uv.w*fc2w[(o2+3)*3+2];
  }
  float tv = t[tid];
  out[tid*3 + 0] = x[tid*3 + 0] + tv*a0;
  out[tid*3 + 1] = x[tid*3 + 1] + tv*a1;
  out[tid*3 + 2] = x[tid*3 + 2] + tv*a2v;
}

extern "C" void kernel_launch(void* const* d_in, const int* in_sizes, int n_in,
                              void* d_out, int out_size, void* d_ws, size_t ws_size,
                              hipStream_t stream) {
  const float* x     = (const float*)d_in[0];
  const float* t     = (const float*)d_in[1];
  const float* nodes = (const float*)d_in[3];
  const float* nodew = (const float*)d_in[4];
  const int*   edges = (const int*)d_in[5];
  const float* egw   = (const float*)d_in[6];
  const float* modes = (const float*)d_in[7];
  const float* spL   = (const float*)d_in[8];
  const float* fc0w  = (const float*)d_in[9];
  const float* fc0b  = (const float*)d_in[10];
  const float* Wc    = (const float*)d_in[11];
  const float* Ws    = (const float*)d_in[12];
  const float* W0    = (const float*)d_in[13];
  const float* wsw   = (const float*)d_in[14];
  const float* wsb   = (const float*)d_in[15];
  const float* gwsw  = (const float*)d_in[16];
  const float* gwsb  = (const float*)d_in[17];
  const float* fc1w  = (const float*)d_in[18];
  const float* fc1b  = (const float*)d_in[19];
  const float* fc2w  = (const float*)d_in[20];
  const float* fc2b  = (const float*)d_in[21];
  float* out = (float*)d_out;

  unsigned short* d_Amatb_p; hipGetSymbolAddress((void**)&d_Amatb_p, HIP_SYMBOL(d_Amatb));
  unsigned short* d_fc1wb_p; hipGetSymbolAddress((void**)&d_fc1wb_p, HIP_SYMBOL(d_fc1wb));
  float* d_hnewT_p; hipGetSymbolAddress((void**)&d_hnewT_p, HIP_SYMBOL(d_hnewT));
  float* d_uT_p;    hipGetSymbolAddress((void**)&d_uT_p,    HIP_SYMBOL(d_uT));
  float* d_bias_p;  hipGetSymbolAddress((void**)&d_bias_p,  HIP_SYMBOL(d_bias));

  hipLaunchKernelGGL(k_basis, dim3(BB*NN), dim3(128), 0, stream, nodes, nodew, modes, spL);
  hipLaunchKernelGGL(k_zero_pad, dim3(288), dim3(256), 0, stream);
  hipLaunchKernelGGL(k_h0, dim3(BB*NN*CC/256), dim3(256), 0, stream, x, t, fc0w, fc0b);
  hipLaunchKernelGGL(k_fc1w, dim3(CC), dim3(FCC), 0, stream, fc1w);
  // CSR build
  hipLaunchKernelGGL(k_csr_zero, dim3((BB*NN + 255)/256), dim3(256), 0, stream);
  hipLaunchKernelGGL(k_csr_count, dim3((BB*EE + 255)/256), dim3(256), 0, stream, edges);
  hipLaunchKernelGGL(k_csr_scan, dim3(BB), dim3(1024), 0, stream);
  hipLaunchKernelGGL(k_csr_scatter, dim3((BB*EE + 255)/256), dim3(256), 0, stream, edges);

  for (int l = 0; l < LL; l++) {
    hipLaunchKernelGGL(k_prep, dim3(BB*NN*CC/4/256), dim3(256), 0, stream);
    hipLaunchKernelGGL(k_gemm1, dim3(NCHK, 2, BB), dim3(256), 0, stream);
    hipLaunchKernelGGL(k_reduce1, dim3(256), dim3(256), 0, stream);
    hipLaunchKernelGGL(k_x0p, dim3(8, BB), dim3(128), 0, stream);
    hipLaunchKernelGGL(k_spec, dim3(BB*CC), dim3(128), 0, stream, Wc, Ws, l);
    hipLaunchKernelGGL(k_f0, dim3(BB), dim3(CC), 0, stream, W0, wsb, gwsb, l);
    hipLaunchKernelGGL(k_buildAb, dim3(BB*CC), dim3(128), 0, stream, wsw, gwsw, l);
    hipLaunchKernelGGL(k_grad_csr, dim3(BB*NN), dim3(128), 0, stream, edges, egw);
    hipLaunchKernelGGL(k_mfma, dim3(NCHK, 1, BB), dim3(256), 0, stream,
                       0, KR, d_Amatb_p, (size_t)CC*KR, d_hnewT_p, d_bias_p, CC,
                       (l != LL-1) ? 1 : 0);
  }

  // fc1 via MFMA on the h slab (convert final h to bf16 first)
  hipLaunchKernelGGL(k_prep, dim3(BB*NN*CC/4/256), dim3(256), 0, stream);
  hipLaunchKernelGGL(k_mfma, dim3(NCHK, 1, BB), dim3(256), 0, stream,
                     256, CC, d_fc1wb_p, (size_t)0, d_uT_p, fc1b, 0, 1);
  hipLaunchKernelGGL(k_out, dim3((BB*NN + 255)/256), dim3(256), 0, stream, x, t, fc2w, fc2b, out);
}

// Round 6
// 721.127 us; speedup vs baseline: 21.1206x; 1.3731x over previous
//
#include <hip/hip_runtime.h>
#include <math.h>

#define BB 2
#define NN 20000
#define EE 100000
#define DD 3
#define KK 128
#define CC 128
#define LL 3
#define FCC 128
#define GJ (DD*CC)    // 384
#define KR 768        // stacked contraction: 128 bc + 128 bs + 128 h + 384 g
#define NP 20096      // padded N: 157 tiles * 128
#define NCHK 157      // 128-row chunks

typedef __attribute__((ext_vector_type(8))) short bf16x8;
typedef __attribute__((ext_vector_type(4))) float f32x4;

__device__ inline unsigned short f2bf(float f) {
  unsigned int u = __float_as_uint(f);
  u += 0x7fffu + ((u >> 16) & 1u);
  return (unsigned short)(u >> 16);
}

// ---- scratch (device globals) ----
__device__ __align__(16) float d_bc[(size_t)BB*NP*KK];      // [b][n][k] fp32 (gemm1)
__device__ __align__(16) float d_bs[(size_t)BB*NP*KK];
__device__ float d_nw[BB*NN];
__device__ __align__(16) unsigned short d_stackT[(size_t)BB*NP*KR]; // [b][n][r] bf16: 0 bc,128 bs,256 h,384 g
__device__ __align__(16) float d_hnewT[(size_t)BB*NP*CC];   // h [b][n][c] fp32
__device__ __align__(16) float d_uT[(size_t)BB*NP*FCC];     // fc1 out [b][n][o2]
__device__ __align__(16) float d_hTw[(size_t)BB*NP*CC];     // h*nw [b][n][c] fp32, pad-zeroed
__device__ __align__(16) unsigned short d_Amatb[BB*CC*KR];  // [b][o][r] bf16
__device__ __align__(16) unsigned short d_fc1wb[FCC*CC];    // [o2][c] bf16
__device__ __align__(16) float d_part[(size_t)BB*2*NCHK*2*64*128];
__device__ float d_xc[BB*CC*KK];
__device__ float d_xs[BB*CC*KK];
__device__ float d_x0p[BB*NCHK*CC];
__device__ float d_fcv[BB*CC*KK];
__device__ float d_fsv[BB*CC*KK];
__device__ float d_bias[BB*CC];
// CSR
__device__ int d_cnt[BB*NN];
__device__ int d_cursor[BB*NN];
__device__ int d_off[BB*(NN+1)];
__device__ int d_eidx[BB*EE];

// ---- basis: fp32 [n][k] for gemm1 + bf16 stackT rows ----
__global__ __launch_bounds__(128) void k_basis(const float* __restrict__ nodes,
                                               const float* __restrict__ nodew,
                                               const float* __restrict__ modes,
                                               const float* __restrict__ spL) {
  int bn = blockIdx.x;            // b*NN + n
  int k  = threadIdx.x;
  int b = bn / NN, n = bn % NN;
  float x0 = nodes[bn*3+0], x1 = nodes[bn*3+1], x2 = nodes[bn*3+2];
  float tmp = x0*modes[k*3+0]*spL[0] + x1*modes[k*3+1]*spL[1] + x2*modes[k*3+2]*spL[2];
  float cv = cosf(tmp), sv = sinf(tmp);
  size_t row = (size_t)(b*NP + n);
  d_bc[row*KK + k] = cv;
  d_bs[row*KK + k] = sv;
  d_stackT[row*KR + k]       = f2bf(cv);
  d_stackT[row*KR + 128 + k] = f2bf(sv);
  if (k == 0) d_nw[bn] = nodew[bn];
}

// ---- zero pads of bc/bs/hTw fp32 rows [NN,NP) ----
__global__ __launch_bounds__(256) void k_zero_pad() {
  int tid = blockIdx.x*256 + threadIdx.x;
  int arr = tid / 24576;
  int rem = tid % 24576;
  int b = rem / 12288;
  int r = rem % 12288;
  int n = NN + r/128;
  int k = r % 128;
  size_t idx = ((size_t)(b*NP + n))*128 + k;
  if (arr == 0) d_bc[idx] = 0.f;
  else if (arr == 1) d_bs[idx] = 0.f;
  else d_hTw[idx] = 0.f;
}

// ---- CSR build ----
__global__ __launch_bounds__(256) void k_csr_zero() {
  int tid = blockIdx.x*256 + threadIdx.x;
  if (tid < BB*NN) { d_cnt[tid] = 0; d_cursor[tid] = 0; }
}

__global__ __launch_bounds__(256) void k_csr_count(const int* __restrict__ edges) {
  int e = blockIdx.x*256 + threadIdx.x;
  if (e >= BB*EE) return;
  int b = e / EE;
  int src = edges[e*2 + 0];
  atomicAdd(&d_cnt[b*NN + src], 1);
}

__global__ __launch_bounds__(1024) void k_csr_scan() {
  int b = blockIdx.x;
  __shared__ int sdata[1024];
  __shared__ int carry_s;
  int tid = threadIdx.x;
  if (tid == 0) carry_s = 0;
  __syncthreads();
  for (int chunk = 0; chunk < 20; ++chunk) {
    int i = chunk*1024 + tid;
    int v = (i < NN) ? d_cnt[b*NN + i] : 0;
    sdata[tid] = v;
    __syncthreads();
    for (int s = 1; s < 1024; s <<= 1) {
      int tv = (tid >= s) ? sdata[tid - s] : 0;
      __syncthreads();
      sdata[tid] += tv;
      __syncthreads();
    }
    int excl = carry_s + sdata[tid] - v;
    if (i < NN) d_off[b*(NN+1) + i] = excl;
    __syncthreads();
    if (tid == 1023) carry_s += sdata[1023];
    __syncthreads();
  }
  if (tid == 0) d_off[b*(NN+1) + NN] = carry_s;
}

__global__ __launch_bounds__(256) void k_csr_scatter(const int* __restrict__ edges) {
  int e = blockIdx.x*256 + threadIdx.x;
  if (e >= BB*EE) return;
  int b = e / EE, ee = e % EE;
  int src = edges[e*2 + 0];
  int pos = atomicAdd(&d_cursor[b*NN + src], 1);
  d_eidx[b*EE + d_off[b*(NN+1) + src] + pos] = ee;
}

// ---- fc0 -> hnewT + hTw + stackT h slab ----
__global__ __launch_bounds__(256) void k_h0(const float* __restrict__ x,
                                            const float* __restrict__ t,
                                            const float* __restrict__ w,
                                            const float* __restrict__ bias) {
  int tid = blockIdx.x*256 + threadIdx.x;   // (b*NN+n)*CC + c
  int c = tid & 127;
  int bn = tid >> 7;
  int b = bn / NN, n = bn % NN;
  const float* xv = x + bn*3;
  float acc = bias[c] + xv[0]*w[c] + xv[1]*w[CC+c] + xv[2]*w[2*CC+c]
            + t[bn]*w[3*CC+c];
  size_t row = (size_t)(b*NP + n);
  d_hnewT[row*CC + c] = acc;
  d_hTw[row*CC + c] = acc*d_nw[bn];
  d_stackT[row*KR + 256 + c] = f2bf(acc);
}

// ---- gemm1: split-k fp32 (xc = hTw^T*bc, xs = -hTw^T*bs) ----
__global__ __launch_bounds__(256) void k_gemm1() {
  __shared__ float As[16][64];
  __shared__ float Bc[16][128];
  __shared__ float Bs[16][128];
  int chunk = blockIdx.x;
  int half  = blockIdx.y;
  int b     = blockIdx.z;
  int tid = threadIdx.x;
  int tk = tid & 15;
  int tc = tid >> 4;
  float accC[4][8], accS[4][8];
  #pragma unroll
  for (int i = 0; i < 4; i++)
    #pragma unroll
    for (int j = 0; j < 8; j++) { accC[i][j] = 0.f; accS[i][j] = 0.f; }
  int n0 = chunk*128;
  for (int s = 0; s < 8; s++) {
    int nb = n0 + s*16;
    __syncthreads();
    {
      int r = tid >> 4, c4 = (tid & 15)*4;
      *(float4*)&As[r][c4] = *(const float4*)&d_hTw[((size_t)(b*NP + nb + r))*CC + half*64 + c4];
    }
    #pragma unroll
    for (int i = 0; i < 2; i++) {
      int idx = tid + i*256;
      int r = idx >> 5, k4 = (idx & 31)*4;
      *(float4*)&Bc[r][k4] = *(const float4*)&d_bc[((size_t)(b*NP + nb + r))*KK + k4];
      *(float4*)&Bs[r][k4] = *(const float4*)&d_bs[((size_t)(b*NP + nb + r))*KK + k4];
    }
    __syncthreads();
    #pragma unroll
    for (int kk = 0; kk < 16; kk++) {
      float4 a4  = *(float4*)&As[kk][tc*4];
      float4 c4a = *(float4*)&Bc[kk][tk*8];
      float4 c4b = *(float4*)&Bc[kk][tk*8+4];
      float4 s4a = *(float4*)&Bs[kk][tk*8];
      float4 s4b = *(float4*)&Bs[kk][tk*8+4];
      float av[4] = {a4.x, a4.y, a4.z, a4.w};
      float cv[8] = {c4a.x,c4a.y,c4a.z,c4a.w,c4b.x,c4b.y,c4b.z,c4b.w};
      float sv[8] = {s4a.x,s4a.y,s4a.z,s4a.w,s4b.x,s4b.y,s4b.z,s4b.w};
      #pragma unroll
      for (int i = 0; i < 4; i++)
        #pragma unroll
        for (int j = 0; j < 8; j++) {
          accC[i][j] += av[i]*cv[j];
          accS[i][j] -= av[i]*sv[j];
        }
    }
  }
  float* base = d_part + (size_t)((b*2 + half)*NCHK + chunk)*2*8192;
  #pragma unroll
  for (int i = 0; i < 4; i++) {
    int row = tc*4 + i;
    *(float4*)&base[row*128 + tk*8]     = make_float4(accC[i][0],accC[i][1],accC[i][2],accC[i][3]);
    *(float4*)&base[row*128 + tk*8 + 4] = make_float4(accC[i][4],accC[i][5],accC[i][6],accC[i][7]);
    *(float4*)&base[8192 + row*128 + tk*8]     = make_float4(accS[i][0],accS[i][1],accS[i][2],accS[i][3]);
    *(float4*)&base[8192 + row*128 + tk*8 + 4] = make_float4(accS[i][4],accS[i][5],accS[i][6],accS[i][7]);
  }
}

__global__ __launch_bounds__(256) void k_reduce1() {
  int tid = blockIdx.x*256 + threadIdx.x;
  int k = tid & 127;
  int rest = tid >> 7;
  int c = rest & 127;
  int ba = rest >> 7;
  int arr = ba & 1, b = ba >> 1;
  int half = c >> 6, cl = c & 63;
  const float* p = d_part + ((size_t)(b*2 + half)*NCHK*2 + arr)*8192 + cl*128 + k;
  float acc = 0.f;
  for (int ch = 0; ch < NCHK; ch++) acc += p[(size_t)ch*16384];
  if (arr == 0) d_xc[(b*CC + c)*KK + k] = acc;
  else          d_xs[(b*CC + c)*KK + k] = acc;
}

// ---- x0 partials per 128-row chunk: x0p[b][chunk][c] = sum hTw[n][c] ----
__global__ __launch_bounds__(256) void k_x0() {
  int chunk = blockIdx.x;    // NCHK
  int b = blockIdx.y;
  int c = threadIdx.x & 127;
  int half = threadIdx.x >> 7;
  int n0 = chunk*128 + half*64;
  const float* base = d_hTw + ((size_t)(b*NP + n0))*CC + c;
  float acc = 0.f;
  #pragma unroll 8
  for (int i = 0; i < 64; i++) acc += base[(size_t)i*CC];
  __shared__ float red[2][128];
  red[half][c] = acc;
  __syncthreads();
  if (half == 0) d_x0p[(b*NCHK + chunk)*CC + c] = red[0][c] + red[1][c];
}

// ---- spectral mix per k ----
__global__ __launch_bounds__(128) void k_spec(const float* __restrict__ Wc,
                                              const float* __restrict__ Ws, int l) {
  int b = blockIdx.x >> 7;
  int o = blockIdx.x & 127;
  int k = threadIdx.x;
  const float* wcp = Wc + ((size_t)(l*CC)*CC + o)*KK + k;
  const float* wsp = Ws + ((size_t)(l*CC)*CC + o)*KK + k;
  float fc = 0.f, fs = 0.f;
  for (int i = 0; i < CC; i++) {
    float xcv = d_xc[(b*CC + i)*KK + k];
    float xsv = d_xs[(b*CC + i)*KK + k];
    float wcv = wcp[(size_t)i*CC*KK];
    float wsv = wsp[(size_t)i*CC*KK];
    fc += xcv*wcv - xsv*wsv;
    fs += xsv*wcv + xcv*wsv;
  }
  d_fcv[(b*CC + o)*KK + k] = fc;
  d_fsv[(b*CC + o)*KK + k] = fs;
}

// ---- f0 + full bias (reduces x0 partials) ----
__global__ __launch_bounds__(128) void k_f0(const float* __restrict__ W0,
                                            const float* __restrict__ wsb,
                                            const float* __restrict__ gwsb, int l) {
  int b = blockIdx.x;
  int o = threadIdx.x;
  __shared__ float sx[CC];
  float xv = 0.f;
  for (int p = 0; p < NCHK; p++) xv += d_x0p[(b*NCHK + p)*CC + o];
  sx[o] = xv;
  __syncthreads();
  float acc = 0.f;
  for (int i = 0; i < CC; i++) acc += sx[i]*W0[(l*CC + i)*CC + o];
  d_bias[b*CC + o] = acc + wsb[l*CC + o] + gwsb[l*CC + o];
}

// ---- build A matrix [b][o][r] bf16 (k-major) ----
__global__ __launch_bounds__(128) void k_buildAb(const float* __restrict__ wsw,
                                                 const float* __restrict__ gwsw, int l) {
  int bo = blockIdx.x;        // b*CC + o
  int b = bo >> 7, o = bo & 127;
  int t = threadIdx.x;
  unsigned short* dst = d_Amatb + (size_t)bo*KR;
  dst[t]       = f2bf( 2.f*d_fcv[(size_t)bo*KK + t]);
  dst[128 + t] = f2bf(-2.f*d_fsv[(size_t)bo*KK + t]);
  dst[256 + t] = f2bf(wsw[(l*CC + o)*CC + t]);
  #pragma unroll
  for (int j = 0; j < 3; j++)
    dst[384 + j*128 + t] = f2bf(gwsw[(size_t)(l*CC + o)*GJ + j*128 + t]);
}

// ---- fc1w transpose to [o2][c] bf16 ----
__global__ __launch_bounds__(128) void k_fc1w(const float* __restrict__ fc1w) {
  int c = blockIdx.x;
  int o2 = threadIdx.x;
  d_fc1wb[o2*CC + c] = f2bf(fc1w[c*FCC + o2]);
}

// ---- CSR edge gradient -> stackT g slab (bf16, with g/(1+|g|)) ----
__global__ __launch_bounds__(128) void k_grad_csr(const int* __restrict__ edges,
                                                  const float* __restrict__ egw) {
  int bn = blockIdx.x;            // b*NN + n
  int b = bn / NN, n = bn % NN;
  int c = threadIdx.x;
  int beg = d_off[b*(NN+1) + n];
  int end = d_off[b*(NN+1) + n + 1];
  float a0 = 0.f, a1 = 0.f, a2 = 0.f;
  float sw0 = 0.f, sw1 = 0.f, sw2 = 0.f;
  for (int p = beg; p < end; ++p) {
    int ee = d_eidx[b*EE + p];
    int dst = edges[(b*EE + ee)*2 + 1];
    float w0 = egw[(b*EE + ee)*3 + 0];
    float w1 = egw[(b*EE + ee)*3 + 1];
    float w2 = egw[(b*EE + ee)*3 + 2];
    float fv = d_hnewT[((size_t)(b*NP + dst))*CC + c];
    a0 += w0*fv; a1 += w1*fv; a2 += w2*fv;
    sw0 += w0; sw1 += w1; sw2 += w2;
  }
  float fs = d_hnewT[((size_t)(b*NP + n))*CC + c];
  a0 -= sw0*fs; a1 -= sw1*fs; a2 -= sw2*fs;
  unsigned short* gp = d_stackT + ((size_t)(b*NP + n))*KR + 384;
  gp[c]        = f2bf(a0/(1.f + fabsf(a0)));
  gp[CC + c]   = f2bf(a1/(1.f + fabsf(a1)));
  gp[2*CC + c] = f2bf(a2/(1.f + fabsf(a2)));
}

// ---- MFMA GEMM: Out[b][n][o] = sum_k stackT[b][n][koff+k] * W[b?][o][k] + bias[o] ----
// aux: also emit hTw (fp32, *nw) and stackT h slab (bf16) for the next layer.
__global__ __launch_bounds__(256) void k_mfma(int koff, int K,
                                              const unsigned short* __restrict__ W, size_t wstride,
                                              float* __restrict__ Out,
                                              const float* __restrict__ bias, int bias_stride,
                                              int gelu, int aux) {
  __shared__ unsigned short As[128*40];   // [n-row][k] pad to 40
  __shared__ unsigned short Bs[128*40];   // [o-row][k]
  int b = blockIdx.z;
  int n_base = blockIdx.x*128;
  int tid = threadIdx.x;
  int lane = tid & 63, wid = tid >> 6;
  int q = lane >> 4, m = lane & 15;

  f32x4 acc[2][8];
  #pragma unroll
  for (int i = 0; i < 2; i++)
    #pragma unroll
    for (int j = 0; j < 8; j++) acc[i][j] = (f32x4){0.f,0.f,0.f,0.f};

  const unsigned short* Wb = W + (size_t)b*wstride;
  const unsigned short* Ab = d_stackT + (size_t)b*NP*KR + koff;

  for (int k0 = 0; k0 < K; k0 += 32) {
    __syncthreads();
    #pragma unroll
    for (int i = 0; i < 2; i++) {
      int row = (tid >> 2) + i*64;
      int e8  = (tid & 3)*8;             // ushort offset (16B)
      *(uint4*)&As[row*40 + e8] = *(const uint4*)(Ab + (size_t)(n_base + row)*KR + k0 + e8);
      *(uint4*)&Bs[row*40 + e8] = *(const uint4*)(Wb + (size_t)row*K + k0 + e8);
    }
    __syncthreads();
    bf16x8 a0 = *(const bf16x8*)&As[(wid*32 + m)*40 + q*8];
    bf16x8 a1 = *(const bf16x8*)&As[(wid*32 + 16 + m)*40 + q*8];
    #pragma unroll
    for (int ot = 0; ot < 8; ot++) {
      bf16x8 bf = *(const bf16x8*)&Bs[(ot*16 + m)*40 + q*8];
      acc[0][ot] = __builtin_amdgcn_mfma_f32_16x16x32_bf16(a0, bf, acc[0][ot], 0, 0, 0);
      acc[1][ot] = __builtin_amdgcn_mfma_f32_16x16x32_bf16(a1, bf, acc[1][ot], 0, 0, 0);
    }
  }

  const float* bp = bias + (size_t)b*bias_stride;
  #pragma unroll
  for (int nt = 0; nt < 2; nt++) {
    #pragma unroll
    for (int r = 0; r < 4; r++) {
      int n = n_base + wid*32 + nt*16 + q*4 + r;
      size_t row = (size_t)(b*NP + n);
      float nwv = (aux && n < NN) ? d_nw[b*NN + n] : 0.f;
      #pragma unroll
      for (int ot = 0; ot < 8; ot++) {
        int o = ot*16 + m;
        float v = acc[nt][ot][r] + bp[o];
        if (gelu) v = 0.5f*v*(1.f + erff(v*0.70710678118f));
        Out[row*128 + o] = v;
        if (aux && n < NN) {
          d_hTw[row*CC + o] = v*nwv;
          d_stackT[row*KR + 256 + o] = f2bf(v);
        }
      }
    }
  }
}

// ---- fc2 + residual; u = d_uT [b][n][o2] ----
__global__ __launch_bounds__(256) void k_out(const float* __restrict__ x,
                                             const float* __restrict__ t,
                                             const float* __restrict__ fc2w,
                                             const float* __restrict__ fc2b,
                                             float* __restrict__ out) {
  int tid = blockIdx.x*256 + threadIdx.x;
  if (tid >= BB*NN) return;
  int b = tid / NN, n = tid % NN;
  const float* up = d_uT + ((size_t)(b*NP + n))*FCC;
  float a0 = fc2b[0], a1 = fc2b[1], a2v = fc2b[2];
  #pragma unroll 4
  for (int o2 = 0; o2 < FCC; o2 += 4) {
    float4 uv = *(const float4*)&up[o2];
    a0  += uv.x*fc2w[(o2+0)*3+0] + uv.y*fc2w[(o2+1)*3+0] + uv.z*fc2w[(o2+2)*3+0] + uv.w*fc2w[(o2+3)*3+0];
    a1  += uv.x*fc2w[(o2+0)*3+1] + uv.y*fc2w[(o2+1)*3+1] + uv.z*fc2w[(o2+2)*3+1] + uv.w*fc2w[(o2+3)*3+1];
    a2v += uv.x*fc2w[(o2+0)*3+2] + uv.y*fc2w[(o2+1)*3+2] + uv.z*fc2w[(o2+2)*3+2] + uv.w*fc2w[(o2+3)*3+2];
  }
  float tv = t[tid];
  out[tid*3 + 0] = x[tid*3 + 0] + tv*a0;
  out[tid*3 + 1] = x[tid*3 + 1] + tv*a1;
  out[tid*3 + 2] = x[tid*3 + 2] + tv*a2v;
}

extern "C" void kernel_launch(void* const* d_in, const int* in_sizes, int n_in,
                              void* d_out, int out_size, void* d_ws, size_t ws_size,
                              hipStream_t stream) {
  const float* x     = (const float*)d_in[0];
  const float* t     = (const float*)d_in[1];
  const float* nodes = (const float*)d_in[3];
  const float* nodew = (const float*)d_in[4];
  const int*   edges = (const int*)d_in[5];
  const float* egw   = (const float*)d_in[6];
  const float* modes = (const float*)d_in[7];
  const float* spL   = (const float*)d_in[8];
  const float* fc0w  = (const float*)d_in[9];
  const float* fc0b  = (const float*)d_in[10];
  const float* Wc    = (const float*)d_in[11];
  const float* Ws    = (const float*)d_in[12];
  const float* W0    = (const float*)d_in[13];
  const float* wsw   = (const float*)d_in[14];
  const float* wsb   = (const float*)d_in[15];
  const float* gwsw  = (const float*)d_in[16];
  const float* gwsb  = (const float*)d_in[17];
  const float* fc1w  = (const float*)d_in[18];
  const float* fc1b  = (const float*)d_in[19];
  const float* fc2w  = (const float*)d_in[20];
  const float* fc2b  = (const float*)d_in[21];
  float* out = (float*)d_out;

  unsigned short* d_Amatb_p; hipGetSymbolAddress((void**)&d_Amatb_p, HIP_SYMBOL(d_Amatb));
  unsigned short* d_fc1wb_p; hipGetSymbolAddress((void**)&d_fc1wb_p, HIP_SYMBOL(d_fc1wb));
  float* d_hnewT_p; hipGetSymbolAddress((void**)&d_hnewT_p, HIP_SYMBOL(d_hnewT));
  float* d_uT_p;    hipGetSymbolAddress((void**)&d_uT_p,    HIP_SYMBOL(d_uT));
  float* d_bias_p;  hipGetSymbolAddress((void**)&d_bias_p,  HIP_SYMBOL(d_bias));

  hipLaunchKernelGGL(k_basis, dim3(BB*NN), dim3(128), 0, stream, nodes, nodew, modes, spL);
  hipLaunchKernelGGL(k_zero_pad, dim3(288), dim3(256), 0, stream);
  hipLaunchKernelGGL(k_h0, dim3(BB*NN*CC/256), dim3(256), 0, stream, x, t, fc0w, fc0b);
  hipLaunchKernelGGL(k_fc1w, dim3(CC), dim3(FCC), 0, stream, fc1w);
  // CSR build
  hipLaunchKernelGGL(k_csr_zero, dim3((BB*NN + 255)/256), dim3(256), 0, stream);
  hipLaunchKernelGGL(k_csr_count, dim3((BB*EE + 255)/256), dim3(256), 0, stream, edges);
  hipLaunchKernelGGL(k_csr_scan, dim3(BB), dim3(1024), 0, stream);
  hipLaunchKernelGGL(k_csr_scatter, dim3((BB*EE + 255)/256), dim3(256), 0, stream, edges);

  for (int l = 0; l < LL; l++) {
    hipLaunchKernelGGL(k_gemm1, dim3(NCHK, 2, BB), dim3(256), 0, stream);
    hipLaunchKernelGGL(k_reduce1, dim3(256), dim3(256), 0, stream);
    hipLaunchKernelGGL(k_x0, dim3(NCHK, BB), dim3(256), 0, stream);
    hipLaunchKernelGGL(k_spec, dim3(BB*CC), dim3(128), 0, stream, Wc, Ws, l);
    hipLaunchKernelGGL(k_f0, dim3(BB), dim3(CC), 0, stream, W0, wsb, gwsb, l);
    hipLaunchKernelGGL(k_buildAb, dim3(BB*CC), dim3(128), 0, stream, wsw, gwsw, l);
    hipLaunchKernelGGL(k_grad_csr, dim3(BB*NN), dim3(128), 0, stream, edges, egw);
    hipLaunchKernelGGL(k_mfma, dim3(NCHK, 1, BB), dim3(256), 0, stream,
                       0, KR, d_Amatb_p, (size_t)CC*KR, d_hnewT_p, d_bias_p, CC,
                       (l != LL-1) ? 1 : 0, 1);
  }

  // fc1 via MFMA on the h slab (stackT h written by last k_mfma aux)
  hipLaunchKernelGGL(k_mfma, dim3(NCHK, 1, BB), dim3(256), 0, stream,
                     256, CC, d_fc1wb_p, (size_t)0, d_uT_p, fc1b, 0, 1, 0);
  hipLaunchKernelGGL(k_out, dim3((BB*NN + 255)/256), dim3(256), 0, stream, x, t, fc2w, fc2b, out);
}

// Round 7
// 581.524 us; speedup vs baseline: 26.1909x; 1.2401x over previous
//
#include <hip/hip_runtime.h>
#include <math.h>

#define BB 2
#define NN 20000
#define EE 100000
#define DD 3
#define KK 128
#define CC 128
#define LL 3
#define FCC 128
#define GJ (DD*CC)    // 384
#define KR 768        // stacked contraction: 128 bc + 128 bs + 128 h + 384 g
#define NP 20096      // padded N: 157 tiles * 128
#define NCHK 157      // 128-row chunks
#define G1CH 79       // gemm1 split-k chunks (256 n each)
#define G1N 256

typedef __attribute__((ext_vector_type(8))) short bf16x8;
typedef __attribute__((ext_vector_type(4))) float f32x4;

__device__ inline unsigned short f2bf(float f) {
  unsigned int u = __float_as_uint(f);
  u += 0x7fffu + ((u >> 16) & 1u);
  return (unsigned short)(u >> 16);
}
__device__ inline float bf2f(unsigned short u) {
  return __uint_as_float(((unsigned int)u) << 16);
}

// ---- scratch (device globals) ----
__device__ float d_nw[BB*NN];
__device__ __align__(16) unsigned short d_stackT[(size_t)BB*NP*KR]; // [b][n][r] bf16: 0 bc,128 bs,256 h,384 g
__device__ __align__(16) unsigned short d_bcT[(size_t)BB*KK*NP];    // [b][k][n] bf16, pad-zeroed
__device__ __align__(16) unsigned short d_bsT[(size_t)BB*KK*NP];
__device__ __align__(16) unsigned short d_hTwT[(size_t)BB*CC*NP];   // [b][c][n] bf16 = h*nw, pad-zeroed
__device__ __align__(16) float d_hnewT[(size_t)BB*NP*CC];   // h [b][n][c] fp32
__device__ __align__(16) float d_uT[(size_t)BB*NP*FCC];     // fc1 out [b][n][o2]
__device__ __align__(16) unsigned short d_Amatb[BB*CC*KR];  // [b][o][r] bf16
__device__ __align__(16) unsigned short d_fc1wb[FCC*CC];    // [o2][c] bf16
__device__ __align__(16) float d_part[(size_t)BB*G1CH*2*128*128];   // [b][chunk][arr][c*128+k]
__device__ float d_xc[BB*CC*KK];
__device__ float d_xs[BB*CC*KK];
__device__ float d_x0p[BB*NCHK*CC];
__device__ float d_fcv[BB*CC*KK];
__device__ float d_fsv[BB*CC*KK];
__device__ float d_bias[BB*CC];
// CSR
__device__ int d_cnt[BB*NN];
__device__ int d_cursor[BB*NN];
__device__ int d_off[BB*(NN+1)];
__device__ __align__(16) float4 d_erec[(size_t)BB*EE];      // {dst_bits, w0, w1, w2}

// ---- basis -> stackT bc/bs slabs (bf16) ----
__global__ __launch_bounds__(128) void k_basis(const float* __restrict__ nodes,
                                               const float* __restrict__ nodew,
                                               const float* __restrict__ modes,
                                               const float* __restrict__ spL) {
  int bn = blockIdx.x;            // b*NN + n
  int k  = threadIdx.x;
  int b = bn / NN, n = bn % NN;
  float x0 = nodes[bn*3+0], x1 = nodes[bn*3+1], x2 = nodes[bn*3+2];
  float tmp = x0*modes[k*3+0]*spL[0] + x1*modes[k*3+1]*spL[1] + x2*modes[k*3+2]*spL[2];
  float cv = cosf(tmp), sv = sinf(tmp);
  size_t row = (size_t)(b*NP + n);
  d_stackT[row*KR + k]       = f2bf(cv);
  d_stackT[row*KR + 128 + k] = f2bf(sv);
  if (k == 0) d_nw[bn] = nodew[bn];
}

// ---- transpose stackT bc/bs slabs -> bcT/bsT [k][n] bf16 (once; zero-pads n>=NN) ----
__global__ __launch_bounds__(256) void k_basisT() {
  __shared__ unsigned short t1[32][136];
  __shared__ unsigned short t2[32][136];
  int blk = blockIdx.x;          // 628 * BB
  int nt = blk % 628, b = blk / 628;
  int n0 = nt*32;
  int tid = threadIdx.x;
  int kl = tid & 127, ng = tid >> 7;
  for (int nn = ng; nn < 32; nn += 2) {
    int n = n0 + nn;
    unsigned short cv = 0, sv = 0;
    if (n < NN) {
      const unsigned short* sp = d_stackT + ((size_t)(b*NP + n))*KR;
      cv = sp[kl]; sv = sp[128 + kl];
    }
    t1[nn][kl] = cv;
    t2[nn][kl] = sv;
  }
  __syncthreads();
  int nl = tid & 31, kg = tid >> 5;
  for (int k = kg; k < 128; k += 8) {
    d_bcT[((size_t)(b*KK + k))*NP + n0 + nl] = t1[nl][k];
    d_bsT[((size_t)(b*KK + k))*NP + n0 + nl] = t2[nl][k];
  }
}

// ---- CSR build ----
__global__ __launch_bounds__(256) void k_csr_zero() {
  int tid = blockIdx.x*256 + threadIdx.x;
  if (tid < BB*NN) { d_cnt[tid] = 0; d_cursor[tid] = 0; }
}

__global__ __launch_bounds__(256) void k_csr_count(const int* __restrict__ edges) {
  int e = blockIdx.x*256 + threadIdx.x;
  if (e >= BB*EE) return;
  int b = e / EE;
  int src = edges[e*2 + 0];
  atomicAdd(&d_cnt[b*NN + src], 1);
}

__global__ __launch_bounds__(1024) void k_csr_scan() {
  int b = blockIdx.x;
  __shared__ int sdata[1024];
  __shared__ int carry_s;
  int tid = threadIdx.x;
  if (tid == 0) carry_s = 0;
  __syncthreads();
  for (int chunk = 0; chunk < 20; ++chunk) {
    int i = chunk*1024 + tid;
    int v = (i < NN) ? d_cnt[b*NN + i] : 0;
    sdata[tid] = v;
    __syncthreads();
    for (int s = 1; s < 1024; s <<= 1) {
      int tv = (tid >= s) ? sdata[tid - s] : 0;
      __syncthreads();
      sdata[tid] += tv;
      __syncthreads();
    }
    int excl = carry_s + sdata[tid] - v;
    if (i < NN) d_off[b*(NN+1) + i] = excl;
    __syncthreads();
    if (tid == 1023) carry_s += sdata[1023];
    __syncthreads();
  }
  if (tid == 0) d_off[b*(NN+1) + NN] = carry_s;
}

// ---- scatter: build packed edge records {dst, w0, w1, w2} ----
__global__ __launch_bounds__(256) void k_csr_scatter(const int* __restrict__ edges,
                                                     const float* __restrict__ egw) {
  int e = blockIdx.x*256 + threadIdx.x;
  if (e >= BB*EE) return;
  int b = e / EE;
  int src = edges[e*2 + 0];
  int dst = edges[e*2 + 1];
  int pos = atomicAdd(&d_cursor[b*NN + src], 1);
  d_erec[(size_t)b*EE + d_off[b*(NN+1) + src] + pos] =
      make_float4(__int_as_float(dst), egw[e*3+0], egw[e*3+1], egw[e*3+2]);
}

// ---- fc0 -> hnewT + stackT h slab ----
__global__ __launch_bounds__(256) void k_h0(const float* __restrict__ x,
                                            const float* __restrict__ t,
                                            const float* __restrict__ w,
                                            const float* __restrict__ bias) {
  int tid = blockIdx.x*256 + threadIdx.x;   // (b*NN+n)*CC + c
  int c = tid & 127;
  int bn = tid >> 7;
  int b = bn / NN, n = bn % NN;
  const float* xv = x + bn*3;
  float acc = bias[c] + xv[0]*w[c] + xv[1]*w[CC+c] + xv[2]*w[2*CC+c]
            + t[bn]*w[3*CC+c];
  size_t row = (size_t)(b*NP + n);
  d_hnewT[row*CC + c] = acc;
  d_stackT[row*KR + 256 + c] = f2bf(acc);
}

// ---- layer-0 hTwT: hnewT [n][c] * nw -> bf16 [c][n], zero-pads ----
__global__ __launch_bounds__(256) void k_hT0() {
  __shared__ unsigned short t[128][136];
  int chunk = blockIdx.x;   // NCHK
  int b = blockIdx.y;
  int n0 = chunk*128;
  int tid = threadIdx.x;
  int cl = tid & 127, ng = tid >> 7;
  for (int nn = ng; nn < 128; nn += 2) {
    int n = n0 + nn;
    unsigned short v = 0;
    if (n < NN) v = f2bf(d_hnewT[((size_t)(b*NP + n))*CC + cl] * d_nw[b*NN + n]);
    t[nn][cl] = v;
  }
  __syncthreads();
  int nl = tid & 31, cg = tid >> 5;
  for (int c = cg; c < 128; c += 8)
    for (int nn2 = 0; nn2 < 128; nn2 += 32)
      d_hTwT[((size_t)(b*CC + c))*NP + n0 + nn2 + nl] = t[nn2 + nl][c];
}

// ---- gemm1 MFMA: part[c][k] += sum_n hTwT[c][n]*bcT/bsT[k][n] ----
__global__ __launch_bounds__(256) void k_gemm1m() {
  __shared__ unsigned short Bsh[2][128][40];
  int chunk = blockIdx.x;   // G1CH
  int b = blockIdx.y;
  int tid = threadIdx.x, lane = tid & 63, wid = tid >> 6;
  int q = lane >> 4, m = lane & 15;
  f32x4 accC[2][8], accS[2][8];
  #pragma unroll
  for (int i = 0; i < 2; i++)
    #pragma unroll
    for (int j = 0; j < 8; j++) { accC[i][j] = (f32x4){0.f,0.f,0.f,0.f}; accS[i][j] = (f32x4){0.f,0.f,0.f,0.f}; }
  const unsigned short* Ab = d_hTwT + (size_t)b*CC*NP;
  const unsigned short* Bcp = d_bcT + (size_t)b*KK*NP;
  const unsigned short* Bsp = d_bsT + (size_t)b*KK*NP;
  int n0 = chunk*G1N;
  for (int s = 0; s < G1N/32; s++) {
    int nb = n0 + s*32;
    if (nb >= NP) break;
    __syncthreads();
    {
      int arr = tid >> 7, row = tid & 127;
      const unsigned short* src = (arr ? Bsp : Bcp) + (size_t)row*NP + nb;
      unsigned short* dr = &Bsh[arr][row][0];
      *(uint4*)&dr[0]  = *(const uint4*)&src[0];
      *(uint4*)&dr[8]  = *(const uint4*)&src[8];
      *(uint4*)&dr[16] = *(const uint4*)&src[16];
      *(uint4*)&dr[24] = *(const uint4*)&src[24];
    }
    __syncthreads();
    bf16x8 a0 = *(const bf16x8*)(Ab + (size_t)(wid*32 + m)*NP + nb + q*8);
    bf16x8 a1 = *(const bf16x8*)(Ab + (size_t)(wid*32 + 16 + m)*NP + nb + q*8);
    #pragma unroll
    for (int kt = 0; kt < 8; kt++) {
      bf16x8 bcf = *(const bf16x8*)&Bsh[0][kt*16 + m][q*8];
      bf16x8 bsf = *(const bf16x8*)&Bsh[1][kt*16 + m][q*8];
      accC[0][kt] = __builtin_amdgcn_mfma_f32_16x16x32_bf16(a0, bcf, accC[0][kt], 0, 0, 0);
      accC[1][kt] = __builtin_amdgcn_mfma_f32_16x16x32_bf16(a1, bcf, accC[1][kt], 0, 0, 0);
      accS[0][kt] = __builtin_amdgcn_mfma_f32_16x16x32_bf16(a0, bsf, accS[0][kt], 0, 0, 0);
      accS[1][kt] = __builtin_amdgcn_mfma_f32_16x16x32_bf16(a1, bsf, accS[1][kt], 0, 0, 0);
    }
  }
  float* base = d_part + (((size_t)b*G1CH + chunk)*2)*16384;
  #pragma unroll
  for (int mt = 0; mt < 2; mt++)
    #pragma unroll
    for (int kt = 0; kt < 8; kt++)
      #pragma unroll
      for (int r = 0; r < 4; r++) {
        int c = wid*32 + mt*16 + q*4 + r;
        int k = kt*16 + m;
        base[c*128 + k]         =  accC[mt][kt][r];
        base[16384 + c*128 + k] = -accS[mt][kt][r];   // xs = -sum
      }
}

// ---- reduce split-k partials -> xc, xs ----
__global__ __launch_bounds__(256) void k_reduce1() {
  int tid = blockIdx.x*256 + threadIdx.x;   // BB*2*128*128 = 65536
  int k = tid & 127;
  int c = (tid >> 7) & 127;
  int arr = (tid >> 14) & 1;
  int b = tid >> 15;
  const float* p = d_part + (((size_t)b*G1CH)*2 + arr)*16384 + c*128 + k;
  float acc = 0.f;
  for (int ch = 0; ch < G1CH; ch++) acc += p[(size_t)ch*2*16384];
  if (arr == 0) d_xc[(b*CC + c)*KK + k] = acc;
  else          d_xs[(b*CC + c)*KK + k] = acc;
}

// ---- x0 partials from hTwT bf16: x0p[b][chunk][c] = sum_n hTwT[c][n] ----
__global__ __launch_bounds__(256) void k_x0() {
  int chunk = blockIdx.x;   // NCHK
  int b = blockIdx.y;
  int tid = threadIdx.x;
  int c = tid >> 1, half = tid & 1;
  const unsigned short* p = d_hTwT + ((size_t)(b*CC + c))*NP + chunk*128 + half*64;
  float acc = 0.f;
  #pragma unroll
  for (int i = 0; i < 8; i++) {
    ushort4 v0 = *(const ushort4*)&p[i*8];
    ushort4 v1 = *(const ushort4*)&p[i*8 + 4];
    acc += bf2f(v0.x) + bf2f(v0.y) + bf2f(v0.z) + bf2f(v0.w)
         + bf2f(v1.x) + bf2f(v1.y) + bf2f(v1.z) + bf2f(v1.w);
  }
  __shared__ float red[128][2];
  red[c][half] = acc;
  __syncthreads();
  if (half == 0) d_x0p[(b*NCHK + chunk)*CC + c] = red[c][0] + red[c][1];
}

// ---- spectral mix per k ----
__global__ __launch_bounds__(128) void k_spec(const float* __restrict__ Wc,
                                              const float* __restrict__ Ws, int l) {
  int b = blockIdx.x >> 7;
  int o = blockIdx.x & 127;
  int k = threadIdx.x;
  const float* wcp = Wc + ((size_t)(l*CC)*CC + o)*KK + k;
  const float* wsp = Ws + ((size_t)(l*CC)*CC + o)*KK + k;
  float fc = 0.f, fs = 0.f;
  for (int i = 0; i < CC; i++) {
    float xcv = d_xc[(b*CC + i)*KK + k];
    float xsv = d_xs[(b*CC + i)*KK + k];
    float wcv = wcp[(size_t)i*CC*KK];
    float wsv = wsp[(size_t)i*CC*KK];
    fc += xcv*wcv - xsv*wsv;
    fs += xsv*wcv + xcv*wsv;
  }
  d_fcv[(b*CC + o)*KK + k] = fc;
  d_fsv[(b*CC + o)*KK + k] = fs;
}

// ---- f0 + full bias ----
__global__ __launch_bounds__(128) void k_f0(const float* __restrict__ W0,
                                            const float* __restrict__ wsb,
                                            const float* __restrict__ gwsb, int l) {
  int b = blockIdx.x;
  int o = threadIdx.x;
  __shared__ float sx[CC];
  float xv = 0.f;
  for (int p = 0; p < NCHK; p++) xv += d_x0p[(b*NCHK + p)*CC + o];
  sx[o] = xv;
  __syncthreads();
  float acc = 0.f;
  for (int i = 0; i < CC; i++) acc += sx[i]*W0[(l*CC + i)*CC + o];
  d_bias[b*CC + o] = acc + wsb[l*CC + o] + gwsb[l*CC + o];
}

// ---- build A matrix [b][o][r] bf16 ----
__global__ __launch_bounds__(128) void k_buildAb(const float* __restrict__ wsw,
                                                 const float* __restrict__ gwsw, int l) {
  int bo = blockIdx.x;
  int b = bo >> 7, o = bo & 127;
  int t = threadIdx.x;
  unsigned short* dst = d_Amatb + (size_t)bo*KR;
  dst[t]       = f2bf( 2.f*d_fcv[(size_t)bo*KK + t]);
  dst[128 + t] = f2bf(-2.f*d_fsv[(size_t)bo*KK + t]);
  dst[256 + t] = f2bf(wsw[(l*CC + o)*CC + t]);
  #pragma unroll
  for (int j = 0; j < 3; j++)
    dst[384 + j*128 + t] = f2bf(gwsw[(size_t)(l*CC + o)*GJ + j*128 + t]);
}

// ---- fc1w transpose to [o2][c] bf16 ----
__global__ __launch_bounds__(128) void k_fc1w(const float* __restrict__ fc1w) {
  int c = blockIdx.x;
  int o2 = threadIdx.x;
  d_fc1wb[o2*CC + c] = f2bf(fc1w[c*FCC + o2]);
}

// ---- CSR edge gradient via packed records -> stackT g slab ----
__global__ __launch_bounds__(128) void k_grad_csr() {
  int bn = blockIdx.x;            // b*NN + n
  int b = bn / NN, n = bn % NN;
  int c = threadIdx.x;
  int beg = d_off[b*(NN+1) + n];
  int end = d_off[b*(NN+1) + n + 1];
  const float4* rp = d_erec + (size_t)b*EE;
  const float* hb = d_hnewT + (size_t)b*NP*CC + c;
  float a0 = 0.f, a1 = 0.f, a2 = 0.f;
  float sw0 = 0.f, sw1 = 0.f, sw2 = 0.f;
  int p = beg;
  for (; p + 2 <= end; p += 2) {
    float4 r1 = rp[p], r2 = rp[p+1];
    float f1 = hb[(size_t)__float_as_int(r1.x)*CC];
    float f2 = hb[(size_t)__float_as_int(r2.x)*CC];
    a0 += r1.y*f1 + r2.y*f2;
    a1 += r1.z*f1 + r2.z*f2;
    a2 += r1.w*f1 + r2.w*f2;
    sw0 += r1.y + r2.y; sw1 += r1.z + r2.z; sw2 += r1.w + r2.w;
  }
  if (p < end) {
    float4 r1 = rp[p];
    float f1 = hb[(size_t)__float_as_int(r1.x)*CC];
    a0 += r1.y*f1; a1 += r1.z*f1; a2 += r1.w*f1;
    sw0 += r1.y; sw1 += r1.z; sw2 += r1.w;
  }
  float fs = d_hnewT[((size_t)(b*NP + n))*CC + c];
  a0 -= sw0*fs; a1 -= sw1*fs; a2 -= sw2*fs;
  unsigned short* gp = d_stackT + ((size_t)(b*NP + n))*KR + 384;
  gp[c]        = f2bf(a0/(1.f + fabsf(a0)));
  gp[CC + c]   = f2bf(a1/(1.f + fabsf(a1)));
  gp[2*CC + c] = f2bf(a2/(1.f + fabsf(a2)));
}

// ---- MFMA GEMM: Out[b][n][o] = sum_k stackT[b][n][koff+k] * W[b?][o][k] + bias[o] ----
// aux: also emit stackT h slab (bf16) and hTwT [o][n] bf16 for the next layer.
__global__ __launch_bounds__(256) void k_mfma(int koff, int K,
                                              const unsigned short* __restrict__ W, size_t wstride,
                                              float* __restrict__ Out,
                                              const float* __restrict__ bias, int bias_stride,
                                              int gelu, int aux) {
  __shared__ unsigned short As[128*40];   // [n-row][k] pad to 40
  __shared__ unsigned short Bs[128*40];   // [o-row][k]
  int b = blockIdx.z;
  int n_base = blockIdx.x*128;
  int tid = threadIdx.x;
  int lane = tid & 63, wid = tid >> 6;
  int q = lane >> 4, m = lane & 15;

  f32x4 acc[2][8];
  #pragma unroll
  for (int i = 0; i < 2; i++)
    #pragma unroll
    for (int j = 0; j < 8; j++) acc[i][j] = (f32x4){0.f,0.f,0.f,0.f};

  const unsigned short* Wb = W + (size_t)b*wstride;
  const unsigned short* Ab = d_stackT + (size_t)b*NP*KR + koff;

  for (int k0 = 0; k0 < K; k0 += 32) {
    __syncthreads();
    #pragma unroll
    for (int i = 0; i < 2; i++) {
      int row = (tid >> 2) + i*64;
      int e8  = (tid & 3)*8;
      *(uint4*)&As[row*40 + e8] = *(const uint4*)(Ab + (size_t)(n_base + row)*KR + k0 + e8);
      *(uint4*)&Bs[row*40 + e8] = *(const uint4*)(Wb + (size_t)row*K + k0 + e8);
    }
    __syncthreads();
    bf16x8 a0 = *(const bf16x8*)&As[(wid*32 + m)*40 + q*8];
    bf16x8 a1 = *(const bf16x8*)&As[(wid*32 + 16 + m)*40 + q*8];
    #pragma unroll
    for (int ot = 0; ot < 8; ot++) {
      bf16x8 bf = *(const bf16x8*)&Bs[(ot*16 + m)*40 + q*8];
      acc[0][ot] = __builtin_amdgcn_mfma_f32_16x16x32_bf16(a0, bf, acc[0][ot], 0, 0, 0);
      acc[1][ot] = __builtin_amdgcn_mfma_f32_16x16x32_bf16(a1, bf, acc[1][ot], 0, 0, 0);
    }
  }

  const float* bp = bias + (size_t)b*bias_stride;
  #pragma unroll
  for (int nt = 0; nt < 2; nt++) {
    int nb4 = n_base + wid*32 + nt*16 + q*4;
    float nw4[4];
    #pragma unroll
    for (int r = 0; r < 4; r++)
      nw4[r] = (aux && nb4 + r < NN) ? d_nw[b*NN + nb4 + r] : 0.f;
    #pragma unroll
    for (int ot = 0; ot < 8; ot++) {
      int o = ot*16 + m;
      float bvv = bp[o];
      float vals[4];
      #pragma unroll
      for (int r = 0; r < 4; r++) {
        float v = acc[nt][ot][r] + bvv;
        if (gelu) v = 0.5f*v*(1.f + erff(v*0.70710678118f));
        vals[r] = v;
        Out[((size_t)(b*NP + nb4 + r))*128 + o] = v;
        if (aux && nb4 + r < NN)
          d_stackT[((size_t)(b*NP + nb4 + r))*KR + 256 + o] = f2bf(v);
      }
      if (aux) {
        ushort4 pk;
        pk.x = f2bf(vals[0]*nw4[0]);
        pk.y = f2bf(vals[1]*nw4[1]);
        pk.z = f2bf(vals[2]*nw4[2]);
        pk.w = f2bf(vals[3]*nw4[3]);
        *(ushort4*)&d_hTwT[((size_t)(b*CC + o))*NP + nb4] = pk;
      }
    }
  }
}

// ---- fc2 + residual; u = d_uT [b][n][o2] ----
__global__ __launch_bounds__(256) void k_out(const float* __restrict__ x,
                                             const float* __restrict__ t,
                                             const float* __restrict__ fc2w,
                                             const float* __restrict__ fc2b,
                                             float* __restrict__ out) {
  int tid = blockIdx.x*256 + threadIdx.x;
  if (tid >= BB*NN) return;
  int b = tid / NN, n = tid % NN;
  const float* up = d_uT + ((size_t)(b*NP + n))*FCC;
  float a0 = fc2b[0], a1 = fc2b[1], a2v = fc2b[2];
  #pragma unroll 4
  for (int o2 = 0; o2 < FCC; o2 += 4) {
    float4 uv = *(const float4*)&up[o2];
    a0  += uv.x*fc2w[(o2+0)*3+0] + uv.y*fc2w[(o2+1)*3+0] + uv.z*fc2w[(o2+2)*3+0] + uv.w*fc2w[(o2+3)*3+0];
    a1  += uv.x*fc2w[(o2+0)*3+1] + uv.y*fc2w[(o2+1)*3+1] + uv.z*fc2w[(o2+2)*3+1] + uv.w*fc2w[(o2+3)*3+1];
    a2v += uv.x*fc2w[(o2+0)*3+2] + uv.y*fc2w[(o2+1)*3+2] + uv.z*fc2w[(o2+2)*3+2] + uv.w*fc2w[(o2+3)*3+2];
  }
  float tv = t[tid];
  out[tid*3 + 0] = x[tid*3 + 0] + tv*a0;
  out[tid*3 + 1] = x[tid*3 + 1] + tv*a1;
  out[tid*3 + 2] = x[tid*3 + 2] + tv*a2v;
}

extern "C" void kernel_launch(void* const* d_in, const int* in_sizes, int n_in,
                              void* d_out, int out_size, void* d_ws, size_t ws_size,
                              hipStream_t stream) {
  const float* x     = (const float*)d_in[0];
  const float* t     = (const float*)d_in[1];
  const float* nodes = (const float*)d_in[3];
  const float* nodew = (const float*)d_in[4];
  const int*   edges = (const int*)d_in[5];
  const float* egw   = (const float*)d_in[6];
  const float* modes = (const float*)d_in[7];
  const float* spL   = (const float*)d_in[8];
  const float* fc0w  = (const float*)d_in[9];
  const float* fc0b  = (const float*)d_in[10];
  const float* Wc    = (const float*)d_in[11];
  const float* Ws    = (const float*)d_in[12];
  const float* W0    = (const float*)d_in[13];
  const float* wsw   = (const float*)d_in[14];
  const float* wsb   = (const float*)d_in[15];
  const float* gwsw  = (const float*)d_in[16];
  const float* gwsb  = (const float*)d_in[17];
  const float* fc1w  = (const float*)d_in[18];
  const float* fc1b  = (const float*)d_in[19];
  const float* fc2w  = (const float*)d_in[20];
  const float* fc2b  = (const float*)d_in[21];
  float* out = (float*)d_out;

  unsigned short* d_Amatb_p; hipGetSymbolAddress((void**)&d_Amatb_p, HIP_SYMBOL(d_Amatb));
  unsigned short* d_fc1wb_p; hipGetSymbolAddress((void**)&d_fc1wb_p, HIP_SYMBOL(d_fc1wb));
  float* d_hnewT_p; hipGetSymbolAddress((void**)&d_hnewT_p, HIP_SYMBOL(d_hnewT));
  float* d_uT_p;    hipGetSymbolAddress((void**)&d_uT_p,    HIP_SYMBOL(d_uT));
  float* d_bias_p;  hipGetSymbolAddress((void**)&d_bias_p,  HIP_SYMBOL(d_bias));

  hipLaunchKernelGGL(k_basis, dim3(BB*NN), dim3(128), 0, stream, nodes, nodew, modes, spL);
  hipLaunchKernelGGL(k_basisT, dim3(628*BB), dim3(256), 0, stream);
  hipLaunchKernelGGL(k_h0, dim3(BB*NN*CC/256), dim3(256), 0, stream, x, t, fc0w, fc0b);
  hipLaunchKernelGGL(k_hT0, dim3(NCHK, BB), dim3(256), 0, stream);
  hipLaunchKernelGGL(k_fc1w, dim3(CC), dim3(FCC), 0, stream, fc1w);
  // CSR build (once; edges constant across layers)
  hipLaunchKernelGGL(k_csr_zero, dim3((BB*NN + 255)/256), dim3(256), 0, stream);
  hipLaunchKernelGGL(k_csr_count, dim3((BB*EE + 255)/256), dim3(256), 0, stream, edges);
  hipLaunchKernelGGL(k_csr_scan, dim3(BB), dim3(1024), 0, stream);
  hipLaunchKernelGGL(k_csr_scatter, dim3((BB*EE + 255)/256), dim3(256), 0, stream, edges, egw);

  for (int l = 0; l < LL; l++) {
    hipLaunchKernelGGL(k_gemm1m, dim3(G1CH, BB), dim3(256), 0, stream);
    hipLaunchKernelGGL(k_reduce1, dim3(256), dim3(256), 0, stream);
    hipLaunchKernelGGL(k_x0, dim3(NCHK, BB), dim3(256), 0, stream);
    hipLaunchKernelGGL(k_spec, dim3(BB*CC), dim3(128), 0, stream, Wc, Ws, l);
    hipLaunchKernelGGL(k_f0, dim3(BB), dim3(CC), 0, stream, W0, wsb, gwsb, l);
    hipLaunchKernelGGL(k_buildAb, dim3(BB*CC), dim3(128), 0, stream, wsw, gwsw, l);
    hipLaunchKernelGGL(k_grad_csr, dim3(BB*NN), dim3(128), 0, stream);
    hipLaunchKernelGGL(k_mfma, dim3(NCHK, 1, BB), dim3(256), 0, stream,
                       0, KR, d_Amatb_p, (size_t)CC*KR, d_hnewT_p, d_bias_p, CC,
                       (l != LL-1) ? 1 : 0, 1);
  }

  // fc1 via MFMA on the h slab
  hipLaunchKernelGGL(k_mfma, dim3(NCHK, 1, BB), dim3(256), 0, stream,
                     256, CC, d_fc1wb_p, (size_t)0, d_uT_p, fc1b, 0, 1, 0);
  hipLaunchKernelGGL(k_out, dim3((BB*NN + 255)/256), dim3(256), 0, stream, x, t, fc2w, fc2b, out);
}

// Round 8
// 563.462 us; speedup vs baseline: 27.0305x; 1.0321x over previous
//
#include <hip/hip_runtime.h>
#include <math.h>

#define BB 2
#define NN 20000
#define EE 100000
#define DD 3
#define KK 128
#define CC 128
#define LL 3
#define FCC 128
#define GJ (DD*CC)    // 384
#define KR 768        // stacked contraction: 128 bc + 128 bs + 128 h + 384 g
#define NP 20096      // padded N: 157 tiles * 128
#define NCHK 157      // 128-row chunks
#define G1CH 79       // gemm1 split-k chunks (256 n each)
#define G1N 256

typedef __attribute__((ext_vector_type(8))) short bf16x8;
typedef __attribute__((ext_vector_type(4))) float f32x4;

__device__ inline unsigned short f2bf(float f) {
  unsigned int u = __float_as_uint(f);
  u += 0x7fffu + ((u >> 16) & 1u);
  return (unsigned short)(u >> 16);
}
__device__ inline float bf2f(unsigned short u) {
  return __uint_as_float(((unsigned int)u) << 16);
}

// ---- scratch (device globals) ----
__device__ float d_nw[BB*NN];
__device__ __align__(16) unsigned short d_stackT[(size_t)BB*NP*KR]; // [b][n][r] bf16: 0 bc,128 bs,256 h,384 g
__device__ __align__(16) unsigned short d_bcT[(size_t)BB*KK*NP];    // [b][k][n] bf16, pad-zeroed
__device__ __align__(16) unsigned short d_bsT[(size_t)BB*KK*NP];
__device__ __align__(16) unsigned short d_hTwT[(size_t)BB*CC*NP];   // [b][c][n] bf16 = h*nw, pad-zeroed
__device__ __align__(16) float d_hnewT[(size_t)BB*NP*CC];   // h [b][n][c] fp32
__device__ __align__(16) float d_uT[(size_t)BB*NP*FCC];     // fc1 out [b][n][o2]
__device__ __align__(16) unsigned short d_Amatb[BB*CC*KR];  // [b][o][r] bf16
__device__ __align__(16) unsigned short d_fc1wb[FCC*CC];    // [o2][c] bf16
__device__ __align__(16) float d_part[(size_t)BB*G1CH*2*128*128];   // [b][chunk][arr][c*128+k]
__device__ float d_xc[BB*CC*KK];
__device__ float d_xs[BB*CC*KK];
__device__ float d_x0p[BB*NCHK*CC];
__device__ float d_fcv[BB*CC*KK];
__device__ float d_fsv[BB*CC*KK];
__device__ float d_bias[BB*CC];
// CSR
__device__ int d_cnt[BB*NN];
__device__ int d_cursor[BB*NN];
__device__ int d_off[BB*(NN+1)];
__device__ __align__(16) float4 d_erec[(size_t)BB*EE];      // {dst_bits, w0, w1, w2}

// ---- basis -> stackT bc/bs slabs (bf16) ----
__global__ __launch_bounds__(128) void k_basis(const float* __restrict__ nodes,
                                               const float* __restrict__ nodew,
                                               const float* __restrict__ modes,
                                               const float* __restrict__ spL) {
  int bn = blockIdx.x;            // b*NN + n
  int k  = threadIdx.x;
  int b = bn / NN, n = bn % NN;
  float x0 = nodes[bn*3+0], x1 = nodes[bn*3+1], x2 = nodes[bn*3+2];
  float tmp = x0*modes[k*3+0]*spL[0] + x1*modes[k*3+1]*spL[1] + x2*modes[k*3+2]*spL[2];
  float cv = cosf(tmp), sv = sinf(tmp);
  size_t row = (size_t)(b*NP + n);
  d_stackT[row*KR + k]       = f2bf(cv);
  d_stackT[row*KR + 128 + k] = f2bf(sv);
  if (k == 0) d_nw[bn] = nodew[bn];
}

// ---- transpose stackT bc/bs slabs -> bcT/bsT [k][n] bf16 (once; zero-pads n>=NN) ----
__global__ __launch_bounds__(256) void k_basisT() {
  __shared__ unsigned short t1[32][136];
  __shared__ unsigned short t2[32][136];
  int blk = blockIdx.x;          // 628 * BB
  int nt = blk % 628, b = blk / 628;
  int n0 = nt*32;
  int tid = threadIdx.x;
  int kl = tid & 127, ng = tid >> 7;
  for (int nn = ng; nn < 32; nn += 2) {
    int n = n0 + nn;
    unsigned short cv = 0, sv = 0;
    if (n < NN) {
      const unsigned short* sp = d_stackT + ((size_t)(b*NP + n))*KR;
      cv = sp[kl]; sv = sp[128 + kl];
    }
    t1[nn][kl] = cv;
    t2[nn][kl] = sv;
  }
  __syncthreads();
  int nl = tid & 31, kg = tid >> 5;
  for (int k = kg; k < 128; k += 8) {
    d_bcT[((size_t)(b*KK + k))*NP + n0 + nl] = t1[nl][k];
    d_bsT[((size_t)(b*KK + k))*NP + n0 + nl] = t2[nl][k];
  }
}

// ---- CSR build ----
__global__ __launch_bounds__(256) void k_csr_zero() {
  int tid = blockIdx.x*256 + threadIdx.x;
  if (tid < BB*NN) { d_cnt[tid] = 0; d_cursor[tid] = 0; }
}

__global__ __launch_bounds__(256) void k_csr_count(const int* __restrict__ edges) {
  int e = blockIdx.x*256 + threadIdx.x;
  if (e >= BB*EE) return;
  int b = e / EE;
  int src = edges[e*2 + 0];
  atomicAdd(&d_cnt[b*NN + src], 1);
}

__global__ __launch_bounds__(1024) void k_csr_scan() {
  int b = blockIdx.x;
  __shared__ int sdata[1024];
  __shared__ int carry_s;
  int tid = threadIdx.x;
  if (tid == 0) carry_s = 0;
  __syncthreads();
  for (int chunk = 0; chunk < 20; ++chunk) {
    int i = chunk*1024 + tid;
    int v = (i < NN) ? d_cnt[b*NN + i] : 0;
    sdata[tid] = v;
    __syncthreads();
    for (int s = 1; s < 1024; s <<= 1) {
      int tv = (tid >= s) ? sdata[tid - s] : 0;
      __syncthreads();
      sdata[tid] += tv;
      __syncthreads();
    }
    int excl = carry_s + sdata[tid] - v;
    if (i < NN) d_off[b*(NN+1) + i] = excl;
    __syncthreads();
    if (tid == 1023) carry_s += sdata[1023];
    __syncthreads();
  }
  if (tid == 0) d_off[b*(NN+1) + NN] = carry_s;
}

// ---- scatter: build packed edge records {dst, w0, w1, w2} ----
__global__ __launch_bounds__(256) void k_csr_scatter(const int* __restrict__ edges,
                                                     const float* __restrict__ egw) {
  int e = blockIdx.x*256 + threadIdx.x;
  if (e >= BB*EE) return;
  int b = e / EE;
  int src = edges[e*2 + 0];
  int dst = edges[e*2 + 1];
  int pos = atomicAdd(&d_cursor[b*NN + src], 1);
  d_erec[(size_t)b*EE + d_off[b*(NN+1) + src] + pos] =
      make_float4(__int_as_float(dst), egw[e*3+0], egw[e*3+1], egw[e*3+2]);
}

// ---- fc0 -> hnewT + stackT h slab ----
__global__ __launch_bounds__(256) void k_h0(const float* __restrict__ x,
                                            const float* __restrict__ t,
                                            const float* __restrict__ w,
                                            const float* __restrict__ bias) {
  int tid = blockIdx.x*256 + threadIdx.x;   // (b*NN+n)*CC + c
  int c = tid & 127;
  int bn = tid >> 7;
  int b = bn / NN, n = bn % NN;
  const float* xv = x + bn*3;
  float acc = bias[c] + xv[0]*w[c] + xv[1]*w[CC+c] + xv[2]*w[2*CC+c]
            + t[bn]*w[3*CC+c];
  size_t row = (size_t)(b*NP + n);
  d_hnewT[row*CC + c] = acc;
  d_stackT[row*KR + 256 + c] = f2bf(acc);
}

// ---- layer-0 hTwT: hnewT [n][c] * nw -> bf16 [c][n], zero-pads ----
__global__ __launch_bounds__(256) void k_hT0() {
  __shared__ unsigned short t[128][136];
  int chunk = blockIdx.x;   // NCHK
  int b = blockIdx.y;
  int n0 = chunk*128;
  int tid = threadIdx.x;
  int cl = tid & 127, ng = tid >> 7;
  for (int nn = ng; nn < 128; nn += 2) {
    int n = n0 + nn;
    unsigned short v = 0;
    if (n < NN) v = f2bf(d_hnewT[((size_t)(b*NP + n))*CC + cl] * d_nw[b*NN + n]);
    t[nn][cl] = v;
  }
  __syncthreads();
  int nl = tid & 31, cg = tid >> 5;
  for (int c = cg; c < 128; c += 8)
    for (int nn2 = 0; nn2 < 128; nn2 += 32)
      d_hTwT[((size_t)(b*CC + c))*NP + n0 + nn2 + nl] = t[nn2 + nl][c];
}

// ---- gemm1 MFMA: part[c][k] += sum_n hTwT[c][n]*bcT/bsT[k][n] ----
__global__ __launch_bounds__(256) void k_gemm1m() {
  __shared__ unsigned short Bsh[2][128][40];
  int chunk = blockIdx.x;   // G1CH
  int b = blockIdx.y;
  int tid = threadIdx.x, lane = tid & 63, wid = tid >> 6;
  int q = lane >> 4, m = lane & 15;
  f32x4 accC[2][8], accS[2][8];
  #pragma unroll
  for (int i = 0; i < 2; i++)
    #pragma unroll
    for (int j = 0; j < 8; j++) { accC[i][j] = (f32x4){0.f,0.f,0.f,0.f}; accS[i][j] = (f32x4){0.f,0.f,0.f,0.f}; }
  const unsigned short* Ab = d_hTwT + (size_t)b*CC*NP;
  const unsigned short* Bcp = d_bcT + (size_t)b*KK*NP;
  const unsigned short* Bsp = d_bsT + (size_t)b*KK*NP;
  int n0 = chunk*G1N;
  for (int s = 0; s < G1N/32; s++) {
    int nb = n0 + s*32;
    if (nb >= NP) break;
    __syncthreads();
    {
      int arr = tid >> 7, row = tid & 127;
      const unsigned short* src = (arr ? Bsp : Bcp) + (size_t)row*NP + nb;
      unsigned short* dr = &Bsh[arr][row][0];
      *(uint4*)&dr[0]  = *(const uint4*)&src[0];
      *(uint4*)&dr[8]  = *(const uint4*)&src[8];
      *(uint4*)&dr[16] = *(const uint4*)&src[16];
      *(uint4*)&dr[24] = *(const uint4*)&src[24];
    }
    __syncthreads();
    bf16x8 a0 = *(const bf16x8*)(Ab + (size_t)(wid*32 + m)*NP + nb + q*8);
    bf16x8 a1 = *(const bf16x8*)(Ab + (size_t)(wid*32 + 16 + m)*NP + nb + q*8);
    #pragma unroll
    for (int kt = 0; kt < 8; kt++) {
      bf16x8 bcf = *(const bf16x8*)&Bsh[0][kt*16 + m][q*8];
      bf16x8 bsf = *(const bf16x8*)&Bsh[1][kt*16 + m][q*8];
      accC[0][kt] = __builtin_amdgcn_mfma_f32_16x16x32_bf16(a0, bcf, accC[0][kt], 0, 0, 0);
      accC[1][kt] = __builtin_amdgcn_mfma_f32_16x16x32_bf16(a1, bcf, accC[1][kt], 0, 0, 0);
      accS[0][kt] = __builtin_amdgcn_mfma_f32_16x16x32_bf16(a0, bsf, accS[0][kt], 0, 0, 0);
      accS[1][kt] = __builtin_amdgcn_mfma_f32_16x16x32_bf16(a1, bsf, accS[1][kt], 0, 0, 0);
    }
  }
  float* base = d_part + (((size_t)b*G1CH + chunk)*2)*16384;
  #pragma unroll
  for (int mt = 0; mt < 2; mt++)
    #pragma unroll
    for (int kt = 0; kt < 8; kt++)
      #pragma unroll
      for (int r = 0; r < 4; r++) {
        int c = wid*32 + mt*16 + q*4 + r;
        int k = kt*16 + m;
        base[c*128 + k]         =  accC[mt][kt][r];
        base[16384 + c*128 + k] = -accS[mt][kt][r];   // xs = -sum
      }
}

// ---- reduce split-k partials -> xc, xs ----
__global__ __launch_bounds__(256) void k_reduce1() {
  int tid = blockIdx.x*256 + threadIdx.x;   // BB*2*128*128 = 65536
  int k = tid & 127;
  int c = (tid >> 7) & 127;
  int arr = (tid >> 14) & 1;
  int b = tid >> 15;
  const float* p = d_part + (((size_t)b*G1CH)*2 + arr)*16384 + c*128 + k;
  float acc = 0.f;
  for (int ch = 0; ch < G1CH; ch++) acc += p[(size_t)ch*2*16384];
  if (arr == 0) d_xc[(b*CC + c)*KK + k] = acc;
  else          d_xs[(b*CC + c)*KK + k] = acc;
}

// ---- x0 partials from hTwT bf16 ----
__global__ __launch_bounds__(256) void k_x0() {
  int chunk = blockIdx.x;   // NCHK
  int b = blockIdx.y;
  int tid = threadIdx.x;
  int c = tid >> 1, half = tid & 1;
  const unsigned short* p = d_hTwT + ((size_t)(b*CC + c))*NP + chunk*128 + half*64;
  float acc = 0.f;
  #pragma unroll
  for (int i = 0; i < 8; i++) {
    ushort4 v0 = *(const ushort4*)&p[i*8];
    ushort4 v1 = *(const ushort4*)&p[i*8 + 4];
    acc += bf2f(v0.x) + bf2f(v0.y) + bf2f(v0.z) + bf2f(v0.w)
         + bf2f(v1.x) + bf2f(v1.y) + bf2f(v1.z) + bf2f(v1.w);
  }
  __shared__ float red[128][2];
  red[c][half] = acc;
  __syncthreads();
  if (half == 0) d_x0p[(b*NCHK + chunk)*CC + c] = red[c][0] + red[c][1];
}

// ---- spectral mix per k ----
__global__ __launch_bounds__(128) void k_spec(const float* __restrict__ Wc,
                                              const float* __restrict__ Ws, int l) {
  int b = blockIdx.x >> 7;
  int o = blockIdx.x & 127;
  int k = threadIdx.x;
  const float* wcp = Wc + ((size_t)(l*CC)*CC + o)*KK + k;
  const float* wsp = Ws + ((size_t)(l*CC)*CC + o)*KK + k;
  float fc = 0.f, fs = 0.f;
  for (int i = 0; i < CC; i++) {
    float xcv = d_xc[(b*CC + i)*KK + k];
    float xsv = d_xs[(b*CC + i)*KK + k];
    float wcv = wcp[(size_t)i*CC*KK];
    float wsv = wsp[(size_t)i*CC*KK];
    fc += xcv*wcv - xsv*wsv;
    fs += xsv*wcv + xcv*wsv;
  }
  d_fcv[(b*CC + o)*KK + k] = fc;
  d_fsv[(b*CC + o)*KK + k] = fs;
}

// ---- f0 + full bias ----
__global__ __launch_bounds__(128) void k_f0(const float* __restrict__ W0,
                                            const float* __restrict__ wsb,
                                            const float* __restrict__ gwsb, int l) {
  int b = blockIdx.x;
  int o = threadIdx.x;
  __shared__ float sx[CC];
  float xv = 0.f;
  for (int p = 0; p < NCHK; p++) xv += d_x0p[(b*NCHK + p)*CC + o];
  sx[o] = xv;
  __syncthreads();
  float acc = 0.f;
  for (int i = 0; i < CC; i++) acc += sx[i]*W0[(l*CC + i)*CC + o];
  d_bias[b*CC + o] = acc + wsb[l*CC + o] + gwsb[l*CC + o];
}

// ---- build A matrix [b][o][r] bf16 ----
__global__ __launch_bounds__(128) void k_buildAb(const float* __restrict__ wsw,
                                                 const float* __restrict__ gwsw, int l) {
  int bo = blockIdx.x;
  int b = bo >> 7, o = bo & 127;
  int t = threadIdx.x;
  unsigned short* dst = d_Amatb + (size_t)bo*KR;
  dst[t]       = f2bf( 2.f*d_fcv[(size_t)bo*KK + t]);
  dst[128 + t] = f2bf(-2.f*d_fsv[(size_t)bo*KK + t]);
  dst[256 + t] = f2bf(wsw[(l*CC + o)*CC + t]);
  #pragma unroll
  for (int j = 0; j < 3; j++)
    dst[384 + j*128 + t] = f2bf(gwsw[(size_t)(l*CC + o)*GJ + j*128 + t]);
}

// ---- fc1w transpose to [o2][c] bf16 ----
__global__ __launch_bounds__(128) void k_fc1w(const float* __restrict__ fc1w) {
  int c = blockIdx.x;
  int o2 = threadIdx.x;
  d_fc1wb[o2*CC + c] = f2bf(fc1w[c*FCC + o2]);
}

// ---- CSR edge gradient via packed records -> stackT g slab ----
__global__ __launch_bounds__(128) void k_grad_csr() {
  int bn = blockIdx.x;            // b*NN + n
  int b = bn / NN, n = bn % NN;
  int c = threadIdx.x;
  int beg = d_off[b*(NN+1) + n];
  int end = d_off[b*(NN+1) + n + 1];
  const float4* rp = d_erec + (size_t)b*EE;
  const float* hb = d_hnewT + (size_t)b*NP*CC + c;
  float a0 = 0.f, a1 = 0.f, a2 = 0.f;
  float sw0 = 0.f, sw1 = 0.f, sw2 = 0.f;
  int p = beg;
  for (; p + 2 <= end; p += 2) {
    float4 r1 = rp[p], r2 = rp[p+1];
    float f1 = hb[(size_t)__float_as_int(r1.x)*CC];
    float f2 = hb[(size_t)__float_as_int(r2.x)*CC];
    a0 += r1.y*f1 + r2.y*f2;
    a1 += r1.z*f1 + r2.z*f2;
    a2 += r1.w*f1 + r2.w*f2;
    sw0 += r1.y + r2.y; sw1 += r1.z + r2.z; sw2 += r1.w + r2.w;
  }
  if (p < end) {
    float4 r1 = rp[p];
    float f1 = hb[(size_t)__float_as_int(r1.x)*CC];
    a0 += r1.y*f1; a1 += r1.z*f1; a2 += r1.w*f1;
    sw0 += r1.y; sw1 += r1.z; sw2 += r1.w;
  }
  float fs = d_hnewT[((size_t)(b*NP + n))*CC + c];
  a0 -= sw0*fs; a1 -= sw1*fs; a2 -= sw2*fs;
  unsigned short* gp = d_stackT + ((size_t)(b*NP + n))*KR + 384;
  gp[c]        = f2bf(a0/(1.f + fabsf(a0)));
  gp[CC + c]   = f2bf(a1/(1.f + fabsf(a1)));
  gp[2*CC + c] = f2bf(a2/(1.f + fabsf(a2)));
}

// ---- MFMA GEMM v2: 64n x 128o tile, double-buffered, 1 barrier/chunk ----
// Out[b][n][o] = sum_k stackT[b][n][koff+k] * W[b?][o][k] + bias[o]
__global__ __launch_bounds__(256) void k_mfma(int koff, int K,
                                              const unsigned short* __restrict__ W, size_t wstride,
                                              float* __restrict__ Out,
                                              const float* __restrict__ bias, int bias_stride,
                                              int gelu, int aux) {
  __shared__ unsigned short As[2][64*40];    // [buf][n-row][k] pad 40
  __shared__ unsigned short Bs[2][128*40];   // [buf][o-row][k]
  int b = blockIdx.z;
  int n_base = blockIdx.x*64;
  int tid = threadIdx.x;
  int lane = tid & 63, wid = tid >> 6;
  int q = lane >> 4, m = lane & 15;

  f32x4 acc[8];
  #pragma unroll
  for (int j = 0; j < 8; j++) acc[j] = (f32x4){0.f,0.f,0.f,0.f};

  const unsigned short* Wb = W + (size_t)b*wstride;
  const unsigned short* Ab = d_stackT + (size_t)b*NP*KR + koff;

#define STAGE(k0, d) { \
    int rowA = tid >> 2; int e8A = (tid & 3)*8; \
    *(uint4*)&As[d][rowA*40 + e8A] = *(const uint4*)(Ab + (size_t)(n_base + rowA)*KR + (k0) + e8A); \
    _Pragma("unroll") \
    for (int i_ = 0; i_ < 2; i_++) { \
      int idx_ = tid + i_*256; int rowB = idx_ >> 2; int e8B = (idx_ & 3)*8; \
      *(uint4*)&Bs[d][rowB*40 + e8B] = *(const uint4*)(Wb + (size_t)rowB*K + (k0) + e8B); \
    } }

  STAGE(0, 0)
  int cur = 0;
  for (int k0 = 0; k0 < K; k0 += 32) {
    __syncthreads();
    if (k0 + 32 < K) STAGE(k0 + 32, cur ^ 1)
    bf16x8 a = *(const bf16x8*)&As[cur][(wid*16 + m)*40 + q*8];
    #pragma unroll
    for (int ot = 0; ot < 8; ot++) {
      bf16x8 bf = *(const bf16x8*)&Bs[cur][(ot*16 + m)*40 + q*8];
      acc[ot] = __builtin_amdgcn_mfma_f32_16x16x32_bf16(a, bf, acc[ot], 0, 0, 0);
    }
    cur ^= 1;
  }
#undef STAGE

  const float* bp = bias + (size_t)b*bias_stride;
  int nb4 = n_base + wid*16 + q*4;
  float nw4[4];
  #pragma unroll
  for (int r = 0; r < 4; r++)
    nw4[r] = (aux && nb4 + r < NN) ? d_nw[b*NN + nb4 + r] : 0.f;
  #pragma unroll
  for (int ot = 0; ot < 8; ot++) {
    int o = ot*16 + m;
    float bvv = bp[o];
    float vals[4];
    #pragma unroll
    for (int r = 0; r < 4; r++) {
      float v = acc[ot][r] + bvv;
      if (gelu) v = 0.5f*v*(1.f + erff(v*0.70710678118f));
      vals[r] = v;
      Out[((size_t)(b*NP + nb4 + r))*128 + o] = v;
      if (aux && nb4 + r < NN)
        d_stackT[((size_t)(b*NP + nb4 + r))*KR + 256 + o] = f2bf(v);
    }
    if (aux) {
      ushort4 pk;
      pk.x = f2bf(vals[0]*nw4[0]);
      pk.y = f2bf(vals[1]*nw4[1]);
      pk.z = f2bf(vals[2]*nw4[2]);
      pk.w = f2bf(vals[3]*nw4[3]);
      *(ushort4*)&d_hTwT[((size_t)(b*CC + o))*NP + nb4] = pk;
    }
  }
}

// ---- fc2 + residual; u = d_uT [b][n][o2] ----
__global__ __launch_bounds__(256) void k_out(const float* __restrict__ x,
                                             const float* __restrict__ t,
                                             const float* __restrict__ fc2w,
                                             const float* __restrict__ fc2b,
                                             float* __restrict__ out) {
  int tid = blockIdx.x*256 + threadIdx.x;
  if (tid >= BB*NN) return;
  int b = tid / NN, n = tid % NN;
  const float* up = d_uT + ((size_t)(b*NP + n))*FCC;
  float a0 = fc2b[0], a1 = fc2b[1], a2v = fc2b[2];
  #pragma unroll 4
  for (int o2 = 0; o2 < FCC; o2 += 4) {
    float4 uv = *(const float4*)&up[o2];
    a0  += uv.x*fc2w[(o2+0)*3+0] + uv.y*fc2w[(o2+1)*3+0] + uv.z*fc2w[(o2+2)*3+0] + uv.w*fc2w[(o2+3)*3+0];
    a1  += uv.x*fc2w[(o2+0)*3+1] + uv.y*fc2w[(o2+1)*3+1] + uv.z*fc2w[(o2+2)*3+1] + uv.w*fc2w[(o2+3)*3+1];
    a2v += uv.x*fc2w[(o2+0)*3+2] + uv.y*fc2w[(o2+1)*3+2] + uv.z*fc2w[(o2+2)*3+2] + uv.w*fc2w[(o2+3)*3+2];
  }
  float tv = t[tid];
  out[tid*3 + 0] = x[tid*3 + 0] + tv*a0;
  out[tid*3 + 1] = x[tid*3 + 1] + tv*a1;
  out[tid*3 + 2] = x[tid*3 + 2] + tv*a2v;
}

extern "C" void kernel_launch(void* const* d_in, const int* in_sizes, int n_in,
                              void* d_out, int out_size, void* d_ws, size_t ws_size,
                              hipStream_t stream) {
  const float* x     = (const float*)d_in[0];
  const float* t     = (const float*)d_in[1];
  const float* nodes = (const float*)d_in[3];
  const float* nodew = (const float*)d_in[4];
  const int*   edges = (const int*)d_in[5];
  const float* egw   = (const float*)d_in[6];
  const float* modes = (const float*)d_in[7];
  const float* spL   = (const float*)d_in[8];
  const float* fc0w  = (const float*)d_in[9];
  const float* fc0b  = (const float*)d_in[10];
  const float* Wc    = (const float*)d_in[11];
  const float* Ws    = (const float*)d_in[12];
  const float* W0    = (const float*)d_in[13];
  const float* wsw   = (const float*)d_in[14];
  const float* wsb   = (const float*)d_in[15];
  const float* gwsw  = (const float*)d_in[16];
  const float* gwsb  = (const float*)d_in[17];
  const float* fc1w  = (const float*)d_in[18];
  const float* fc1b  = (const float*)d_in[19];
  const float* fc2w  = (const float*)d_in[20];
  const float* fc2b  = (const float*)d_in[21];
  float* out = (float*)d_out;

  unsigned short* d_Amatb_p; hipGetSymbolAddress((void**)&d_Amatb_p, HIP_SYMBOL(d_Amatb));
  unsigned short* d_fc1wb_p; hipGetSymbolAddress((void**)&d_fc1wb_p, HIP_SYMBOL(d_fc1wb));
  float* d_hnewT_p; hipGetSymbolAddress((void**)&d_hnewT_p, HIP_SYMBOL(d_hnewT));
  float* d_uT_p;    hipGetSymbolAddress((void**)&d_uT_p,    HIP_SYMBOL(d_uT));
  float* d_bias_p;  hipGetSymbolAddress((void**)&d_bias_p,  HIP_SYMBOL(d_bias));

  hipLaunchKernelGGL(k_basis, dim3(BB*NN), dim3(128), 0, stream, nodes, nodew, modes, spL);
  hipLaunchKernelGGL(k_basisT, dim3(628*BB), dim3(256), 0, stream);
  hipLaunchKernelGGL(k_h0, dim3(BB*NN*CC/256), dim3(256), 0, stream, x, t, fc0w, fc0b);
  hipLaunchKernelGGL(k_hT0, dim3(NCHK, BB), dim3(256), 0, stream);
  hipLaunchKernelGGL(k_fc1w, dim3(CC), dim3(FCC), 0, stream, fc1w);
  // CSR build (once; edges constant across layers)
  hipLaunchKernelGGL(k_csr_zero, dim3((BB*NN + 255)/256), dim3(256), 0, stream);
  hipLaunchKernelGGL(k_csr_count, dim3((BB*EE + 255)/256), dim3(256), 0, stream, edges);
  hipLaunchKernelGGL(k_csr_scan, dim3(BB), dim3(1024), 0, stream);
  hipLaunchKernelGGL(k_csr_scatter, dim3((BB*EE + 255)/256), dim3(256), 0, stream, edges, egw);

  for (int l = 0; l < LL; l++) {
    hipLaunchKernelGGL(k_gemm1m, dim3(G1CH, BB), dim3(256), 0, stream);
    hipLaunchKernelGGL(k_reduce1, dim3(256), dim3(256), 0, stream);
    hipLaunchKernelGGL(k_x0, dim3(NCHK, BB), dim3(256), 0, stream);
    hipLaunchKernelGGL(k_spec, dim3(BB*CC), dim3(128), 0, stream, Wc, Ws, l);
    hipLaunchKernelGGL(k_f0, dim3(BB), dim3(CC), 0, stream, W0, wsb, gwsb, l);
    hipLaunchKernelGGL(k_buildAb, dim3(BB*CC), dim3(128), 0, stream, wsw, gwsw, l);
    hipLaunchKernelGGL(k_grad_csr, dim3(BB*NN), dim3(128), 0, stream);
    hipLaunchKernelGGL(k_mfma, dim3(NP/64, 1, BB), dim3(256), 0, stream,
                       0, KR, d_Amatb_p, (size_t)CC*KR, d_hnewT_p, d_bias_p, CC,
                       (l != LL-1) ? 1 : 0, 1);
  }

  // fc1 via MFMA on the h slab
  hipLaunchKernelGGL(k_mfma, dim3(NP/64, 1, BB), dim3(256), 0, stream,
                     256, CC, d_fc1wb_p, (size_t)0, d_uT_p, fc1b, 0, 1, 0);
  hipLaunchKernelGGL(k_out, dim3((BB*NN + 255)/256), dim3(256), 0, stream, x, t, fc2w, fc2b, out);
}